// Round 1
// baseline (1319.460 us; speedup 1.0000x reference)
//
#include <hip/hip_runtime.h>

#define NN 50000
#define NE 400000

__device__ __forceinline__ float lrelu01(float v) { return v >= 0.f ? v : 0.01f * v; }
__device__ __forceinline__ float lrelu02(float v) { return v >= 0.f ? v : 0.2f * v; }

// ---------------- CSR build ----------------
__global__ void count_kernel(const int* __restrict__ dst, int* __restrict__ counts, int e) {
  int i = blockIdx.x * 256 + threadIdx.x;
  if (i < e) atomicAdd(&counts[dst[i]], 1);
}

__global__ void dinv_kernel(const int* __restrict__ counts, float* __restrict__ dinv, int n) {
  int i = blockIdx.x * 256 + threadIdx.x;
  if (i < n) dinv[i] = rsqrtf((float)counts[i] + 1.0f);
}

__global__ __launch_bounds__(1024) void scan_kernel(const int* __restrict__ counts,
                                                    int* __restrict__ row_start, int n) {
  __shared__ int part[1024];
  int tid = threadIdx.x;
  int chunk = (n + 1023) >> 10;
  int lo = tid * chunk;
  int hi = lo + chunk; if (hi > n) hi = n;
  int s = 0;
  for (int i = lo; i < hi; ++i) s += counts[i];
  part[tid] = s;
  __syncthreads();
  for (int off = 1; off < 1024; off <<= 1) {
    int v = 0;
    if (tid >= off) v = part[tid - off];
    __syncthreads();
    part[tid] += v;
    __syncthreads();
  }
  int running = (tid == 0) ? 0 : part[tid - 1];
  for (int i = lo; i < hi; ++i) { row_start[i] = running; running += counts[i]; }
  if (tid == 1023) row_start[n] = part[1023];
}

__global__ void fill_kernel(const int* __restrict__ src, const int* __restrict__ dst,
                            const int* __restrict__ row_start, int* __restrict__ cursor,
                            int* __restrict__ csr, int e) {
  int i = blockIdx.x * 256 + threadIdx.x;
  if (i >= e) return;
  int d = dst[i];
  int pos = atomicAdd(&cursor[d], 1);
  csr[row_start[d] + pos] = src[i];
}

// ---------------- fp32 tiled GEMM: C[M,N] = A[M,K] @ B[K,N] ----------------
// BM=128, BN=64, BK=16, 256 threads, 8x4 microtile. K % 16 == 0 required.
__global__ __launch_bounds__(256) void gemm_tiled(const float* __restrict__ A,
                                                  const float* __restrict__ B,
                                                  float* __restrict__ C,
                                                  int M, int K, int N) {
  __shared__ float As[16][132];
  __shared__ float Bs[16][68];
  const int tid = threadIdx.x;
  const int bm = blockIdx.x * 128;
  const int bn = blockIdx.y * 64;
  const int tx = tid & 15;
  const int ty = tid >> 4;
  float acc[8][4];
#pragma unroll
  for (int i = 0; i < 8; ++i)
#pragma unroll
    for (int j = 0; j < 4; ++j) acc[i][j] = 0.f;

  for (int k0 = 0; k0 < K; k0 += 16) {
#pragma unroll
    for (int i = 0; i < 2; ++i) {
      int s = tid + i * 256;        // 0..511
      int r = s >> 2;               // 0..127
      int kq = (s & 3) << 2;        // 0,4,8,12
      float4 v = make_float4(0.f, 0.f, 0.f, 0.f);
      int row = bm + r;
      if (row < M) v = *reinterpret_cast<const float4*>(&A[(size_t)row * K + k0 + kq]);
      As[kq + 0][r] = v.x; As[kq + 1][r] = v.y; As[kq + 2][r] = v.z; As[kq + 3][r] = v.w;
    }
    {
      int k = tid >> 4;             // 0..15
      int c = (tid & 15) << 2;      // 0..60
      float4 v = make_float4(0.f, 0.f, 0.f, 0.f);
      if (bn + c < N) v = *reinterpret_cast<const float4*>(&B[(size_t)(k0 + k) * N + bn + c]);
      Bs[k][c + 0] = v.x; Bs[k][c + 1] = v.y; Bs[k][c + 2] = v.z; Bs[k][c + 3] = v.w;
    }
    __syncthreads();
#pragma unroll
    for (int k = 0; k < 16; ++k) {
      float a[8], b[4];
#pragma unroll
      for (int i = 0; i < 8; ++i) a[i] = As[k][ty * 8 + i];
#pragma unroll
      for (int j = 0; j < 4; ++j) b[j] = Bs[k][tx * 4 + j];
#pragma unroll
      for (int i = 0; i < 8; ++i)
#pragma unroll
        for (int j = 0; j < 4; ++j) acc[i][j] += a[i] * b[j];
    }
    __syncthreads();
  }
#pragma unroll
  for (int i = 0; i < 8; ++i) {
    int row = bm + ty * 8 + i;
    if (row >= M) continue;
#pragma unroll
    for (int j = 0; j < 4; ++j) {
      int col = bn + tx * 4 + j;
      if (col < N) C[(size_t)row * N + col] = acc[i][j];
    }
  }
}

// ---------------- GCN aggregation (CSR gather) ----------------
template <int F>
__global__ __launch_bounds__(256) void gcn_agg(const float* __restrict__ h,
                                               const int* __restrict__ row_start,
                                               const int* __restrict__ csr,
                                               const float* __restrict__ dinv,
                                               const float* __restrict__ bias,
                                               float* __restrict__ out, int n) {
  constexpr int NPB = 256 / F;
  int node = blockIdx.x * NPB + threadIdx.x / F;
  int f = threadIdx.x % F;
  if (node >= n) return;
  float di = dinv[node];
  float acc = h[(size_t)node * F + f] * di * di;   // self loop
  int s0 = row_start[node], s1 = row_start[node + 1];
  for (int e = s0; e < s1; ++e) {
    int s = csr[e];
    acc += di * dinv[s] * h[(size_t)s * F + f];
  }
  out[(size_t)node * F + f] = acc + bias[f];
}

// ---------------- BatchNorm (training stats) + leaky relu ----------------
template <int F>
__global__ __launch_bounds__(256) void bn_stats(const float* __restrict__ x,
                                                float* __restrict__ stats, int n) {
  constexpr int RSTEP = 256 / F;
  int col = threadIdx.x % F;
  int rsub = threadIdx.x / F;
  int r0 = blockIdx.x * 256;
  int rend = r0 + 256; if (rend > n) rend = n;
  float s = 0.f, ss = 0.f;
  for (int r = r0 + rsub; r < rend; r += RSTEP) {
    float v = x[(size_t)r * F + col];
    s += v; ss += v * v;
  }
  atomicAdd(&stats[col], s);
  atomicAdd(&stats[F + col], ss);
}

template <int F>
__global__ __launch_bounds__(256) void bn_lrelu(float* __restrict__ x,
                                                const float* __restrict__ stats,
                                                const float* __restrict__ gamma,
                                                const float* __restrict__ beta, int n) {
  int i = blockIdx.x * 256 + threadIdx.x;
  int total = n * F;
  if (i >= total) return;
  int col = i & (F - 1);
  const float inv_n = 1.0f / (float)n;
  float mean = stats[col] * inv_n;
  float var = stats[F + col] * inv_n - mean * mean;
  float sc = gamma[col] * rsqrtf(var + 1e-5f);
  float v = (x[i] - mean) * sc + beta[col];
  x[i] = v >= 0.f ? v : 0.01f * v;
}

// ---------------- GAT ----------------
// per-node per-head attention scores: asc/adc [n,4]
__global__ __launch_bounds__(256) void gat_scores(const float* __restrict__ hg,
                                                  const float* __restrict__ a_src,
                                                  const float* __restrict__ a_dst,
                                                  float* __restrict__ asc,
                                                  float* __restrict__ adc, int n) {
  int node = blockIdx.x;
  int head = threadIdx.x >> 6;
  int lane = threadIdx.x & 63;
  const float* row = hg + (size_t)node * 512 + head * 128;
  float v0 = row[lane], v1 = row[lane + 64];
  float s = v0 * a_src[head * 128 + lane] + v1 * a_src[head * 128 + lane + 64];
  float d = v0 * a_dst[head * 128 + lane] + v1 * a_dst[head * 128 + lane + 64];
#pragma unroll
  for (int off = 32; off > 0; off >>= 1) {
    s += __shfl_down(s, off);
    d += __shfl_down(d, off);
  }
  if (lane == 0) {
    asc[node * 4 + head] = s;
    adc[node * 4 + head] = d;
  }
}

// per (node,head): softmax max + denom over incoming edges (+self); store exp weights per csr slot
__global__ __launch_bounds__(256) void gat_softmax(const int* __restrict__ row_start,
                                                   const int* __restrict__ csr,
                                                   const float* __restrict__ asc,
                                                   const float* __restrict__ adc,
                                                   float* __restrict__ alpha,
                                                   float* __restrict__ wself,
                                                   float* __restrict__ invden, int n) {
  int i = blockIdx.x * 256 + threadIdx.x;
  if (i >= 4 * n) return;
  int node = i >> 2, h = i & 3;
  int s0 = row_start[node], s1 = row_start[node + 1];
  float ad = adc[i];
  float eself = lrelu02(asc[i] + ad);
  float m = eself;
  for (int e = s0; e < s1; ++e) {
    float v = lrelu02(asc[csr[e] * 4 + h] + ad);
    m = fmaxf(m, v);
  }
  float ws = __expf(eself - m);
  wself[i] = ws;
  float den = ws;
  for (int e = s0; e < s1; ++e) {
    float v = __expf(lrelu02(asc[csr[e] * 4 + h] + ad) - m);
    alpha[(size_t)e * 4 + h] = v;
    den += v;
  }
  invden[i] = 1.f / (den + 1e-16f);
}

// aggregate alpha * h over incoming edges, mean over 4 heads, + bias
__global__ __launch_bounds__(128) void gat_agg(const float* __restrict__ hg,
                                               const int* __restrict__ row_start,
                                               const int* __restrict__ csr,
                                               const float* __restrict__ alpha,
                                               const float* __restrict__ wself,
                                               const float* __restrict__ invden,
                                               const float* __restrict__ gat_b,
                                               float* __restrict__ out, int n) {
  int node = blockIdx.x;
  int f = threadIdx.x;  // 0..127
  float id0 = invden[node * 4 + 0], id1 = invden[node * 4 + 1];
  float id2 = invden[node * 4 + 2], id3 = invden[node * 4 + 3];
  const float* hrow = hg + (size_t)node * 512;
  float acc = wself[node * 4 + 0] * id0 * hrow[f]
            + wself[node * 4 + 1] * id1 * hrow[128 + f]
            + wself[node * 4 + 2] * id2 * hrow[256 + f]
            + wself[node * 4 + 3] * id3 * hrow[384 + f];
  int s0 = row_start[node], s1 = row_start[node + 1];
  for (int e = s0; e < s1; ++e) {
    int s = csr[e];
    const float* srow = hg + (size_t)s * 512;
    float4 al = *reinterpret_cast<const float4*>(&alpha[(size_t)e * 4]);
    acc += al.x * id0 * srow[f] + al.y * id1 * srow[128 + f]
         + al.z * id2 * srow[256 + f] + al.w * id3 * srow[384 + f];
  }
  out[(size_t)node * 128 + f] = acc * 0.25f + gat_b[f];
}

// ---------------- FC head + log_softmax ----------------
__global__ __launch_bounds__(256) void head_kernel(const float* __restrict__ h,
                                                   const float* __restrict__ fw1,
                                                   const float* __restrict__ fb1,
                                                   const float* __restrict__ fw2,
                                                   const float* __restrict__ fb2,
                                                   float* __restrict__ out, int n) {
  int i = blockIdx.x * 256 + threadIdx.x;
  if (i >= n) return;
  float xr[16];
#pragma unroll
  for (int q = 0; q < 4; ++q) {
    float4 v = *reinterpret_cast<const float4*>(&h[(size_t)i * 16 + q * 4]);
    xr[q * 4 + 0] = v.x; xr[q * 4 + 1] = v.y; xr[q * 4 + 2] = v.z; xr[q * 4 + 3] = v.w;
  }
  float z[8];
#pragma unroll
  for (int j = 0; j < 8; ++j) z[j] = fb1[j];
#pragma unroll
  for (int k = 0; k < 16; ++k) {
    float a = xr[k];
#pragma unroll
    for (int j = 0; j < 8; ++j) z[j] += a * fw1[k * 8 + j];
  }
#pragma unroll
  for (int j = 0; j < 8; ++j) z[j] = lrelu01(z[j]);
  float l[3];
#pragma unroll
  for (int j = 0; j < 3; ++j) l[j] = fb2[j];
#pragma unroll
  for (int k = 0; k < 8; ++k) {
    float a = z[k];
#pragma unroll
    for (int j = 0; j < 3; ++j) l[j] += a * fw2[k * 3 + j];
  }
  float mx = fmaxf(l[0], fmaxf(l[1], l[2]));
  float se = __expf(l[0] - mx) + __expf(l[1] - mx) + __expf(l[2] - mx);
  float ls = __logf(se);
#pragma unroll
  for (int j = 0; j < 3; ++j) out[(size_t)i * 3 + j] = l[j] - mx - ls;
}

// ---------------- launch ----------------
extern "C" void kernel_launch(void* const* d_in, const int* in_sizes, int n_in,
                              void* d_out, int out_size, void* d_ws, size_t ws_size,
                              hipStream_t stream) {
  const float* x      = (const float*)d_in[0];
  const int*   ei     = (const int*)d_in[1];
  const int*   srcI   = ei;
  const int*   dstI   = ei + NE;
  const float* w1     = (const float*)d_in[2];
  const float* b1     = (const float*)d_in[3];
  const float* g1     = (const float*)d_in[4];
  const float* be1    = (const float*)d_in[5];
  const float* gat_w  = (const float*)d_in[6];
  const float* gat_as = (const float*)d_in[7];
  const float* gat_ad = (const float*)d_in[8];
  const float* gat_b  = (const float*)d_in[9];
  const float* g2     = (const float*)d_in[10];
  const float* be2    = (const float*)d_in[11];
  const float* w3     = (const float*)d_in[12];
  const float* b3     = (const float*)d_in[13];
  const float* g3     = (const float*)d_in[14];
  const float* be3    = (const float*)d_in[15];
  const float* w4     = (const float*)d_in[16];
  const float* b4     = (const float*)d_in[17];
  const float* g4     = (const float*)d_in[18];
  const float* be4    = (const float*)d_in[19];
  const float* w5     = (const float*)d_in[20];
  const float* b5     = (const float*)d_in[21];
  const float* g5     = (const float*)d_in[22];
  const float* be5    = (const float*)d_in[23];
  const float* fw1    = (const float*)d_in[24];
  const float* fb1    = (const float*)d_in[25];
  const float* fw2    = (const float*)d_in[26];
  const float* fb2    = (const float*)d_in[27];
  float* out = (float*)d_out;

  char* wsp = (char*)d_ws;
  size_t off = 0;
  auto alloc = [&](size_t bytes) -> void* {
    void* p = wsp + off;
    off += (bytes + 255) & ~(size_t)255;
    return p;
  };
  float* bufA     = (float*)alloc((size_t)NN * 512 * 4);  // GEMM outputs (up to 512 wide)
  float* bufB     = (float*)alloc((size_t)NN * 256 * 4);  // agg outputs / layer activations
  float* dinv     = (float*)alloc((size_t)NN * 4);
  int*   counts   = (int*)alloc((size_t)NN * 4);
  int*   cursor   = (int*)alloc((size_t)NN * 4);
  int*   rstart   = (int*)alloc((size_t)(NN + 4) * 4);
  int*   csr      = (int*)alloc((size_t)NE * 4);
  float* asc      = (float*)alloc((size_t)NN * 4 * 4);
  float* adc      = (float*)alloc((size_t)NN * 4 * 4);
  float* wself    = (float*)alloc((size_t)NN * 4 * 4);
  float* invden   = (float*)alloc((size_t)NN * 4 * 4);
  float* alpha    = (float*)alloc((size_t)NE * 4 * 4);
  float* stats    = (float*)alloc(2048);

  const int egrid = (NE + 255) / 256;
  const int ngrid = (NN + 255) / 256;

  // CSR build (reused by all 5 propagation layers)
  hipMemsetAsync(counts, 0, (size_t)NN * 4, stream);
  hipMemsetAsync(cursor, 0, (size_t)NN * 4, stream);
  count_kernel<<<egrid, 256, 0, stream>>>(dstI, counts, NE);
  dinv_kernel<<<ngrid, 256, 0, stream>>>(counts, dinv, NN);
  scan_kernel<<<1, 1024, 0, stream>>>(counts, rstart, NN);
  fill_kernel<<<egrid, 256, 0, stream>>>(srcI, dstI, rstart, cursor, csr, NE);

  const int mblocks = (NN + 127) / 128;

  // ---- Layer 1: GCN 256 -> 256 ----
  gemm_tiled<<<dim3(mblocks, 4), 256, 0, stream>>>(x, w1, bufA, NN, 256, 256);
  gcn_agg<256><<<NN, 256, 0, stream>>>(bufA, rstart, csr, dinv, b1, bufB, NN);
  hipMemsetAsync(stats, 0, 2048, stream);
  bn_stats<256><<<(NN + 255) / 256, 256, 0, stream>>>(bufB, stats, NN);
  bn_lrelu<256><<<(NN * 256 + 255) / 256, 256, 0, stream>>>(bufB, stats, g1, be1, NN);

  // ---- Layer 2: GAT 256 -> 128 (4 heads, mean) ----
  gemm_tiled<<<dim3(mblocks, 8), 256, 0, stream>>>(bufB, gat_w, bufA, NN, 256, 512);
  gat_scores<<<NN, 256, 0, stream>>>(bufA, gat_as, gat_ad, asc, adc, NN);
  gat_softmax<<<(4 * NN + 255) / 256, 256, 0, stream>>>(rstart, csr, asc, adc, alpha, wself, invden, NN);
  gat_agg<<<NN, 128, 0, stream>>>(bufA, rstart, csr, alpha, wself, invden, gat_b, bufB, NN);
  hipMemsetAsync(stats, 0, 2048, stream);
  bn_stats<128><<<(NN + 255) / 256, 256, 0, stream>>>(bufB, stats, NN);
  bn_lrelu<128><<<(NN * 128 + 255) / 256, 256, 0, stream>>>(bufB, stats, g2, be2, NN);

  // ---- Layer 3: GCN 128 -> 64 ----
  gemm_tiled<<<dim3(mblocks, 1), 256, 0, stream>>>(bufB, w3, bufA, NN, 128, 64);
  gcn_agg<64><<<(NN + 3) / 4, 256, 0, stream>>>(bufA, rstart, csr, dinv, b3, bufB, NN);
  hipMemsetAsync(stats, 0, 2048, stream);
  bn_stats<64><<<(NN + 255) / 256, 256, 0, stream>>>(bufB, stats, NN);
  bn_lrelu<64><<<(NN * 64 + 255) / 256, 256, 0, stream>>>(bufB, stats, g3, be3, NN);

  // ---- Layer 4: GCN 64 -> 32 ----
  gemm_tiled<<<dim3(mblocks, 1), 256, 0, stream>>>(bufB, w4, bufA, NN, 64, 32);
  gcn_agg<32><<<(NN + 7) / 8, 256, 0, stream>>>(bufA, rstart, csr, dinv, b4, bufB, NN);
  hipMemsetAsync(stats, 0, 2048, stream);
  bn_stats<32><<<(NN + 255) / 256, 256, 0, stream>>>(bufB, stats, NN);
  bn_lrelu<32><<<(NN * 32 + 255) / 256, 256, 0, stream>>>(bufB, stats, g4, be4, NN);

  // ---- Layer 5: GCN 32 -> 16 ----
  gemm_tiled<<<dim3(mblocks, 1), 256, 0, stream>>>(bufB, w5, bufA, NN, 32, 16);
  gcn_agg<16><<<(NN + 15) / 16, 256, 0, stream>>>(bufA, rstart, csr, dinv, b5, bufB, NN);
  hipMemsetAsync(stats, 0, 2048, stream);
  bn_stats<16><<<(NN + 255) / 256, 256, 0, stream>>>(bufB, stats, NN);
  bn_lrelu<16><<<(NN * 16 + 255) / 256, 256, 0, stream>>>(bufB, stats, g5, be5, NN);

  // ---- FC head + log_softmax ----
  head_kernel<<<ngrid, 256, 0, stream>>>(bufB, fw1, fb1, fw2, fb2, out, NN);
}

// Round 2
// 1104.260 us; speedup vs baseline: 1.1949x; 1.1949x over previous
//
#include <hip/hip_runtime.h>

#define NN 50000
#define NE 400000

typedef short bf16x8 __attribute__((ext_vector_type(8)));
typedef float f32x4 __attribute__((ext_vector_type(4)));

__device__ __forceinline__ float lrelu01(float v) { return v >= 0.f ? v : 0.01f * v; }
__device__ __forceinline__ float lrelu02(float v) { return v >= 0.f ? v : 0.2f * v; }

__device__ __forceinline__ ushort f2bf(float f) {
  union { float f; unsigned u; } v; v.f = f;
  unsigned u = v.u;
  return (ushort)((u + 0x7FFFu + ((u >> 16) & 1u)) >> 16);
}

// ---------------- bf16 conversion helpers ----------------
__global__ void f32_to_bf16(const float* __restrict__ in, ushort* __restrict__ out, int n4) {
  int i = blockIdx.x * 256 + threadIdx.x;
  if (i >= n4) return;
  float4 v = *reinterpret_cast<const float4*>(&in[(size_t)i * 4]);
  ushort4 o;
  o.x = f2bf(v.x); o.y = f2bf(v.y); o.z = f2bf(v.z); o.w = f2bf(v.w);
  *reinterpret_cast<ushort4*>(&out[(size_t)i * 4]) = o;
}

// W [K][N] fp32 -> WT [N][K] bf16
__global__ void transpose_bf(const float* __restrict__ W, ushort* __restrict__ WT, int K, int N) {
  int i = blockIdx.x * 256 + threadIdx.x;
  if (i >= K * N) return;
  int k = i / N, c = i % N;
  WT[(size_t)c * K + k] = f2bf(W[i]);
}

// ---------------- CSR build ----------------
__global__ void count_kernel(const int* __restrict__ dst, int* __restrict__ counts, int e) {
  int i = blockIdx.x * 256 + threadIdx.x;
  if (i < e) atomicAdd(&counts[dst[i]], 1);
}

__global__ void dinv_kernel(const int* __restrict__ counts, float* __restrict__ dinv, int n) {
  int i = blockIdx.x * 256 + threadIdx.x;
  if (i < n) dinv[i] = rsqrtf((float)counts[i] + 1.0f);
}

__global__ __launch_bounds__(1024) void scan_kernel(const int* __restrict__ counts,
                                                    int* __restrict__ row_start, int n) {
  __shared__ int part[1024];
  int tid = threadIdx.x;
  int chunk = (n + 1023) >> 10;
  int lo = tid * chunk;
  int hi = lo + chunk; if (hi > n) hi = n;
  int s = 0;
  for (int i = lo; i < hi; ++i) s += counts[i];
  part[tid] = s;
  __syncthreads();
  for (int off = 1; off < 1024; off <<= 1) {
    int v = 0;
    if (tid >= off) v = part[tid - off];
    __syncthreads();
    part[tid] += v;
    __syncthreads();
  }
  int running = (tid == 0) ? 0 : part[tid - 1];
  for (int i = lo; i < hi; ++i) { row_start[i] = running; running += counts[i]; }
  if (tid == 1023) row_start[n] = part[1023];
}

__global__ void fill_kernel(const int* __restrict__ src, const int* __restrict__ dst,
                            const int* __restrict__ row_start, int* __restrict__ cursor,
                            int* __restrict__ csr, int e) {
  int i = blockIdx.x * 256 + threadIdx.x;
  if (i >= e) return;
  int d = dst[i];
  int pos = atomicAdd(&cursor[d], 1);
  csr[row_start[d] + pos] = src[i];
}

// ---------------- bf16 MFMA GEMM: C[M,N] f32 = A[M,K]bf16 @ (BT[N,K])^T ----------------
// 128x128 tile, 4 waves, BK=32. K % 32 == 0, N % 128 == 0.
__global__ __launch_bounds__(256) void gemm_mfma(const ushort* __restrict__ A,
                                                 const ushort* __restrict__ BT,
                                                 float* __restrict__ C,
                                                 int M, int K, int N) {
  __shared__ ushort As[128][40];
  __shared__ ushort Bs[128][40];
  const int tid = threadIdx.x;
  const int bm = blockIdx.x * 128;
  const int bn = blockIdx.y * 128;
  const int wave = tid >> 6, lane = tid & 63;
  const int wr = (wave >> 1) * 64;   // wave row offset in tile
  const int wc = (wave & 1) * 64;    // wave col offset in tile
  const int lr = lane & 15;          // fragment row/col index
  const int lk = (lane >> 4) * 8;    // fragment k offset

  f32x4 acc[4][4];
#pragma unroll
  for (int m = 0; m < 4; ++m)
#pragma unroll
    for (int n = 0; n < 4; ++n)
#pragma unroll
      for (int q = 0; q < 4; ++q) acc[m][n][q] = 0.f;

  for (int k0 = 0; k0 < K; k0 += 32) {
    // stage A tile: 128 rows x 32 bf16 (64B) = 8KB -> 512 x int4
#pragma unroll
    for (int it = 0; it < 2; ++it) {
      int s = tid + it * 256;
      int r = s >> 2;
      int c = (s & 3) * 8;
      int grow = bm + r; if (grow >= M) grow = M - 1;
      int4 v = *reinterpret_cast<const int4*>(&A[(size_t)grow * K + k0 + c]);
      *reinterpret_cast<int4*>(&As[r][c]) = v;
    }
    // stage BT tile (rows of BT = cols of B)
#pragma unroll
    for (int it = 0; it < 2; ++it) {
      int s = tid + it * 256;
      int r = s >> 2;
      int c = (s & 3) * 8;
      int4 v = *reinterpret_cast<const int4*>(&BT[(size_t)(bn + r) * K + k0 + c]);
      *reinterpret_cast<int4*>(&Bs[r][c]) = v;
    }
    __syncthreads();

    bf16x8 af[4], bfr[4];
#pragma unroll
    for (int m = 0; m < 4; ++m)
      af[m] = *reinterpret_cast<const bf16x8*>(&As[wr + m * 16 + lr][lk]);
#pragma unroll
    for (int n = 0; n < 4; ++n)
      bfr[n] = *reinterpret_cast<const bf16x8*>(&Bs[wc + n * 16 + lr][lk]);
#pragma unroll
    for (int m = 0; m < 4; ++m)
#pragma unroll
      for (int n = 0; n < 4; ++n)
        acc[m][n] = __builtin_amdgcn_mfma_f32_16x16x32_bf16(af[m], bfr[n], acc[m][n], 0, 0, 0);
    __syncthreads();
  }

  // epilogue: C/D layout col=lane&15, row=(lane>>4)*4+q
  const int rbase = (lane >> 4) * 4;
  const int cbase = lane & 15;
#pragma unroll
  for (int m = 0; m < 4; ++m) {
    int row0 = bm + wr + m * 16 + rbase;
#pragma unroll
    for (int n = 0; n < 4; ++n) {
      int col = bn + wc + n * 16 + cbase;
#pragma unroll
      for (int q = 0; q < 4; ++q) {
        int row = row0 + q;
        if (row < M) C[(size_t)row * N + col] = acc[m][n][q];
      }
    }
  }
}

// ---------------- fp32 tiled GEMM (small layers): C[M,N] = A[M,K] @ B[K,N] ----------------
__global__ __launch_bounds__(256) void gemm_tiled(const float* __restrict__ A,
                                                  const float* __restrict__ B,
                                                  float* __restrict__ C,
                                                  int M, int K, int N) {
  __shared__ float As[16][132];
  __shared__ float Bs[16][68];
  const int tid = threadIdx.x;
  const int bm = blockIdx.x * 128;
  const int bn = blockIdx.y * 64;
  const int tx = tid & 15;
  const int ty = tid >> 4;
  float acc[8][4];
#pragma unroll
  for (int i = 0; i < 8; ++i)
#pragma unroll
    for (int j = 0; j < 4; ++j) acc[i][j] = 0.f;

  for (int k0 = 0; k0 < K; k0 += 16) {
#pragma unroll
    for (int i = 0; i < 2; ++i) {
      int s = tid + i * 256;
      int r = s >> 2;
      int kq = (s & 3) << 2;
      float4 v = make_float4(0.f, 0.f, 0.f, 0.f);
      int row = bm + r;
      if (row < M) v = *reinterpret_cast<const float4*>(&A[(size_t)row * K + k0 + kq]);
      As[kq + 0][r] = v.x; As[kq + 1][r] = v.y; As[kq + 2][r] = v.z; As[kq + 3][r] = v.w;
    }
    {
      int k = tid >> 4;
      int c = (tid & 15) << 2;
      float4 v = make_float4(0.f, 0.f, 0.f, 0.f);
      if (bn + c < N) v = *reinterpret_cast<const float4*>(&B[(size_t)(k0 + k) * N + bn + c]);
      Bs[k][c + 0] = v.x; Bs[k][c + 1] = v.y; Bs[k][c + 2] = v.z; Bs[k][c + 3] = v.w;
    }
    __syncthreads();
#pragma unroll
    for (int k = 0; k < 16; ++k) {
      float a[8], b[4];
#pragma unroll
      for (int i = 0; i < 8; ++i) a[i] = As[k][ty * 8 + i];
#pragma unroll
      for (int j = 0; j < 4; ++j) b[j] = Bs[k][tx * 4 + j];
#pragma unroll
      for (int i = 0; i < 8; ++i)
#pragma unroll
        for (int j = 0; j < 4; ++j) acc[i][j] += a[i] * b[j];
    }
    __syncthreads();
  }
#pragma unroll
  for (int i = 0; i < 8; ++i) {
    int row = bm + ty * 8 + i;
    if (row >= M) continue;
#pragma unroll
    for (int j = 0; j < 4; ++j) {
      int col = bn + tx * 4 + j;
      if (col < N) C[(size_t)row * N + col] = acc[i][j];
    }
  }
}

// ---------------- GCN aggregation (CSR gather) ----------------
template <int F>
__global__ __launch_bounds__(256) void gcn_agg(const float* __restrict__ h,
                                               const int* __restrict__ row_start,
                                               const int* __restrict__ csr,
                                               const float* __restrict__ dinv,
                                               const float* __restrict__ bias,
                                               float* __restrict__ out, int n) {
  constexpr int NPB = 256 / F;
  int node = blockIdx.x * NPB + threadIdx.x / F;
  int f = threadIdx.x % F;
  if (node >= n) return;
  float di = dinv[node];
  float acc = h[(size_t)node * F + f] * di * di;   // self loop
  int s0 = row_start[node], s1 = row_start[node + 1];
  for (int e = s0; e < s1; ++e) {
    int s = csr[e];
    acc += di * dinv[s] * h[(size_t)s * F + f];
  }
  out[(size_t)node * F + f] = acc + bias[f];
}

// ---------------- BatchNorm (training stats) + leaky relu ----------------
template <int F>
__global__ __launch_bounds__(256) void bn_stats(const float* __restrict__ x,
                                                float* __restrict__ stats, int n) {
  constexpr int RSTEP = 256 / F;
  int col = threadIdx.x % F;
  int rsub = threadIdx.x / F;
  int r0 = blockIdx.x * 256;
  int rend = r0 + 256; if (rend > n) rend = n;
  float s = 0.f, ss = 0.f;
  for (int r = r0 + rsub; r < rend; r += RSTEP) {
    float v = x[(size_t)r * F + col];
    s += v; ss += v * v;
  }
  atomicAdd(&stats[col], s);
  atomicAdd(&stats[F + col], ss);
}

template <int F>
__global__ __launch_bounds__(256) void bn_lrelu(float* __restrict__ x,
                                                const float* __restrict__ stats,
                                                const float* __restrict__ gamma,
                                                const float* __restrict__ beta, int n) {
  int i = blockIdx.x * 256 + threadIdx.x;
  int total = n * F;
  if (i >= total) return;
  int col = i & (F - 1);
  const float inv_n = 1.0f / (float)n;
  float mean = stats[col] * inv_n;
  float var = stats[F + col] * inv_n - mean * mean;
  float sc = gamma[col] * rsqrtf(var + 1e-5f);
  float v = (x[i] - mean) * sc + beta[col];
  x[i] = v >= 0.f ? v : 0.01f * v;
}

// BN + lrelu writing bf16 (feeds next MFMA GEMM)
template <int F>
__global__ __launch_bounds__(256) void bn_lrelu_bf(const float* __restrict__ x,
                                                   const float* __restrict__ stats,
                                                   const float* __restrict__ gamma,
                                                   const float* __restrict__ beta,
                                                   ushort* __restrict__ out, int n) {
  int i = blockIdx.x * 256 + threadIdx.x;
  int total = n * F;
  if (i >= total) return;
  int col = i & (F - 1);
  const float inv_n = 1.0f / (float)n;
  float mean = stats[col] * inv_n;
  float var = stats[F + col] * inv_n - mean * mean;
  float sc = gamma[col] * rsqrtf(var + 1e-5f);
  float v = (x[i] - mean) * sc + beta[col];
  out[i] = f2bf(v >= 0.f ? v : 0.01f * v);
}

// ---------------- GAT ----------------
__global__ __launch_bounds__(256) void gat_scores(const float* __restrict__ hg,
                                                  const float* __restrict__ a_src,
                                                  const float* __restrict__ a_dst,
                                                  float* __restrict__ asc,
                                                  float* __restrict__ adc, int n) {
  int node = blockIdx.x;
  int head = threadIdx.x >> 6;
  int lane = threadIdx.x & 63;
  const float* row = hg + (size_t)node * 512 + head * 128;
  float v0 = row[lane], v1 = row[lane + 64];
  float s = v0 * a_src[head * 128 + lane] + v1 * a_src[head * 128 + lane + 64];
  float d = v0 * a_dst[head * 128 + lane] + v1 * a_dst[head * 128 + lane + 64];
#pragma unroll
  for (int off = 32; off > 0; off >>= 1) {
    s += __shfl_down(s, off);
    d += __shfl_down(d, off);
  }
  if (lane == 0) {
    asc[node * 4 + head] = s;
    adc[node * 4 + head] = d;
  }
}

__global__ __launch_bounds__(256) void gat_softmax(const int* __restrict__ row_start,
                                                   const int* __restrict__ csr,
                                                   const float* __restrict__ asc,
                                                   const float* __restrict__ adc,
                                                   float* __restrict__ alpha,
                                                   float* __restrict__ wself,
                                                   float* __restrict__ invden, int n) {
  int i = blockIdx.x * 256 + threadIdx.x;
  if (i >= 4 * n) return;
  int node = i >> 2, h = i & 3;
  int s0 = row_start[node], s1 = row_start[node + 1];
  float ad = adc[i];
  float eself = lrelu02(asc[i] + ad);
  float m = eself;
  for (int e = s0; e < s1; ++e) {
    float v = lrelu02(asc[csr[e] * 4 + h] + ad);
    m = fmaxf(m, v);
  }
  float ws = __expf(eself - m);
  wself[i] = ws;
  float den = ws;
  for (int e = s0; e < s1; ++e) {
    float v = __expf(lrelu02(asc[csr[e] * 4 + h] + ad) - m);
    alpha[(size_t)e * 4 + h] = v;
    den += v;
  }
  invden[i] = 1.f / (den + 1e-16f);
}

__global__ __launch_bounds__(128) void gat_agg(const float* __restrict__ hg,
                                               const int* __restrict__ row_start,
                                               const int* __restrict__ csr,
                                               const float* __restrict__ alpha,
                                               const float* __restrict__ wself,
                                               const float* __restrict__ invden,
                                               const float* __restrict__ gat_b,
                                               float* __restrict__ out, int n) {
  int node = blockIdx.x;
  int f = threadIdx.x;
  float id0 = invden[node * 4 + 0], id1 = invden[node * 4 + 1];
  float id2 = invden[node * 4 + 2], id3 = invden[node * 4 + 3];
  const float* hrow = hg + (size_t)node * 512;
  float acc = wself[node * 4 + 0] * id0 * hrow[f]
            + wself[node * 4 + 1] * id1 * hrow[128 + f]
            + wself[node * 4 + 2] * id2 * hrow[256 + f]
            + wself[node * 4 + 3] * id3 * hrow[384 + f];
  int s0 = row_start[node], s1 = row_start[node + 1];
  for (int e = s0; e < s1; ++e) {
    int s = csr[e];
    const float* srow = hg + (size_t)s * 512;
    float4 al = *reinterpret_cast<const float4*>(&alpha[(size_t)e * 4]);
    acc += al.x * id0 * srow[f] + al.y * id1 * srow[128 + f]
         + al.z * id2 * srow[256 + f] + al.w * id3 * srow[384 + f];
  }
  out[(size_t)node * 128 + f] = acc * 0.25f + gat_b[f];
}

// ---------------- FC head + log_softmax ----------------
__global__ __launch_bounds__(256) void head_kernel(const float* __restrict__ h,
                                                   const float* __restrict__ fw1,
                                                   const float* __restrict__ fb1,
                                                   const float* __restrict__ fw2,
                                                   const float* __restrict__ fb2,
                                                   float* __restrict__ out, int n) {
  int i = blockIdx.x * 256 + threadIdx.x;
  if (i >= n) return;
  float xr[16];
#pragma unroll
  for (int q = 0; q < 4; ++q) {
    float4 v = *reinterpret_cast<const float4*>(&h[(size_t)i * 16 + q * 4]);
    xr[q * 4 + 0] = v.x; xr[q * 4 + 1] = v.y; xr[q * 4 + 2] = v.z; xr[q * 4 + 3] = v.w;
  }
  float z[8];
#pragma unroll
  for (int j = 0; j < 8; ++j) z[j] = fb1[j];
#pragma unroll
  for (int k = 0; k < 16; ++k) {
    float a = xr[k];
#pragma unroll
    for (int j = 0; j < 8; ++j) z[j] += a * fw1[k * 8 + j];
  }
#pragma unroll
  for (int j = 0; j < 8; ++j) z[j] = lrelu01(z[j]);
  float l[3];
#pragma unroll
  for (int j = 0; j < 3; ++j) l[j] = fb2[j];
#pragma unroll
  for (int k = 0; k < 8; ++k) {
    float a = z[k];
#pragma unroll
    for (int j = 0; j < 3; ++j) l[j] += a * fw2[k * 3 + j];
  }
  float mx = fmaxf(l[0], fmaxf(l[1], l[2]));
  float se = __expf(l[0] - mx) + __expf(l[1] - mx) + __expf(l[2] - mx);
  float ls = __logf(se);
#pragma unroll
  for (int j = 0; j < 3; ++j) out[(size_t)i * 3 + j] = l[j] - mx - ls;
}

// ---------------- launch ----------------
extern "C" void kernel_launch(void* const* d_in, const int* in_sizes, int n_in,
                              void* d_out, int out_size, void* d_ws, size_t ws_size,
                              hipStream_t stream) {
  const float* x      = (const float*)d_in[0];
  const int*   ei     = (const int*)d_in[1];
  const int*   srcI   = ei;
  const int*   dstI   = ei + NE;
  const float* w1     = (const float*)d_in[2];
  const float* b1     = (const float*)d_in[3];
  const float* g1     = (const float*)d_in[4];
  const float* be1    = (const float*)d_in[5];
  const float* gat_w  = (const float*)d_in[6];
  const float* gat_as = (const float*)d_in[7];
  const float* gat_ad = (const float*)d_in[8];
  const float* gat_b  = (const float*)d_in[9];
  const float* g2     = (const float*)d_in[10];
  const float* be2    = (const float*)d_in[11];
  const float* w3     = (const float*)d_in[12];
  const float* b3     = (const float*)d_in[13];
  const float* g3     = (const float*)d_in[14];
  const float* be3    = (const float*)d_in[15];
  const float* w4     = (const float*)d_in[16];
  const float* b4     = (const float*)d_in[17];
  const float* g4     = (const float*)d_in[18];
  const float* be4    = (const float*)d_in[19];
  const float* w5     = (const float*)d_in[20];
  const float* b5     = (const float*)d_in[21];
  const float* g5     = (const float*)d_in[22];
  const float* be5    = (const float*)d_in[23];
  const float* fw1    = (const float*)d_in[24];
  const float* fb1    = (const float*)d_in[25];
  const float* fw2    = (const float*)d_in[26];
  const float* fb2    = (const float*)d_in[27];
  float* out = (float*)d_out;

  char* wsp = (char*)d_ws;
  size_t off = 0;
  auto alloc = [&](size_t bytes) -> void* {
    void* p = wsp + off;
    off += (bytes + 255) & ~(size_t)255;
    return p;
  };
  float*  bufA   = (float*)alloc((size_t)NN * 512 * 4);  // GEMM outputs (up to 512 wide)
  float*  bufB   = (float*)alloc((size_t)NN * 256 * 4);  // agg outputs / activations
  ushort* h1_bf  = (ushort*)alloc((size_t)NN * 256 * 2); // layer-1 activations bf16
  ushort* w1T    = (ushort*)alloc((size_t)256 * 256 * 2);
  ushort* gwT    = (ushort*)alloc((size_t)512 * 256 * 2);
  float*  dinv   = (float*)alloc((size_t)NN * 4);
  int*    counts = (int*)alloc((size_t)NN * 4);
  int*    cursor = (int*)alloc((size_t)NN * 4);
  int*    rstart = (int*)alloc((size_t)(NN + 4) * 4);
  int*    csr    = (int*)alloc((size_t)NE * 4);
  float*  asc    = (float*)alloc((size_t)NN * 4 * 4);
  float*  adc    = (float*)alloc((size_t)NN * 4 * 4);
  float*  wself  = (float*)alloc((size_t)NN * 4 * 4);
  float*  invden = (float*)alloc((size_t)NN * 4 * 4);
  float*  alpha  = (float*)alloc((size_t)NE * 4 * 4);
  float*  stats  = (float*)alloc(2048);
  // x_bf overlays the second half of bufA (dead during layer-1 GEMM, which
  // writes only the first NN*256 floats; overwritten later by GAT GEMM).
  ushort* x_bf   = (ushort*)(bufA + (size_t)NN * 256);

  const int egrid = (NE + 255) / 256;
  const int ngrid = (NN + 255) / 256;
  const int mblocks = (NN + 127) / 128;   // 391

  // CSR build (reused by all 5 propagation layers)
  hipMemsetAsync(counts, 0, (size_t)NN * 4, stream);
  hipMemsetAsync(cursor, 0, (size_t)NN * 4, stream);
  count_kernel<<<egrid, 256, 0, stream>>>(dstI, counts, NE);
  dinv_kernel<<<ngrid, 256, 0, stream>>>(counts, dinv, NN);
  scan_kernel<<<1, 1024, 0, stream>>>(counts, rstart, NN);
  fill_kernel<<<egrid, 256, 0, stream>>>(srcI, dstI, rstart, cursor, csr, NE);

  // bf16 conversions
  f32_to_bf16<<<(NN * 256 / 4 + 255) / 256, 256, 0, stream>>>(x, x_bf, NN * 256 / 4);
  transpose_bf<<<(256 * 256 + 255) / 256, 256, 0, stream>>>(w1, w1T, 256, 256);
  transpose_bf<<<(256 * 512 + 255) / 256, 256, 0, stream>>>(gat_w, gwT, 256, 512);

  // ---- Layer 1: GCN 256 -> 256 (MFMA) ----
  gemm_mfma<<<dim3(mblocks, 2), 256, 0, stream>>>(x_bf, w1T, bufA, NN, 256, 256);
  gcn_agg<256><<<NN, 256, 0, stream>>>(bufA, rstart, csr, dinv, b1, bufB, NN);
  hipMemsetAsync(stats, 0, 2048, stream);
  bn_stats<256><<<(NN + 255) / 256, 256, 0, stream>>>(bufB, stats, NN);
  bn_lrelu_bf<256><<<(NN * 256 + 255) / 256, 256, 0, stream>>>(bufB, stats, g1, be1, h1_bf, NN);

  // ---- Layer 2: GAT 256 -> 128 (4 heads, mean), GEMM via MFMA ----
  gemm_mfma<<<dim3(mblocks, 4), 256, 0, stream>>>(h1_bf, gwT, bufA, NN, 256, 512);
  gat_scores<<<NN, 256, 0, stream>>>(bufA, gat_as, gat_ad, asc, adc, NN);
  gat_softmax<<<(4 * NN + 255) / 256, 256, 0, stream>>>(rstart, csr, asc, adc, alpha, wself, invden, NN);
  gat_agg<<<NN, 128, 0, stream>>>(bufA, rstart, csr, alpha, wself, invden, gat_b, bufB, NN);
  hipMemsetAsync(stats, 0, 2048, stream);
  bn_stats<128><<<(NN + 255) / 256, 256, 0, stream>>>(bufB, stats, NN);
  bn_lrelu<128><<<(NN * 128 + 255) / 256, 256, 0, stream>>>(bufB, stats, g2, be2, NN);

  // ---- Layer 3: GCN 128 -> 64 ----
  gemm_tiled<<<dim3(mblocks, 1), 256, 0, stream>>>(bufB, w3, bufA, NN, 128, 64);
  gcn_agg<64><<<(NN + 3) / 4, 256, 0, stream>>>(bufA, rstart, csr, dinv, b3, bufB, NN);
  hipMemsetAsync(stats, 0, 2048, stream);
  bn_stats<64><<<(NN + 255) / 256, 256, 0, stream>>>(bufB, stats, NN);
  bn_lrelu<64><<<(NN * 64 + 255) / 256, 256, 0, stream>>>(bufB, stats, g3, be3, NN);

  // ---- Layer 4: GCN 64 -> 32 ----
  gemm_tiled<<<dim3(mblocks, 1), 256, 0, stream>>>(bufB, w4, bufA, NN, 64, 32);
  gcn_agg<32><<<(NN + 7) / 8, 256, 0, stream>>>(bufA, rstart, csr, dinv, b4, bufB, NN);
  hipMemsetAsync(stats, 0, 2048, stream);
  bn_stats<32><<<(NN + 255) / 256, 256, 0, stream>>>(bufB, stats, NN);
  bn_lrelu<32><<<(NN * 32 + 255) / 256, 256, 0, stream>>>(bufB, stats, g4, be4, NN);

  // ---- Layer 5: GCN 32 -> 16 ----
  gemm_tiled<<<dim3(mblocks, 1), 256, 0, stream>>>(bufB, w5, bufA, NN, 32, 16);
  gcn_agg<16><<<(NN + 15) / 16, 256, 0, stream>>>(bufA, rstart, csr, dinv, b5, bufB, NN);
  hipMemsetAsync(stats, 0, 2048, stream);
  bn_stats<16><<<(NN + 255) / 256, 256, 0, stream>>>(bufB, stats, NN);
  bn_lrelu<16><<<(NN * 16 + 255) / 256, 256, 0, stream>>>(bufB, stats, g5, be5, NN);

  // ---- FC head + log_softmax ----
  head_kernel<<<ngrid, 256, 0, stream>>>(bufB, fw1, fb1, fw2, fb2, out, NN);
}

// Round 3
// 882.791 us; speedup vs baseline: 1.4946x; 1.2509x over previous
//
#include <hip/hip_runtime.h>

#define NN 50000
#define NE 400000

typedef short bf16x8 __attribute__((ext_vector_type(8)));
typedef float f32x4 __attribute__((ext_vector_type(4)));

__device__ __forceinline__ float lrelu01(float v) { return v >= 0.f ? v : 0.01f * v; }
__device__ __forceinline__ float lrelu02(float v) { return v >= 0.f ? v : 0.2f * v; }

__device__ __forceinline__ ushort f2bf(float f) {
  union { float f; unsigned u; } v; v.f = f;
  unsigned u = v.u;
  return (ushort)((u + 0x7FFFu + ((u >> 16) & 1u)) >> 16);
}
__device__ __forceinline__ float bf2f(ushort u) {
  union { unsigned u; float f; } v; v.u = ((unsigned)u) << 16;
  return v.f;
}

// ---------------- bf16 conversion helpers ----------------
__global__ void f32_to_bf16(const float* __restrict__ in, ushort* __restrict__ out, int n4) {
  int i = blockIdx.x * 256 + threadIdx.x;
  if (i >= n4) return;
  float4 v = *reinterpret_cast<const float4*>(&in[(size_t)i * 4]);
  ushort4 o;
  o.x = f2bf(v.x); o.y = f2bf(v.y); o.z = f2bf(v.z); o.w = f2bf(v.w);
  *reinterpret_cast<ushort4*>(&out[(size_t)i * 4]) = o;
}

// W [K][N] fp32 -> WT [N][K] bf16
__global__ void transpose_bf(const float* __restrict__ W, ushort* __restrict__ WT, int K, int N) {
  int i = blockIdx.x * 256 + threadIdx.x;
  if (i >= K * N) return;
  int k = i / N, c = i % N;
  WT[(size_t)c * K + k] = f2bf(W[i]);
}

// ---------------- CSR build ----------------
__global__ void count_kernel(const int* __restrict__ dst, int* __restrict__ counts, int e) {
  int i = blockIdx.x * 256 + threadIdx.x;
  if (i < e) atomicAdd(&counts[dst[i]], 1);
}

__global__ void dinv_kernel(const int* __restrict__ counts, float* __restrict__ dinv, int n) {
  int i = blockIdx.x * 256 + threadIdx.x;
  if (i < n) dinv[i] = rsqrtf((float)counts[i] + 1.0f);
}

__global__ __launch_bounds__(1024) void scan_kernel(const int* __restrict__ counts,
                                                    int* __restrict__ row_start, int n) {
  __shared__ int part[1024];
  int tid = threadIdx.x;
  int chunk = (n + 1023) >> 10;
  int lo = tid * chunk;
  int hi = lo + chunk; if (hi > n) hi = n;
  int s = 0;
  for (int i = lo; i < hi; ++i) s += counts[i];
  part[tid] = s;
  __syncthreads();
  for (int off = 1; off < 1024; off <<= 1) {
    int v = 0;
    if (tid >= off) v = part[tid - off];
    __syncthreads();
    part[tid] += v;
    __syncthreads();
  }
  int running = (tid == 0) ? 0 : part[tid - 1];
  for (int i = lo; i < hi; ++i) { row_start[i] = running; running += counts[i]; }
  if (tid == 1023) row_start[n] = part[1023];
}

__global__ void fill_kernel(const int* __restrict__ src, const int* __restrict__ dst,
                            const int* __restrict__ row_start, int* __restrict__ cursor,
                            int* __restrict__ csr, int e) {
  int i = blockIdx.x * 256 + threadIdx.x;
  if (i >= e) return;
  int d = dst[i];
  int pos = atomicAdd(&cursor[d], 1);
  csr[row_start[d] + pos] = src[i];
}

// ---------------- bf16 MFMA GEMM, 128x128 tile, bf16 out, optional row scale ----------------
// C[M,N] bf16 = (A[M,K]bf16 @ BT[N,K]^T) * rowscale[row]; K%32==0, N%128==0.
__global__ __launch_bounds__(256) void gemm_mfma(const ushort* __restrict__ A,
                                                 const ushort* __restrict__ BT,
                                                 ushort* __restrict__ C,
                                                 int M, int K, int N,
                                                 const float* __restrict__ rowscale) {
  __shared__ ushort As[128][40];
  __shared__ ushort Bs[128][40];
  const int tid = threadIdx.x;
  const int bm = blockIdx.x * 128;
  const int bn = blockIdx.y * 128;
  const int wave = tid >> 6, lane = tid & 63;
  const int wr = (wave >> 1) * 64;
  const int wc = (wave & 1) * 64;
  const int lr = lane & 15;
  const int lk = (lane >> 4) * 8;

  f32x4 acc[4][4];
#pragma unroll
  for (int m = 0; m < 4; ++m)
#pragma unroll
    for (int n = 0; n < 4; ++n)
#pragma unroll
      for (int q = 0; q < 4; ++q) acc[m][n][q] = 0.f;

  for (int k0 = 0; k0 < K; k0 += 32) {
#pragma unroll
    for (int it = 0; it < 2; ++it) {
      int s = tid + it * 256;
      int r = s >> 2;
      int c = (s & 3) * 8;
      int grow = bm + r; if (grow >= M) grow = M - 1;
      int4 v = *reinterpret_cast<const int4*>(&A[(size_t)grow * K + k0 + c]);
      *reinterpret_cast<int4*>(&As[r][c]) = v;
    }
#pragma unroll
    for (int it = 0; it < 2; ++it) {
      int s = tid + it * 256;
      int r = s >> 2;
      int c = (s & 3) * 8;
      int4 v = *reinterpret_cast<const int4*>(&BT[(size_t)(bn + r) * K + k0 + c]);
      *reinterpret_cast<int4*>(&Bs[r][c]) = v;
    }
    __syncthreads();

    bf16x8 af[4], bfr[4];
#pragma unroll
    for (int m = 0; m < 4; ++m)
      af[m] = *reinterpret_cast<const bf16x8*>(&As[wr + m * 16 + lr][lk]);
#pragma unroll
    for (int n = 0; n < 4; ++n)
      bfr[n] = *reinterpret_cast<const bf16x8*>(&Bs[wc + n * 16 + lr][lk]);
#pragma unroll
    for (int m = 0; m < 4; ++m)
#pragma unroll
      for (int n = 0; n < 4; ++n)
        acc[m][n] = __builtin_amdgcn_mfma_f32_16x16x32_bf16(af[m], bfr[n], acc[m][n], 0, 0, 0);
    __syncthreads();
  }

  const int rbase = (lane >> 4) * 4;
  const int cbase = lane & 15;
#pragma unroll
  for (int m = 0; m < 4; ++m) {
#pragma unroll
    for (int q = 0; q < 4; ++q) {
      int row = bm + wr + m * 16 + rbase + q;
      if (row >= M) continue;
      float sc = rowscale ? rowscale[row] : 1.f;
#pragma unroll
      for (int n = 0; n < 4; ++n) {
        int col = bn + wc + n * 16 + cbase;
        C[(size_t)row * N + col] = f2bf(acc[m][n][q] * sc);
      }
    }
  }
}

// ---------------- small-N MFMA GEMM: 128xTN tile (TN=N), bf16 out, row scale ----------------
template <int TN>
__global__ __launch_bounds__(256) void gemm_mfma_n(const ushort* __restrict__ A,
                                                   const ushort* __restrict__ BT,
                                                   ushort* __restrict__ C,
                                                   int M, int K,
                                                   const float* __restrict__ rowscale) {
  __shared__ ushort As[128][40];
  __shared__ ushort Bs[TN][40];
  const int tid = threadIdx.x;
  const int bm = blockIdx.x * 128;
  const int wave = tid >> 6, lane = tid & 63;
  const int wr = wave * 32;          // wave handles rows [wr, wr+32)
  const int lr = lane & 15;
  const int lk = (lane >> 4) * 8;
  constexpr int NF = TN / 16;

  f32x4 acc[2][NF];
#pragma unroll
  for (int m = 0; m < 2; ++m)
#pragma unroll
    for (int n = 0; n < NF; ++n)
#pragma unroll
      for (int q = 0; q < 4; ++q) acc[m][n][q] = 0.f;

  for (int k0 = 0; k0 < K; k0 += 32) {
#pragma unroll
    for (int it = 0; it < 2; ++it) {
      int s = tid + it * 256;
      int r = s >> 2;
      int c = (s & 3) * 8;
      int grow = bm + r; if (grow >= M) grow = M - 1;
      int4 v = *reinterpret_cast<const int4*>(&A[(size_t)grow * K + k0 + c]);
      *reinterpret_cast<int4*>(&As[r][c]) = v;
    }
    if (tid < TN * 4) {
      int r = tid >> 2;
      int c = (tid & 3) * 8;
      int4 v = *reinterpret_cast<const int4*>(&BT[(size_t)r * K + k0 + c]);
      *reinterpret_cast<int4*>(&Bs[r][c]) = v;
    }
    __syncthreads();

    bf16x8 af[2], bfr[NF];
#pragma unroll
    for (int m = 0; m < 2; ++m)
      af[m] = *reinterpret_cast<const bf16x8*>(&As[wr + m * 16 + lr][lk]);
#pragma unroll
    for (int n = 0; n < NF; ++n)
      bfr[n] = *reinterpret_cast<const bf16x8*>(&Bs[n * 16 + lr][lk]);
#pragma unroll
    for (int m = 0; m < 2; ++m)
#pragma unroll
      for (int n = 0; n < NF; ++n)
        acc[m][n] = __builtin_amdgcn_mfma_f32_16x16x32_bf16(af[m], bfr[n], acc[m][n], 0, 0, 0);
    __syncthreads();
  }

  const int rbase = (lane >> 4) * 4;
  const int cbase = lane & 15;
#pragma unroll
  for (int m = 0; m < 2; ++m) {
#pragma unroll
    for (int q = 0; q < 4; ++q) {
      int row = bm + wr + m * 16 + rbase + q;
      if (row >= M) continue;
      float sc = rowscale ? rowscale[row] : 1.f;
#pragma unroll
      for (int n = 0; n < NF; ++n) {
        int col = n * 16 + cbase;
        C[(size_t)row * TN + col] = f2bf(acc[m][n][q] * sc);
      }
    }
  }
}

// ---------------- GCN aggregation (bf16 gather, dinv pre-folded into h) ----------------
// h rows are already scaled by dinv[row]; out = dinv[node] * (h[node] + sum_src h[src])
template <int F>
__global__ __launch_bounds__(256) void gcn_agg_bf(const ushort* __restrict__ h,
                                                  const int* __restrict__ row_start,
                                                  const int* __restrict__ csr,
                                                  const float* __restrict__ dinv,
                                                  float* __restrict__ out, int n) {
  constexpr int TPN = F / 4;          // threads per node (4 features each)
  constexpr int NPB = 256 / TPN;
  int node = blockIdx.x * NPB + threadIdx.x / TPN;
  int f4 = (threadIdx.x % TPN) * 4;
  if (node >= n) return;
  float di = dinv[node];
  ushort4 sv = *reinterpret_cast<const ushort4*>(&h[(size_t)node * F + f4]);
  float a0 = bf2f(sv.x), a1 = bf2f(sv.y), a2 = bf2f(sv.z), a3 = bf2f(sv.w);
  int s0 = row_start[node], s1 = row_start[node + 1];
  for (int e = s0; e < s1; ++e) {
    int s = csr[e];
    ushort4 v = *reinterpret_cast<const ushort4*>(&h[(size_t)s * F + f4]);
    a0 += bf2f(v.x); a1 += bf2f(v.y); a2 += bf2f(v.z); a3 += bf2f(v.w);
  }
  float4 o = make_float4(a0 * di, a1 * di, a2 * di, a3 * di);
  *reinterpret_cast<float4*>(&out[(size_t)node * F + f4]) = o;
}

// ---------------- BatchNorm (training stats) + leaky relu ----------------
template <int F>
__global__ __launch_bounds__(256) void bn_stats(const float* __restrict__ x,
                                                float* __restrict__ stats, int n) {
  constexpr int RSTEP = 256 / F;
  int col = threadIdx.x % F;
  int rsub = threadIdx.x / F;
  int r0 = blockIdx.x * 256;
  int rend = r0 + 256; if (rend > n) rend = n;
  float s = 0.f, ss = 0.f;
  for (int r = r0 + rsub; r < rend; r += RSTEP) {
    float v = x[(size_t)r * F + col];
    s += v; ss += v * v;
  }
  atomicAdd(&stats[col], s);
  atomicAdd(&stats[F + col], ss);
}

template <int F>
__global__ __launch_bounds__(256) void bn_lrelu(float* __restrict__ x,
                                                const float* __restrict__ stats,
                                                const float* __restrict__ gamma,
                                                const float* __restrict__ beta, int n) {
  int i = blockIdx.x * 256 + threadIdx.x;
  int total = n * F;
  if (i >= total) return;
  int col = i & (F - 1);
  const float inv_n = 1.0f / (float)n;
  float mean = stats[col] * inv_n;
  float var = stats[F + col] * inv_n - mean * mean;
  float sc = gamma[col] * rsqrtf(var + 1e-5f);
  float v = (x[i] - mean) * sc + beta[col];
  x[i] = v >= 0.f ? v : 0.01f * v;
}

template <int F>
__global__ __launch_bounds__(256) void bn_lrelu_bf(const float* __restrict__ x,
                                                   const float* __restrict__ stats,
                                                   const float* __restrict__ gamma,
                                                   const float* __restrict__ beta,
                                                   ushort* __restrict__ out, int n) {
  int i = blockIdx.x * 256 + threadIdx.x;
  int total = n * F;
  if (i >= total) return;
  int col = i & (F - 1);
  const float inv_n = 1.0f / (float)n;
  float mean = stats[col] * inv_n;
  float var = stats[F + col] * inv_n - mean * mean;
  float sc = gamma[col] * rsqrtf(var + 1e-5f);
  float v = (x[i] - mean) * sc + beta[col];
  out[i] = f2bf(v >= 0.f ? v : 0.01f * v);
}

// ---------------- GAT ----------------
// per-node per-head attention scores from bf16 hg
__global__ __launch_bounds__(256) void gat_scores_bf(const ushort* __restrict__ hg,
                                                     const float* __restrict__ a_src,
                                                     const float* __restrict__ a_dst,
                                                     float* __restrict__ asc,
                                                     float* __restrict__ adc, int n) {
  int node = blockIdx.x;
  int head = threadIdx.x >> 6;
  int lane = threadIdx.x & 63;
  ushort2 v = *reinterpret_cast<const ushort2*>(&hg[(size_t)node * 512 + head * 128 + lane * 2]);
  float v0 = bf2f(v.x), v1 = bf2f(v.y);
  float s = v0 * a_src[head * 128 + lane * 2] + v1 * a_src[head * 128 + lane * 2 + 1];
  float d = v0 * a_dst[head * 128 + lane * 2] + v1 * a_dst[head * 128 + lane * 2 + 1];
#pragma unroll
  for (int off = 32; off > 0; off >>= 1) {
    s += __shfl_down(s, off);
    d += __shfl_down(d, off);
  }
  if (lane == 0) {
    asc[node * 4 + head] = s;
    adc[node * 4 + head] = d;
  }
}

// per (node,head): pass1 gathers scores -> alpha + max; pass2 reads alpha sequentially
__global__ __launch_bounds__(256) void gat_softmax(const int* __restrict__ row_start,
                                                   const int* __restrict__ csr,
                                                   const float* __restrict__ asc,
                                                   const float* __restrict__ adc,
                                                   float* __restrict__ alpha,
                                                   float* __restrict__ wself,
                                                   float* __restrict__ invden, int n) {
  int i = blockIdx.x * 256 + threadIdx.x;
  if (i >= 4 * n) return;
  int node = i >> 2, h = i & 3;
  int s0 = row_start[node], s1 = row_start[node + 1];
  float ad = adc[i];
  float eself = lrelu02(asc[i] + ad);
  float m = eself;
  for (int e = s0; e < s1; ++e) {
    float v = lrelu02(asc[csr[e] * 4 + h] + ad);
    alpha[(size_t)e * 4 + h] = v;
    m = fmaxf(m, v);
  }
  float ws = __expf(eself - m);
  wself[i] = ws;
  float den = ws;
  for (int e = s0; e < s1; ++e) {
    float w = __expf(alpha[(size_t)e * 4 + h] - m);
    alpha[(size_t)e * 4 + h] = w;
    den += w;
  }
  invden[i] = 1.f / (den + 1e-16f);
}

// aggregate alpha * h (bf16 gather), mean over 4 heads
__global__ __launch_bounds__(256) void gat_agg_bf(const ushort* __restrict__ hg,
                                                  const int* __restrict__ row_start,
                                                  const int* __restrict__ csr,
                                                  const float* __restrict__ alpha,
                                                  const float* __restrict__ wself,
                                                  const float* __restrict__ invden,
                                                  float* __restrict__ out, int n) {
  int node = blockIdx.x * 4 + (threadIdx.x >> 6);
  int lane = threadIdx.x & 63;
  if (node >= n) return;
  float4 idv = *reinterpret_cast<const float4*>(&invden[node * 4]);
  float4 wsv = *reinterpret_cast<const float4*>(&wself[node * 4]);
  float id0 = idv.x, id1 = idv.y, id2 = idv.z, id3 = idv.w;
  int f2 = lane * 2;
  const ushort* hrow = hg + (size_t)node * 512;
  float a0 = 0.f, a1 = 0.f;
  {
    ushort2 v0 = *reinterpret_cast<const ushort2*>(&hrow[f2]);
    ushort2 v1 = *reinterpret_cast<const ushort2*>(&hrow[128 + f2]);
    ushort2 v2 = *reinterpret_cast<const ushort2*>(&hrow[256 + f2]);
    ushort2 v3 = *reinterpret_cast<const ushort2*>(&hrow[384 + f2]);
    float c0 = wsv.x * id0, c1 = wsv.y * id1, c2 = wsv.z * id2, c3 = wsv.w * id3;
    a0 = c0 * bf2f(v0.x) + c1 * bf2f(v1.x) + c2 * bf2f(v2.x) + c3 * bf2f(v3.x);
    a1 = c0 * bf2f(v0.y) + c1 * bf2f(v1.y) + c2 * bf2f(v2.y) + c3 * bf2f(v3.y);
  }
  int s0 = row_start[node], s1 = row_start[node + 1];
  for (int e = s0; e < s1; ++e) {
    int s = csr[e];
    const ushort* srow = hg + (size_t)s * 512;
    float4 al = *reinterpret_cast<const float4*>(&alpha[(size_t)e * 4]);
    ushort2 v0 = *reinterpret_cast<const ushort2*>(&srow[f2]);
    ushort2 v1 = *reinterpret_cast<const ushort2*>(&srow[128 + f2]);
    ushort2 v2 = *reinterpret_cast<const ushort2*>(&srow[256 + f2]);
    ushort2 v3 = *reinterpret_cast<const ushort2*>(&srow[384 + f2]);
    float c0 = al.x * id0, c1 = al.y * id1, c2 = al.z * id2, c3 = al.w * id3;
    a0 += c0 * bf2f(v0.x) + c1 * bf2f(v1.x) + c2 * bf2f(v2.x) + c3 * bf2f(v3.x);
    a1 += c0 * bf2f(v0.y) + c1 * bf2f(v1.y) + c2 * bf2f(v2.y) + c3 * bf2f(v3.y);
  }
  out[(size_t)node * 128 + f2] = a0 * 0.25f;
  out[(size_t)node * 128 + f2 + 1] = a1 * 0.25f;
}

// ---------------- FC head + log_softmax ----------------
__global__ __launch_bounds__(256) void head_kernel(const float* __restrict__ h,
                                                   const float* __restrict__ fw1,
                                                   const float* __restrict__ fb1,
                                                   const float* __restrict__ fw2,
                                                   const float* __restrict__ fb2,
                                                   float* __restrict__ out, int n) {
  int i = blockIdx.x * 256 + threadIdx.x;
  if (i >= n) return;
  float xr[16];
#pragma unroll
  for (int q = 0; q < 4; ++q) {
    float4 v = *reinterpret_cast<const float4*>(&h[(size_t)i * 16 + q * 4]);
    xr[q * 4 + 0] = v.x; xr[q * 4 + 1] = v.y; xr[q * 4 + 2] = v.z; xr[q * 4 + 3] = v.w;
  }
  float z[8];
#pragma unroll
  for (int j = 0; j < 8; ++j) z[j] = fb1[j];
#pragma unroll
  for (int k = 0; k < 16; ++k) {
    float a = xr[k];
#pragma unroll
    for (int j = 0; j < 8; ++j) z[j] += a * fw1[k * 8 + j];
  }
#pragma unroll
  for (int j = 0; j < 8; ++j) z[j] = lrelu01(z[j]);
  float l[3];
#pragma unroll
  for (int j = 0; j < 3; ++j) l[j] = fb2[j];
#pragma unroll
  for (int k = 0; k < 8; ++k) {
    float a = z[k];
#pragma unroll
    for (int j = 0; j < 3; ++j) l[j] += a * fw2[k * 3 + j];
  }
  float mx = fmaxf(l[0], fmaxf(l[1], l[2]));
  float se = __expf(l[0] - mx) + __expf(l[1] - mx) + __expf(l[2] - mx);
  float ls = __logf(se);
#pragma unroll
  for (int j = 0; j < 3; ++j) out[(size_t)i * 3 + j] = l[j] - mx - ls;
}

// ---------------- launch ----------------
extern "C" void kernel_launch(void* const* d_in, const int* in_sizes, int n_in,
                              void* d_out, int out_size, void* d_ws, size_t ws_size,
                              hipStream_t stream) {
  const float* x      = (const float*)d_in[0];
  const int*   ei     = (const int*)d_in[1];
  const int*   srcI   = ei;
  const int*   dstI   = ei + NE;
  const float* w1     = (const float*)d_in[2];
  const float* g1     = (const float*)d_in[4];
  const float* be1    = (const float*)d_in[5];
  const float* gat_w  = (const float*)d_in[6];
  const float* gat_as = (const float*)d_in[7];
  const float* gat_ad = (const float*)d_in[8];
  const float* g2     = (const float*)d_in[10];
  const float* be2    = (const float*)d_in[11];
  const float* w3     = (const float*)d_in[12];
  const float* g3     = (const float*)d_in[14];
  const float* be3    = (const float*)d_in[15];
  const float* w4     = (const float*)d_in[16];
  const float* g4     = (const float*)d_in[18];
  const float* be4    = (const float*)d_in[19];
  const float* w5     = (const float*)d_in[20];
  const float* g5     = (const float*)d_in[22];
  const float* be5    = (const float*)d_in[23];
  const float* fw1    = (const float*)d_in[24];
  const float* fb1    = (const float*)d_in[25];
  const float* fw2    = (const float*)d_in[26];
  const float* fb2    = (const float*)d_in[27];
  // b1/b3/b4/b5/gat_b (d_in[3,13,17,21,9]) are per-column constants followed by
  // BatchNorm -> exactly cancelled by mean subtraction; dropped.
  float* out = (float*)d_out;

  char* wsp = (char*)d_ws;
  size_t off = 0;
  auto alloc = [&](size_t bytes) -> void* {
    void* p = wsp + off;
    off += (bytes + 255) & ~(size_t)255;
    return p;
  };
  ushort* hw_bf  = (ushort*)alloc((size_t)NN * 512 * 2); // GEMM outputs (<=512 wide) bf16
  float*  bufB   = (float*)alloc((size_t)NN * 256 * 4);  // agg outputs fp32
  ushort* x_bf   = (ushort*)alloc((size_t)NN * 256 * 2);
  ushort* h1_bf  = (ushort*)alloc((size_t)NN * 256 * 2);
  ushort* h2_bf  = (ushort*)alloc((size_t)NN * 128 * 2);
  ushort* h3_bf  = (ushort*)alloc((size_t)NN * 64 * 2);
  ushort* h4_bf  = (ushort*)alloc((size_t)NN * 32 * 2);
  ushort* w1T    = (ushort*)alloc((size_t)256 * 256 * 2);
  ushort* gwT    = (ushort*)alloc((size_t)512 * 256 * 2);
  ushort* w3T    = (ushort*)alloc((size_t)64 * 128 * 2);
  ushort* w4T    = (ushort*)alloc((size_t)32 * 64 * 2);
  ushort* w5T    = (ushort*)alloc((size_t)16 * 32 * 2);
  float*  dinv   = (float*)alloc((size_t)NN * 4);
  int*    counts = (int*)alloc((size_t)NN * 4);
  int*    cursor = (int*)alloc((size_t)NN * 4);
  int*    rstart = (int*)alloc((size_t)(NN + 4) * 4);
  int*    csr    = (int*)alloc((size_t)NE * 4);
  float*  asc    = (float*)alloc((size_t)NN * 4 * 4);
  float*  adc    = (float*)alloc((size_t)NN * 4 * 4);
  float*  wself  = (float*)alloc((size_t)NN * 4 * 4);
  float*  invden = (float*)alloc((size_t)NN * 4 * 4);
  float*  alpha  = (float*)alloc((size_t)NE * 4 * 4);
  float*  stats  = (float*)alloc(2048);

  const int egrid = (NE + 255) / 256;
  const int ngrid = (NN + 255) / 256;
  const int mblocks = (NN + 127) / 128;   // 391

  // CSR build
  hipMemsetAsync(counts, 0, (size_t)NN * 4, stream);
  hipMemsetAsync(cursor, 0, (size_t)NN * 4, stream);
  count_kernel<<<egrid, 256, 0, stream>>>(dstI, counts, NE);
  dinv_kernel<<<ngrid, 256, 0, stream>>>(counts, dinv, NN);
  scan_kernel<<<1, 1024, 0, stream>>>(counts, rstart, NN);
  fill_kernel<<<egrid, 256, 0, stream>>>(srcI, dstI, rstart, cursor, csr, NE);

  // conversions
  f32_to_bf16<<<(NN * 256 / 4 + 255) / 256, 256, 0, stream>>>(x, x_bf, NN * 256 / 4);
  transpose_bf<<<(256 * 256 + 255) / 256, 256, 0, stream>>>(w1, w1T, 256, 256);
  transpose_bf<<<(256 * 512 + 255) / 256, 256, 0, stream>>>(gat_w, gwT, 256, 512);
  transpose_bf<<<(128 * 64 + 255) / 256, 256, 0, stream>>>(w3, w3T, 128, 64);
  transpose_bf<<<(64 * 32 + 255) / 256, 256, 0, stream>>>(w4, w4T, 64, 32);
  transpose_bf<<<(32 * 16 + 255) / 256, 256, 0, stream>>>(w5, w5T, 32, 16);

  // ---- Layer 1: GCN 256 -> 256 ----
  gemm_mfma<<<dim3(mblocks, 2), 256, 0, stream>>>(x_bf, w1T, hw_bf, NN, 256, 256, dinv);
  gcn_agg_bf<256><<<(NN + 3) / 4, 256, 0, stream>>>(hw_bf, rstart, csr, dinv, bufB, NN);
  hipMemsetAsync(stats, 0, 2048, stream);
  bn_stats<256><<<(NN + 255) / 256, 256, 0, stream>>>(bufB, stats, NN);
  bn_lrelu_bf<256><<<(NN * 256 + 255) / 256, 256, 0, stream>>>(bufB, stats, g1, be1, h1_bf, NN);

  // ---- Layer 2: GAT 256 -> 128 (4 heads, mean) ----
  gemm_mfma<<<dim3(mblocks, 4), 256, 0, stream>>>(h1_bf, gwT, hw_bf, NN, 256, 512, nullptr);
  gat_scores_bf<<<NN, 256, 0, stream>>>(hw_bf, gat_as, gat_ad, asc, adc, NN);
  gat_softmax<<<(4 * NN + 255) / 256, 256, 0, stream>>>(rstart, csr, asc, adc, alpha, wself, invden, NN);
  gat_agg_bf<<<(NN + 3) / 4, 256, 0, stream>>>(hw_bf, rstart, csr, alpha, wself, invden, bufB, NN);
  hipMemsetAsync(stats, 0, 2048, stream);
  bn_stats<128><<<(NN + 255) / 256, 256, 0, stream>>>(bufB, stats, NN);
  bn_lrelu_bf<128><<<(NN * 128 + 255) / 256, 256, 0, stream>>>(bufB, stats, g2, be2, h2_bf, NN);

  // ---- Layer 3: GCN 128 -> 64 ----
  gemm_mfma_n<64><<<mblocks, 256, 0, stream>>>(h2_bf, w3T, hw_bf, NN, 128, dinv);
  gcn_agg_bf<64><<<(NN + 15) / 16, 256, 0, stream>>>(hw_bf, rstart, csr, dinv, bufB, NN);
  hipMemsetAsync(stats, 0, 2048, stream);
  bn_stats<64><<<(NN + 255) / 256, 256, 0, stream>>>(bufB, stats, NN);
  bn_lrelu_bf<64><<<(NN * 64 + 255) / 256, 256, 0, stream>>>(bufB, stats, g3, be3, h3_bf, NN);

  // ---- Layer 4: GCN 64 -> 32 ----
  gemm_mfma_n<32><<<mblocks, 256, 0, stream>>>(h3_bf, w4T, hw_bf, NN, 64, dinv);
  gcn_agg_bf<32><<<(NN + 31) / 32, 256, 0, stream>>>(hw_bf, rstart, csr, dinv, bufB, NN);
  hipMemsetAsync(stats, 0, 2048, stream);
  bn_stats<32><<<(NN + 255) / 256, 256, 0, stream>>>(bufB, stats, NN);
  bn_lrelu_bf<32><<<(NN * 32 + 255) / 256, 256, 0, stream>>>(bufB, stats, g4, be4, h4_bf, NN);

  // ---- Layer 5: GCN 32 -> 16 ----
  gemm_mfma_n<16><<<mblocks, 256, 0, stream>>>(h4_bf, w5T, hw_bf, NN, 32, dinv);
  gcn_agg_bf<16><<<(NN + 63) / 64, 256, 0, stream>>>(hw_bf, rstart, csr, dinv, bufB, NN);
  hipMemsetAsync(stats, 0, 2048, stream);
  bn_stats<16><<<(NN + 255) / 256, 256, 0, stream>>>(bufB, stats, NN);
  bn_lrelu<16><<<(NN * 16 + 255) / 256, 256, 0, stream>>>(bufB, stats, g5, be5, NN);

  // ---- FC head + log_softmax ----
  head_kernel<<<ngrid, 256, 0, stream>>>(bufB, fw1, fb1, fw2, fb2, out, NN);
}

// Round 4
// 805.266 us; speedup vs baseline: 1.6385x; 1.0963x over previous
//
#include <hip/hip_runtime.h>

#define NN 50000
#define NE 400000

typedef short bf16x8 __attribute__((ext_vector_type(8)));
typedef float f32x4 __attribute__((ext_vector_type(4)));

__device__ __forceinline__ float lrelu01(float v) { return v >= 0.f ? v : 0.01f * v; }
__device__ __forceinline__ float lrelu02(float v) { return v >= 0.f ? v : 0.2f * v; }

__device__ __forceinline__ ushort f2bf(float f) {
  union { float f; unsigned u; } v; v.f = f;
  unsigned u = v.u;
  return (ushort)((u + 0x7FFFu + ((u >> 16) & 1u)) >> 16);
}
__device__ __forceinline__ float bf2f(ushort u) {
  union { unsigned u; float f; } v; v.u = ((unsigned)u) << 16;
  return v.f;
}

// ---------------- bf16 conversion helpers ----------------
__global__ void f32_to_bf16(const float* __restrict__ in, ushort* __restrict__ out, int n4) {
  int i = blockIdx.x * 256 + threadIdx.x;
  if (i >= n4) return;
  float4 v = *reinterpret_cast<const float4*>(&in[(size_t)i * 4]);
  ushort4 o;
  o.x = f2bf(v.x); o.y = f2bf(v.y); o.z = f2bf(v.z); o.w = f2bf(v.w);
  *reinterpret_cast<ushort4*>(&out[(size_t)i * 4]) = o;
}

// W [K][N] fp32 -> WT [N][K] bf16
__global__ void transpose_bf(const float* __restrict__ W, ushort* __restrict__ WT, int K, int N) {
  int i = blockIdx.x * 256 + threadIdx.x;
  if (i >= K * N) return;
  int k = i / N, c = i % N;
  WT[(size_t)c * K + k] = f2bf(W[i]);
}

// ---------------- CSR build ----------------
__global__ void count_kernel(const int* __restrict__ dst, int* __restrict__ counts, int e) {
  int i = blockIdx.x * 256 + threadIdx.x;
  if (i < e) atomicAdd(&counts[dst[i]], 1);
}

__global__ void dinv_kernel(const int* __restrict__ counts, float* __restrict__ dinv, int n) {
  int i = blockIdx.x * 256 + threadIdx.x;
  if (i < n) dinv[i] = rsqrtf((float)counts[i] + 1.0f);
}

__global__ __launch_bounds__(1024) void scan_kernel(const int* __restrict__ counts,
                                                    int* __restrict__ row_start, int n) {
  __shared__ int part[1024];
  int tid = threadIdx.x;
  int chunk = (n + 1023) >> 10;
  int lo = tid * chunk;
  int hi = lo + chunk; if (hi > n) hi = n;
  int s = 0;
  for (int i = lo; i < hi; ++i) s += counts[i];
  part[tid] = s;
  __syncthreads();
  for (int off = 1; off < 1024; off <<= 1) {
    int v = 0;
    if (tid >= off) v = part[tid - off];
    __syncthreads();
    part[tid] += v;
    __syncthreads();
  }
  int running = (tid == 0) ? 0 : part[tid - 1];
  for (int i = lo; i < hi; ++i) { row_start[i] = running; running += counts[i]; }
  if (tid == 1023) row_start[n] = part[1023];
}

__global__ void fill_kernel(const int* __restrict__ src, const int* __restrict__ dst,
                            const int* __restrict__ row_start, int* __restrict__ cursor,
                            int* __restrict__ csr, int e) {
  int i = blockIdx.x * 256 + threadIdx.x;
  if (i >= e) return;
  int d = dst[i];
  int pos = atomicAdd(&cursor[d], 1);
  csr[row_start[d] + pos] = src[i];
}

// ---------------- bf16 MFMA GEMM, 128x128 tile, bf16 out, optional row scale ----------------
__global__ __launch_bounds__(256) void gemm_mfma(const ushort* __restrict__ A,
                                                 const ushort* __restrict__ BT,
                                                 ushort* __restrict__ C,
                                                 int M, int K, int N,
                                                 const float* __restrict__ rowscale) {
  __shared__ ushort As[128][40];
  __shared__ ushort Bs[128][40];
  const int tid = threadIdx.x;
  const int bm = blockIdx.x * 128;
  const int bn = blockIdx.y * 128;
  const int wave = tid >> 6, lane = tid & 63;
  const int wr = (wave >> 1) * 64;
  const int wc = (wave & 1) * 64;
  const int lr = lane & 15;
  const int lk = (lane >> 4) * 8;

  f32x4 acc[4][4];
#pragma unroll
  for (int m = 0; m < 4; ++m)
#pragma unroll
    for (int n = 0; n < 4; ++n)
#pragma unroll
      for (int q = 0; q < 4; ++q) acc[m][n][q] = 0.f;

  for (int k0 = 0; k0 < K; k0 += 32) {
#pragma unroll
    for (int it = 0; it < 2; ++it) {
      int s = tid + it * 256;
      int r = s >> 2;
      int c = (s & 3) * 8;
      int grow = bm + r; if (grow >= M) grow = M - 1;
      int4 v = *reinterpret_cast<const int4*>(&A[(size_t)grow * K + k0 + c]);
      *reinterpret_cast<int4*>(&As[r][c]) = v;
    }
#pragma unroll
    for (int it = 0; it < 2; ++it) {
      int s = tid + it * 256;
      int r = s >> 2;
      int c = (s & 3) * 8;
      int4 v = *reinterpret_cast<const int4*>(&BT[(size_t)(bn + r) * K + k0 + c]);
      *reinterpret_cast<int4*>(&Bs[r][c]) = v;
    }
    __syncthreads();

    bf16x8 af[4], bfr[4];
#pragma unroll
    for (int m = 0; m < 4; ++m)
      af[m] = *reinterpret_cast<const bf16x8*>(&As[wr + m * 16 + lr][lk]);
#pragma unroll
    for (int n = 0; n < 4; ++n)
      bfr[n] = *reinterpret_cast<const bf16x8*>(&Bs[wc + n * 16 + lr][lk]);
#pragma unroll
    for (int m = 0; m < 4; ++m)
#pragma unroll
      for (int n = 0; n < 4; ++n)
        acc[m][n] = __builtin_amdgcn_mfma_f32_16x16x32_bf16(af[m], bfr[n], acc[m][n], 0, 0, 0);
    __syncthreads();
  }

  const int rbase = (lane >> 4) * 4;
  const int cbase = lane & 15;
#pragma unroll
  for (int m = 0; m < 4; ++m) {
#pragma unroll
    for (int q = 0; q < 4; ++q) {
      int row = bm + wr + m * 16 + rbase + q;
      if (row >= M) continue;
      float sc = rowscale ? rowscale[row] : 1.f;
#pragma unroll
      for (int n = 0; n < 4; ++n) {
        int col = bn + wc + n * 16 + cbase;
        C[(size_t)row * N + col] = f2bf(acc[m][n][q] * sc);
      }
    }
  }
}

// ---------------- small-N MFMA GEMM: 128xTN tile, bf16 out, row scale ----------------
template <int TN>
__global__ __launch_bounds__(256) void gemm_mfma_n(const ushort* __restrict__ A,
                                                   const ushort* __restrict__ BT,
                                                   ushort* __restrict__ C,
                                                   int M, int K,
                                                   const float* __restrict__ rowscale) {
  __shared__ ushort As[128][40];
  __shared__ ushort Bs[TN][40];
  const int tid = threadIdx.x;
  const int bm = blockIdx.x * 128;
  const int wave = tid >> 6, lane = tid & 63;
  const int wr = wave * 32;
  const int lr = lane & 15;
  const int lk = (lane >> 4) * 8;
  constexpr int NF = TN / 16;

  f32x4 acc[2][NF];
#pragma unroll
  for (int m = 0; m < 2; ++m)
#pragma unroll
    for (int n = 0; n < NF; ++n)
#pragma unroll
      for (int q = 0; q < 4; ++q) acc[m][n][q] = 0.f;

  for (int k0 = 0; k0 < K; k0 += 32) {
#pragma unroll
    for (int it = 0; it < 2; ++it) {
      int s = tid + it * 256;
      int r = s >> 2;
      int c = (s & 3) * 8;
      int grow = bm + r; if (grow >= M) grow = M - 1;
      int4 v = *reinterpret_cast<const int4*>(&A[(size_t)grow * K + k0 + c]);
      *reinterpret_cast<int4*>(&As[r][c]) = v;
    }
    if (tid < TN * 4) {
      int r = tid >> 2;
      int c = (tid & 3) * 8;
      int4 v = *reinterpret_cast<const int4*>(&BT[(size_t)r * K + k0 + c]);
      *reinterpret_cast<int4*>(&Bs[r][c]) = v;
    }
    __syncthreads();

    bf16x8 af[2], bfr[NF];
#pragma unroll
    for (int m = 0; m < 2; ++m)
      af[m] = *reinterpret_cast<const bf16x8*>(&As[wr + m * 16 + lr][lk]);
#pragma unroll
    for (int n = 0; n < NF; ++n)
      bfr[n] = *reinterpret_cast<const bf16x8*>(&Bs[n * 16 + lr][lk]);
#pragma unroll
    for (int m = 0; m < 2; ++m)
#pragma unroll
      for (int n = 0; n < NF; ++n)
        acc[m][n] = __builtin_amdgcn_mfma_f32_16x16x32_bf16(af[m], bfr[n], acc[m][n], 0, 0, 0);
    __syncthreads();
  }

  const int rbase = (lane >> 4) * 4;
  const int cbase = lane & 15;
#pragma unroll
  for (int m = 0; m < 2; ++m) {
#pragma unroll
    for (int q = 0; q < 4; ++q) {
      int row = bm + wr + m * 16 + rbase + q;
      if (row >= M) continue;
      float sc = rowscale ? rowscale[row] : 1.f;
#pragma unroll
      for (int n = 0; n < NF; ++n) {
        int col = n * 16 + cbase;
        C[(size_t)row * TN + col] = f2bf(acc[m][n][q] * sc);
      }
    }
  }
}

// ---------------- GCN aggregation (bf16 gather, dinv pre-folded into h) ----------------
template <int F>
__global__ __launch_bounds__(256) void gcn_agg_bf(const ushort* __restrict__ h,
                                                  const int* __restrict__ row_start,
                                                  const int* __restrict__ csr,
                                                  const float* __restrict__ dinv,
                                                  float* __restrict__ out, int n) {
  constexpr int TPN = F / 4;
  constexpr int NPB = 256 / TPN;
  int node = blockIdx.x * NPB + threadIdx.x / TPN;
  int f4 = (threadIdx.x % TPN) * 4;
  if (node >= n) return;
  float di = dinv[node];
  ushort4 sv = *reinterpret_cast<const ushort4*>(&h[(size_t)node * F + f4]);
  float a0 = bf2f(sv.x), a1 = bf2f(sv.y), a2 = bf2f(sv.z), a3 = bf2f(sv.w);
  int s0 = row_start[node], s1 = row_start[node + 1];
  for (int e = s0; e < s1; ++e) {
    int s = csr[e];
    ushort4 v = *reinterpret_cast<const ushort4*>(&h[(size_t)s * F + f4]);
    a0 += bf2f(v.x); a1 += bf2f(v.y); a2 += bf2f(v.z); a3 += bf2f(v.w);
  }
  float4 o = make_float4(a0 * di, a1 * di, a2 * di, a3 * di);
  *reinterpret_cast<float4*>(&out[(size_t)node * F + f4]) = o;
}

// ---------------- BatchNorm stats: two-stage, NO global atomics ----------------
// Stage 1: each block reduces 64 rows into one partial row of 2F floats.
template <int F>
__global__ __launch_bounds__(256) void bn_stats_part(const float* __restrict__ x,
                                                     float* __restrict__ partials, int n) {
  __shared__ float lss[256], lsq[256];
  constexpr int RSTEP = 256 / F;
  int col = threadIdx.x % F;
  int rsub = threadIdx.x / F;
  int r0 = blockIdx.x * 64;
  int rend = r0 + 64; if (rend > n) rend = n;
  float s = 0.f, ss = 0.f;
  for (int r = r0 + rsub; r < rend; r += RSTEP) {
    float v = x[(size_t)r * F + col];
    s += v; ss += v * v;
  }
  lss[threadIdx.x] = s; lsq[threadIdx.x] = ss;
  __syncthreads();
#pragma unroll
  for (int half = 128; half >= 1; half >>= 1) {
    if (half < F) break;
    if (threadIdx.x < half) {
      lss[threadIdx.x] += lss[threadIdx.x + half];
      lsq[threadIdx.x] += lsq[threadIdx.x + half];
    }
    __syncthreads();
  }
  if (threadIdx.x < F) {
    partials[(size_t)blockIdx.x * 2 * F + threadIdx.x] = lss[threadIdx.x];
    partials[(size_t)blockIdx.x * 2 * F + F + threadIdx.x] = lsq[threadIdx.x];
  }
}

// Stage 2: stats[c] = sum over blocks of partials[b][c], c in [0, 2F)
__global__ __launch_bounds__(512) void bn_stats_reduce(const float* __restrict__ partials,
                                                       float* __restrict__ stats,
                                                       int nb, int twoF) {
  int c = threadIdx.x;
  if (c >= twoF) return;
  float s0 = 0.f, s1 = 0.f, s2 = 0.f, s3 = 0.f;
  int b = 0;
  for (; b + 3 < nb; b += 4) {
    s0 += partials[(size_t)(b + 0) * twoF + c];
    s1 += partials[(size_t)(b + 1) * twoF + c];
    s2 += partials[(size_t)(b + 2) * twoF + c];
    s3 += partials[(size_t)(b + 3) * twoF + c];
  }
  for (; b < nb; ++b) s0 += partials[(size_t)b * twoF + c];
  stats[c] = (s0 + s1) + (s2 + s3);
}

template <int F>
__global__ __launch_bounds__(256) void bn_lrelu(float* __restrict__ x,
                                                const float* __restrict__ stats,
                                                const float* __restrict__ gamma,
                                                const float* __restrict__ beta, int n) {
  int i = blockIdx.x * 256 + threadIdx.x;
  int total = n * F;
  if (i >= total) return;
  int col = i & (F - 1);
  const float inv_n = 1.0f / (float)n;
  float mean = stats[col] * inv_n;
  float var = stats[F + col] * inv_n - mean * mean;
  float sc = gamma[col] * rsqrtf(var + 1e-5f);
  float v = (x[i] - mean) * sc + beta[col];
  x[i] = v >= 0.f ? v : 0.01f * v;
}

template <int F>
__global__ __launch_bounds__(256) void bn_lrelu_bf(const float* __restrict__ x,
                                                   const float* __restrict__ stats,
                                                   const float* __restrict__ gamma,
                                                   const float* __restrict__ beta,
                                                   ushort* __restrict__ out, int n) {
  int i = blockIdx.x * 256 + threadIdx.x;
  int total = n * F;
  if (i >= total) return;
  int col = i & (F - 1);
  const float inv_n = 1.0f / (float)n;
  float mean = stats[col] * inv_n;
  float var = stats[F + col] * inv_n - mean * mean;
  float sc = gamma[col] * rsqrtf(var + 1e-5f);
  float v = (x[i] - mean) * sc + beta[col];
  out[i] = f2bf(v >= 0.f ? v : 0.01f * v);
}

// ---------------- GAT ----------------
__global__ __launch_bounds__(256) void gat_scores_bf(const ushort* __restrict__ hg,
                                                     const float* __restrict__ a_src,
                                                     const float* __restrict__ a_dst,
                                                     float* __restrict__ asc,
                                                     float* __restrict__ adc, int n) {
  int node = blockIdx.x;
  int head = threadIdx.x >> 6;
  int lane = threadIdx.x & 63;
  ushort2 v = *reinterpret_cast<const ushort2*>(&hg[(size_t)node * 512 + head * 128 + lane * 2]);
  float v0 = bf2f(v.x), v1 = bf2f(v.y);
  float s = v0 * a_src[head * 128 + lane * 2] + v1 * a_src[head * 128 + lane * 2 + 1];
  float d = v0 * a_dst[head * 128 + lane * 2] + v1 * a_dst[head * 128 + lane * 2 + 1];
#pragma unroll
  for (int off = 32; off > 0; off >>= 1) {
    s += __shfl_down(s, off);
    d += __shfl_down(d, off);
  }
  if (lane == 0) {
    asc[node * 4 + head] = s;
    adc[node * 4 + head] = d;
  }
}

__global__ __launch_bounds__(256) void gat_softmax(const int* __restrict__ row_start,
                                                   const int* __restrict__ csr,
                                                   const float* __restrict__ asc,
                                                   const float* __restrict__ adc,
                                                   float* __restrict__ alpha,
                                                   float* __restrict__ wself,
                                                   float* __restrict__ invden, int n) {
  int i = blockIdx.x * 256 + threadIdx.x;
  if (i >= 4 * n) return;
  int node = i >> 2, h = i & 3;
  int s0 = row_start[node], s1 = row_start[node + 1];
  float ad = adc[i];
  float eself = lrelu02(asc[i] + ad);
  float m = eself;
  for (int e = s0; e < s1; ++e) {
    float v = lrelu02(asc[csr[e] * 4 + h] + ad);
    alpha[(size_t)e * 4 + h] = v;
    m = fmaxf(m, v);
  }
  float ws = __expf(eself - m);
  wself[i] = ws;
  float den = ws;
  for (int e = s0; e < s1; ++e) {
    float w = __expf(alpha[(size_t)e * 4 + h] - m);
    alpha[(size_t)e * 4 + h] = w;
    den += w;
  }
  invden[i] = 1.f / (den + 1e-16f);
}

__global__ __launch_bounds__(256) void gat_agg_bf(const ushort* __restrict__ hg,
                                                  const int* __restrict__ row_start,
                                                  const int* __restrict__ csr,
                                                  const float* __restrict__ alpha,
                                                  const float* __restrict__ wself,
                                                  const float* __restrict__ invden,
                                                  float* __restrict__ out, int n) {
  int node = blockIdx.x * 4 + (threadIdx.x >> 6);
  int lane = threadIdx.x & 63;
  if (node >= n) return;
  float4 idv = *reinterpret_cast<const float4*>(&invden[node * 4]);
  float4 wsv = *reinterpret_cast<const float4*>(&wself[node * 4]);
  float id0 = idv.x, id1 = idv.y, id2 = idv.z, id3 = idv.w;
  int f2 = lane * 2;
  const ushort* hrow = hg + (size_t)node * 512;
  float a0 = 0.f, a1 = 0.f;
  {
    ushort2 v0 = *reinterpret_cast<const ushort2*>(&hrow[f2]);
    ushort2 v1 = *reinterpret_cast<const ushort2*>(&hrow[128 + f2]);
    ushort2 v2 = *reinterpret_cast<const ushort2*>(&hrow[256 + f2]);
    ushort2 v3 = *reinterpret_cast<const ushort2*>(&hrow[384 + f2]);
    float c0 = wsv.x * id0, c1 = wsv.y * id1, c2 = wsv.z * id2, c3 = wsv.w * id3;
    a0 = c0 * bf2f(v0.x) + c1 * bf2f(v1.x) + c2 * bf2f(v2.x) + c3 * bf2f(v3.x);
    a1 = c0 * bf2f(v0.y) + c1 * bf2f(v1.y) + c2 * bf2f(v2.y) + c3 * bf2f(v3.y);
  }
  int s0 = row_start[node], s1 = row_start[node + 1];
  for (int e = s0; e < s1; ++e) {
    int s = csr[e];
    const ushort* srow = hg + (size_t)s * 512;
    float4 al = *reinterpret_cast<const float4*>(&alpha[(size_t)e * 4]);
    ushort2 v0 = *reinterpret_cast<const ushort2*>(&srow[f2]);
    ushort2 v1 = *reinterpret_cast<const ushort2*>(&srow[128 + f2]);
    ushort2 v2 = *reinterpret_cast<const ushort2*>(&srow[256 + f2]);
    ushort2 v3 = *reinterpret_cast<const ushort2*>(&srow[384 + f2]);
    float c0 = al.x * id0, c1 = al.y * id1, c2 = al.z * id2, c3 = al.w * id3;
    a0 += c0 * bf2f(v0.x) + c1 * bf2f(v1.x) + c2 * bf2f(v2.x) + c3 * bf2f(v3.x);
    a1 += c0 * bf2f(v0.y) + c1 * bf2f(v1.y) + c2 * bf2f(v2.y) + c3 * bf2f(v3.y);
  }
  out[(size_t)node * 128 + f2] = a0 * 0.25f;
  out[(size_t)node * 128 + f2 + 1] = a1 * 0.25f;
}

// ---------------- FC head + log_softmax ----------------
__global__ __launch_bounds__(256) void head_kernel(const float* __restrict__ h,
                                                   const float* __restrict__ fw1,
                                                   const float* __restrict__ fb1,
                                                   const float* __restrict__ fw2,
                                                   const float* __restrict__ fb2,
                                                   float* __restrict__ out, int n) {
  int i = blockIdx.x * 256 + threadIdx.x;
  if (i >= n) return;
  float xr[16];
#pragma unroll
  for (int q = 0; q < 4; ++q) {
    float4 v = *reinterpret_cast<const float4*>(&h[(size_t)i * 16 + q * 4]);
    xr[q * 4 + 0] = v.x; xr[q * 4 + 1] = v.y; xr[q * 4 + 2] = v.z; xr[q * 4 + 3] = v.w;
  }
  float z[8];
#pragma unroll
  for (int j = 0; j < 8; ++j) z[j] = fb1[j];
#pragma unroll
  for (int k = 0; k < 16; ++k) {
    float a = xr[k];
#pragma unroll
    for (int j = 0; j < 8; ++j) z[j] += a * fw1[k * 8 + j];
  }
#pragma unroll
  for (int j = 0; j < 8; ++j) z[j] = lrelu01(z[j]);
  float l[3];
#pragma unroll
  for (int j = 0; j < 3; ++j) l[j] = fb2[j];
#pragma unroll
  for (int k = 0; k < 8; ++k) {
    float a = z[k];
#pragma unroll
    for (int j = 0; j < 3; ++j) l[j] += a * fw2[k * 3 + j];
  }
  float mx = fmaxf(l[0], fmaxf(l[1], l[2]));
  float se = __expf(l[0] - mx) + __expf(l[1] - mx) + __expf(l[2] - mx);
  float ls = __logf(se);
#pragma unroll
  for (int j = 0; j < 3; ++j) out[(size_t)i * 3 + j] = l[j] - mx - ls;
}

// ---------------- launch ----------------
extern "C" void kernel_launch(void* const* d_in, const int* in_sizes, int n_in,
                              void* d_out, int out_size, void* d_ws, size_t ws_size,
                              hipStream_t stream) {
  const float* x      = (const float*)d_in[0];
  const int*   ei     = (const int*)d_in[1];
  const int*   srcI   = ei;
  const int*   dstI   = ei + NE;
  const float* w1     = (const float*)d_in[2];
  const float* g1     = (const float*)d_in[4];
  const float* be1    = (const float*)d_in[5];
  const float* gat_w  = (const float*)d_in[6];
  const float* gat_as = (const float*)d_in[7];
  const float* gat_ad = (const float*)d_in[8];
  const float* g2     = (const float*)d_in[10];
  const float* be2    = (const float*)d_in[11];
  const float* w3     = (const float*)d_in[12];
  const float* g3     = (const float*)d_in[14];
  const float* be3    = (const float*)d_in[15];
  const float* w4     = (const float*)d_in[16];
  const float* g4     = (const float*)d_in[18];
  const float* be4    = (const float*)d_in[19];
  const float* w5     = (const float*)d_in[20];
  const float* g5     = (const float*)d_in[22];
  const float* be5    = (const float*)d_in[23];
  const float* fw1    = (const float*)d_in[24];
  const float* fb1    = (const float*)d_in[25];
  const float* fw2    = (const float*)d_in[26];
  const float* fb2    = (const float*)d_in[27];
  // b1/b3/b4/b5/gat_b are per-column constants followed by BatchNorm ->
  // exactly cancelled by mean subtraction; dropped.
  float* out = (float*)d_out;

  char* wsp = (char*)d_ws;
  size_t off = 0;
  auto alloc = [&](size_t bytes) -> void* {
    void* p = wsp + off;
    off += (bytes + 255) & ~(size_t)255;
    return p;
  };
  ushort* hw_bf  = (ushort*)alloc((size_t)NN * 512 * 2);
  float*  bufB   = (float*)alloc((size_t)NN * 256 * 4);
  ushort* x_bf   = (ushort*)alloc((size_t)NN * 256 * 2);
  ushort* h1_bf  = (ushort*)alloc((size_t)NN * 256 * 2);
  ushort* h2_bf  = (ushort*)alloc((size_t)NN * 128 * 2);
  ushort* h3_bf  = (ushort*)alloc((size_t)NN * 64 * 2);
  ushort* h4_bf  = (ushort*)alloc((size_t)NN * 32 * 2);
  ushort* w1T    = (ushort*)alloc((size_t)256 * 256 * 2);
  ushort* gwT    = (ushort*)alloc((size_t)512 * 256 * 2);
  ushort* w3T    = (ushort*)alloc((size_t)64 * 128 * 2);
  ushort* w4T    = (ushort*)alloc((size_t)32 * 64 * 2);
  ushort* w5T    = (ushort*)alloc((size_t)16 * 32 * 2);
  float*  dinv   = (float*)alloc((size_t)NN * 4);
  int*    counts = (int*)alloc((size_t)NN * 4);
  int*    cursor = (int*)alloc((size_t)NN * 4);
  int*    rstart = (int*)alloc((size_t)(NN + 4) * 4);
  int*    csr    = (int*)alloc((size_t)NE * 4);
  float*  asc    = (float*)alloc((size_t)NN * 4 * 4);
  float*  adc    = (float*)alloc((size_t)NN * 4 * 4);
  float*  wself  = (float*)alloc((size_t)NN * 4 * 4);
  float*  invden = (float*)alloc((size_t)NN * 4 * 4);
  float*  alpha  = (float*)alloc((size_t)NE * 4 * 4);
  float*  stats  = (float*)alloc(2048);
  const int PB = (NN + 63) / 64;          // 782 stat partial blocks
  float*  partials = (float*)alloc((size_t)PB * 512 * 4);

  const int egrid = (NE + 255) / 256;
  const int ngrid = (NN + 255) / 256;
  const int mblocks = (NN + 127) / 128;   // 391

  // CSR build
  hipMemsetAsync(counts, 0, (size_t)NN * 4, stream);
  hipMemsetAsync(cursor, 0, (size_t)NN * 4, stream);
  count_kernel<<<egrid, 256, 0, stream>>>(dstI, counts, NE);
  dinv_kernel<<<ngrid, 256, 0, stream>>>(counts, dinv, NN);
  scan_kernel<<<1, 1024, 0, stream>>>(counts, rstart, NN);
  fill_kernel<<<egrid, 256, 0, stream>>>(srcI, dstI, rstart, cursor, csr, NE);

  // conversions
  f32_to_bf16<<<(NN * 256 / 4 + 255) / 256, 256, 0, stream>>>(x, x_bf, NN * 256 / 4);
  transpose_bf<<<(256 * 256 + 255) / 256, 256, 0, stream>>>(w1, w1T, 256, 256);
  transpose_bf<<<(256 * 512 + 255) / 256, 256, 0, stream>>>(gat_w, gwT, 256, 512);
  transpose_bf<<<(128 * 64 + 255) / 256, 256, 0, stream>>>(w3, w3T, 128, 64);
  transpose_bf<<<(64 * 32 + 255) / 256, 256, 0, stream>>>(w4, w4T, 64, 32);
  transpose_bf<<<(32 * 16 + 255) / 256, 256, 0, stream>>>(w5, w5T, 32, 16);

  // ---- Layer 1: GCN 256 -> 256 ----
  gemm_mfma<<<dim3(mblocks, 2), 256, 0, stream>>>(x_bf, w1T, hw_bf, NN, 256, 256, dinv);
  gcn_agg_bf<256><<<(NN + 3) / 4, 256, 0, stream>>>(hw_bf, rstart, csr, dinv, bufB, NN);
  bn_stats_part<256><<<PB, 256, 0, stream>>>(bufB, partials, NN);
  bn_stats_reduce<<<1, 512, 0, stream>>>(partials, stats, PB, 512);
  bn_lrelu_bf<256><<<(NN * 256 + 255) / 256, 256, 0, stream>>>(bufB, stats, g1, be1, h1_bf, NN);

  // ---- Layer 2: GAT 256 -> 128 (4 heads, mean) ----
  gemm_mfma<<<dim3(mblocks, 4), 256, 0, stream>>>(h1_bf, gwT, hw_bf, NN, 256, 512, nullptr);
  gat_scores_bf<<<NN, 256, 0, stream>>>(hw_bf, gat_as, gat_ad, asc, adc, NN);
  gat_softmax<<<(4 * NN + 255) / 256, 256, 0, stream>>>(rstart, csr, asc, adc, alpha, wself, invden, NN);
  gat_agg_bf<<<(NN + 3) / 4, 256, 0, stream>>>(hw_bf, rstart, csr, alpha, wself, invden, bufB, NN);
  bn_stats_part<128><<<PB, 256, 0, stream>>>(bufB, partials, NN);
  bn_stats_reduce<<<1, 512, 0, stream>>>(partials, stats, PB, 256);
  bn_lrelu_bf<128><<<(NN * 128 + 255) / 256, 256, 0, stream>>>(bufB, stats, g2, be2, h2_bf, NN);

  // ---- Layer 3: GCN 128 -> 64 ----
  gemm_mfma_n<64><<<mblocks, 256, 0, stream>>>(h2_bf, w3T, hw_bf, NN, 128, dinv);
  gcn_agg_bf<64><<<(NN + 15) / 16, 256, 0, stream>>>(hw_bf, rstart, csr, dinv, bufB, NN);
  bn_stats_part<64><<<PB, 256, 0, stream>>>(bufB, partials, NN);
  bn_stats_reduce<<<1, 512, 0, stream>>>(partials, stats, PB, 128);
  bn_lrelu_bf<64><<<(NN * 64 + 255) / 256, 256, 0, stream>>>(bufB, stats, g3, be3, h3_bf, NN);

  // ---- Layer 4: GCN 64 -> 32 ----
  gemm_mfma_n<32><<<mblocks, 256, 0, stream>>>(h3_bf, w4T, hw_bf, NN, 64, dinv);
  gcn_agg_bf<32><<<(NN + 31) / 32, 256, 0, stream>>>(hw_bf, rstart, csr, dinv, bufB, NN);
  bn_stats_part<32><<<PB, 256, 0, stream>>>(bufB, partials, NN);
  bn_stats_reduce<<<1, 512, 0, stream>>>(partials, stats, PB, 64);
  bn_lrelu_bf<32><<<(NN * 32 + 255) / 256, 256, 0, stream>>>(bufB, stats, g4, be4, h4_bf, NN);

  // ---- Layer 5: GCN 32 -> 16 ----
  gemm_mfma_n<16><<<mblocks, 256, 0, stream>>>(h4_bf, w5T, hw_bf, NN, 32, dinv);
  gcn_agg_bf<16><<<(NN + 63) / 64, 256, 0, stream>>>(hw_bf, rstart, csr, dinv, bufB, NN);
  bn_stats_part<16><<<PB, 256, 0, stream>>>(bufB, partials, NN);
  bn_stats_reduce<<<1, 512, 0, stream>>>(partials, stats, PB, 32);
  bn_lrelu<16><<<(NN * 16 + 255) / 256, 256, 0, stream>>>(bufB, stats, g5, be5, NN);

  // ---- FC head + log_softmax ----
  head_kernel<<<ngrid, 256, 0, stream>>>(bufB, fw1, fb1, fw2, fb2, out, NN);
}

// Round 5
// 736.483 us; speedup vs baseline: 1.7916x; 1.0934x over previous
//
#include <hip/hip_runtime.h>

#define NN 50000
#define NE 400000

typedef short bf16x8 __attribute__((ext_vector_type(8)));
typedef float f32x4 __attribute__((ext_vector_type(4)));

__device__ __forceinline__ float lrelu01(float v) { return v >= 0.f ? v : 0.01f * v; }
__device__ __forceinline__ float lrelu02(float v) { return v >= 0.f ? v : 0.2f * v; }

__device__ __forceinline__ ushort f2bf(float f) {
  union { float f; unsigned u; } v; v.f = f;
  unsigned u = v.u;
  return (ushort)((u + 0x7FFFu + ((u >> 16) & 1u)) >> 16);
}
__device__ __forceinline__ float bf2f(ushort u) {
  union { unsigned u; float f; } v; v.u = ((unsigned)u) << 16;
  return v.f;
}

// ---------------- bf16 conversion helpers ----------------
__global__ void f32_to_bf16(const float* __restrict__ in, ushort* __restrict__ out, int n4) {
  int i = blockIdx.x * 256 + threadIdx.x;
  if (i >= n4) return;
  float4 v = *reinterpret_cast<const float4*>(&in[(size_t)i * 4]);
  ushort4 o;
  o.x = f2bf(v.x); o.y = f2bf(v.y); o.z = f2bf(v.z); o.w = f2bf(v.w);
  *reinterpret_cast<ushort4*>(&out[(size_t)i * 4]) = o;
}

// W [K][N] fp32 -> WT [N][K] bf16
__global__ void transpose_bf(const float* __restrict__ W, ushort* __restrict__ WT, int K, int N) {
  int i = blockIdx.x * 256 + threadIdx.x;
  if (i >= K * N) return;
  int k = i / N, c = i % N;
  WT[(size_t)c * K + k] = f2bf(W[i]);
}

// ---------------- CSR build ----------------
__global__ void count_kernel(const int* __restrict__ dst, int* __restrict__ counts, int e) {
  int i = blockIdx.x * 256 + threadIdx.x;
  if (i < e) atomicAdd(&counts[dst[i]], 1);
}

// stage 1: per-block sum of counts (+ fused dinv)
__global__ __launch_bounds__(256) void block_count_sum(const int* __restrict__ counts,
                                                       int* __restrict__ bsum,
                                                       float* __restrict__ dinv, int n) {
  int i = blockIdx.x * 256 + threadIdx.x;
  int c = (i < n) ? counts[i] : 0;
  if (i < n) dinv[i] = rsqrtf((float)c + 1.0f);
  int s = c;
#pragma unroll
  for (int off = 32; off > 0; off >>= 1) s += __shfl_down(s, off);
  __shared__ int ws[4];
  if ((threadIdx.x & 63) == 0) ws[threadIdx.x >> 6] = s;
  __syncthreads();
  if (threadIdx.x == 0) bsum[blockIdx.x] = ws[0] + ws[1] + ws[2] + ws[3];
}

// stage 2: exclusive scan of block sums (nb <= 256), single block
__global__ __launch_bounds__(256) void scan_bsum(int* __restrict__ bsum, int nb) {
  __shared__ int sh[256];
  int v = (threadIdx.x < nb) ? bsum[threadIdx.x] : 0;
  sh[threadIdx.x] = v;
  __syncthreads();
  for (int off = 1; off < 256; off <<= 1) {
    int t = (threadIdx.x >= off) ? sh[threadIdx.x - off] : 0;
    __syncthreads();
    sh[threadIdx.x] += t;
    __syncthreads();
  }
  if (threadIdx.x < nb) bsum[threadIdx.x] = sh[threadIdx.x] - v;  // exclusive
}

// stage 3: per-block exclusive scan + base -> row_start
__global__ __launch_bounds__(256) void row_start_kernel(const int* __restrict__ counts,
                                                        const int* __restrict__ bsum,
                                                        int* __restrict__ row_start, int n) {
  __shared__ int sh[256];
  int i = blockIdx.x * 256 + threadIdx.x;
  int c = (i < n) ? counts[i] : 0;
  sh[threadIdx.x] = c;
  __syncthreads();
  for (int off = 1; off < 256; off <<= 1) {
    int t = (threadIdx.x >= off) ? sh[threadIdx.x - off] : 0;
    __syncthreads();
    sh[threadIdx.x] += t;
    __syncthreads();
  }
  int incl = sh[threadIdx.x];
  int base = bsum[blockIdx.x];
  if (i < n) row_start[i] = base + incl - c;
  if (i == n - 1) row_start[n] = base + incl;
}

__global__ void fill_kernel(const int* __restrict__ src, const int* __restrict__ dst,
                            const int* __restrict__ row_start, int* __restrict__ cursor,
                            int* __restrict__ csr, int e) {
  int i = blockIdx.x * 256 + threadIdx.x;
  if (i >= e) return;
  int d = dst[i];
  int pos = atomicAdd(&cursor[d], 1);
  csr[row_start[d] + pos] = src[i];
}

// ---------------- bf16 MFMA GEMM, 128x128 tile, bf16 out, optional row scale ----------------
__global__ __launch_bounds__(256) void gemm_mfma(const ushort* __restrict__ A,
                                                 const ushort* __restrict__ BT,
                                                 ushort* __restrict__ C,
                                                 int M, int K, int N,
                                                 const float* __restrict__ rowscale) {
  __shared__ ushort As[128][40];
  __shared__ ushort Bs[128][40];
  const int tid = threadIdx.x;
  const int bm = blockIdx.x * 128;
  const int bn = blockIdx.y * 128;
  const int wave = tid >> 6, lane = tid & 63;
  const int wr = (wave >> 1) * 64;
  const int wc = (wave & 1) * 64;
  const int lr = lane & 15;
  const int lk = (lane >> 4) * 8;

  f32x4 acc[4][4];
#pragma unroll
  for (int m = 0; m < 4; ++m)
#pragma unroll
    for (int n = 0; n < 4; ++n)
#pragma unroll
      for (int q = 0; q < 4; ++q) acc[m][n][q] = 0.f;

  for (int k0 = 0; k0 < K; k0 += 32) {
#pragma unroll
    for (int it = 0; it < 2; ++it) {
      int s = tid + it * 256;
      int r = s >> 2;
      int c = (s & 3) * 8;
      int grow = bm + r; if (grow >= M) grow = M - 1;
      int4 v = *reinterpret_cast<const int4*>(&A[(size_t)grow * K + k0 + c]);
      *reinterpret_cast<int4*>(&As[r][c]) = v;
    }
#pragma unroll
    for (int it = 0; it < 2; ++it) {
      int s = tid + it * 256;
      int r = s >> 2;
      int c = (s & 3) * 8;
      int4 v = *reinterpret_cast<const int4*>(&BT[(size_t)(bn + r) * K + k0 + c]);
      *reinterpret_cast<int4*>(&Bs[r][c]) = v;
    }
    __syncthreads();

    bf16x8 af[4], bfr[4];
#pragma unroll
    for (int m = 0; m < 4; ++m)
      af[m] = *reinterpret_cast<const bf16x8*>(&As[wr + m * 16 + lr][lk]);
#pragma unroll
    for (int n = 0; n < 4; ++n)
      bfr[n] = *reinterpret_cast<const bf16x8*>(&Bs[wc + n * 16 + lr][lk]);
#pragma unroll
    for (int m = 0; m < 4; ++m)
#pragma unroll
      for (int n = 0; n < 4; ++n)
        acc[m][n] = __builtin_amdgcn_mfma_f32_16x16x32_bf16(af[m], bfr[n], acc[m][n], 0, 0, 0);
    __syncthreads();
  }

  const int rbase = (lane >> 4) * 4;
  const int cbase = lane & 15;
#pragma unroll
  for (int m = 0; m < 4; ++m) {
#pragma unroll
    for (int q = 0; q < 4; ++q) {
      int row = bm + wr + m * 16 + rbase + q;
      if (row >= M) continue;
      float sc = rowscale ? rowscale[row] : 1.f;
#pragma unroll
      for (int n = 0; n < 4; ++n) {
        int col = bn + wc + n * 16 + cbase;
        C[(size_t)row * N + col] = f2bf(acc[m][n][q] * sc);
      }
    }
  }
}

// ---------------- small-N MFMA GEMM: 128xTN tile, bf16 out, row scale ----------------
template <int TN>
__global__ __launch_bounds__(256) void gemm_mfma_n(const ushort* __restrict__ A,
                                                   const ushort* __restrict__ BT,
                                                   ushort* __restrict__ C,
                                                   int M, int K,
                                                   const float* __restrict__ rowscale) {
  __shared__ ushort As[128][40];
  __shared__ ushort Bs[TN][40];
  const int tid = threadIdx.x;
  const int bm = blockIdx.x * 128;
  const int wave = tid >> 6, lane = tid & 63;
  const int wr = wave * 32;
  const int lr = lane & 15;
  const int lk = (lane >> 4) * 8;
  constexpr int NF = TN / 16;

  f32x4 acc[2][NF];
#pragma unroll
  for (int m = 0; m < 2; ++m)
#pragma unroll
    for (int n = 0; n < NF; ++n)
#pragma unroll
      for (int q = 0; q < 4; ++q) acc[m][n][q] = 0.f;

  for (int k0 = 0; k0 < K; k0 += 32) {
#pragma unroll
    for (int it = 0; it < 2; ++it) {
      int s = tid + it * 256;
      int r = s >> 2;
      int c = (s & 3) * 8;
      int grow = bm + r; if (grow >= M) grow = M - 1;
      int4 v = *reinterpret_cast<const int4*>(&A[(size_t)grow * K + k0 + c]);
      *reinterpret_cast<int4*>(&As[r][c]) = v;
    }
    if (tid < TN * 4) {
      int r = tid >> 2;
      int c = (tid & 3) * 8;
      int4 v = *reinterpret_cast<const int4*>(&BT[(size_t)r * K + k0 + c]);
      *reinterpret_cast<int4*>(&Bs[r][c]) = v;
    }
    __syncthreads();

    bf16x8 af[2], bfr[NF];
#pragma unroll
    for (int m = 0; m < 2; ++m)
      af[m] = *reinterpret_cast<const bf16x8*>(&As[wr + m * 16 + lr][lk]);
#pragma unroll
    for (int n = 0; n < NF; ++n)
      bfr[n] = *reinterpret_cast<const bf16x8*>(&Bs[n * 16 + lr][lk]);
#pragma unroll
    for (int m = 0; m < 2; ++m)
#pragma unroll
      for (int n = 0; n < NF; ++n)
        acc[m][n] = __builtin_amdgcn_mfma_f32_16x16x32_bf16(af[m], bfr[n], acc[m][n], 0, 0, 0);
    __syncthreads();
  }

  const int rbase = (lane >> 4) * 4;
  const int cbase = lane & 15;
#pragma unroll
  for (int m = 0; m < 2; ++m) {
#pragma unroll
    for (int q = 0; q < 4; ++q) {
      int row = bm + wr + m * 16 + rbase + q;
      if (row >= M) continue;
      float sc = rowscale ? rowscale[row] : 1.f;
#pragma unroll
      for (int n = 0; n < NF; ++n) {
        int col = n * 16 + cbase;
        C[(size_t)row * TN + col] = f2bf(acc[m][n][q] * sc);
      }
    }
  }
}

// ---------------- GCN aggregation (bf16 gather, dinv pre-folded into h) ----------------
template <int F>
__global__ __launch_bounds__(256) void gcn_agg_bf(const ushort* __restrict__ h,
                                                  const int* __restrict__ row_start,
                                                  const int* __restrict__ csr,
                                                  const float* __restrict__ dinv,
                                                  float* __restrict__ out, int n) {
  constexpr int TPN = F / 4;
  constexpr int NPB = 256 / TPN;
  int node = blockIdx.x * NPB + threadIdx.x / TPN;
  int f4 = (threadIdx.x % TPN) * 4;
  if (node >= n) return;
  float di = dinv[node];
  ushort4 sv = *reinterpret_cast<const ushort4*>(&h[(size_t)node * F + f4]);
  float a0 = bf2f(sv.x), a1 = bf2f(sv.y), a2 = bf2f(sv.z), a3 = bf2f(sv.w);
  int s0 = row_start[node], s1 = row_start[node + 1];
  for (int e = s0; e < s1; ++e) {
    int s = csr[e];
    ushort4 v = *reinterpret_cast<const ushort4*>(&h[(size_t)s * F + f4]);
    a0 += bf2f(v.x); a1 += bf2f(v.y); a2 += bf2f(v.z); a3 += bf2f(v.w);
  }
  float4 o = make_float4(a0 * di, a1 * di, a2 * di, a3 * di);
  *reinterpret_cast<float4*>(&out[(size_t)node * F + f4]) = o;
}

// ---------------- BatchNorm stats: two-stage, NO global atomics ----------------
template <int F>
__global__ __launch_bounds__(256) void bn_stats_part(const float* __restrict__ x,
                                                     float* __restrict__ partials, int n) {
  __shared__ float lss[256], lsq[256];
  constexpr int RSTEP = 256 / F;
  int col = threadIdx.x % F;
  int rsub = threadIdx.x / F;
  int r0 = blockIdx.x * 64;
  int rend = r0 + 64; if (rend > n) rend = n;
  float s = 0.f, ss = 0.f;
  for (int r = r0 + rsub; r < rend; r += RSTEP) {
    float v = x[(size_t)r * F + col];
    s += v; ss += v * v;
  }
  lss[threadIdx.x] = s; lsq[threadIdx.x] = ss;
  __syncthreads();
#pragma unroll
  for (int half = 128; half >= 1; half >>= 1) {
    if (half < F) break;
    if (threadIdx.x < half) {
      lss[threadIdx.x] += lss[threadIdx.x + half];
      lsq[threadIdx.x] += lsq[threadIdx.x + half];
    }
    __syncthreads();
  }
  if (threadIdx.x < F) {
    partials[(size_t)blockIdx.x * 2 * F + threadIdx.x] = lss[threadIdx.x];
    partials[(size_t)blockIdx.x * 2 * F + F + threadIdx.x] = lsq[threadIdx.x];
  }
}

__global__ __launch_bounds__(512) void bn_stats_reduce(const float* __restrict__ partials,
                                                       float* __restrict__ stats,
                                                       int nb, int twoF) {
  int c = threadIdx.x;
  if (c >= twoF) return;
  float s0 = 0.f, s1 = 0.f, s2 = 0.f, s3 = 0.f;
  int b = 0;
  for (; b + 3 < nb; b += 4) {
    s0 += partials[(size_t)(b + 0) * twoF + c];
    s1 += partials[(size_t)(b + 1) * twoF + c];
    s2 += partials[(size_t)(b + 2) * twoF + c];
    s3 += partials[(size_t)(b + 3) * twoF + c];
  }
  for (; b < nb; ++b) s0 += partials[(size_t)b * twoF + c];
  stats[c] = (s0 + s1) + (s2 + s3);
}

template <int F>
__global__ __launch_bounds__(256) void bn_lrelu(float* __restrict__ x,
                                                const float* __restrict__ stats,
                                                const float* __restrict__ gamma,
                                                const float* __restrict__ beta, int n) {
  int i = blockIdx.x * 256 + threadIdx.x;
  int total = n * F;
  if (i >= total) return;
  int col = i & (F - 1);
  const float inv_n = 1.0f / (float)n;
  float mean = stats[col] * inv_n;
  float var = stats[F + col] * inv_n - mean * mean;
  float sc = gamma[col] * rsqrtf(var + 1e-5f);
  float v = (x[i] - mean) * sc + beta[col];
  x[i] = v >= 0.f ? v : 0.01f * v;
}

template <int F>
__global__ __launch_bounds__(256) void bn_lrelu_bf(const float* __restrict__ x,
                                                   const float* __restrict__ stats,
                                                   const float* __restrict__ gamma,
                                                   const float* __restrict__ beta,
                                                   ushort* __restrict__ out, int n) {
  int i = blockIdx.x * 256 + threadIdx.x;
  int total = n * F;
  if (i >= total) return;
  int col = i & (F - 1);
  const float inv_n = 1.0f / (float)n;
  float mean = stats[col] * inv_n;
  float var = stats[F + col] * inv_n - mean * mean;
  float sc = gamma[col] * rsqrtf(var + 1e-5f);
  float v = (x[i] - mean) * sc + beta[col];
  out[i] = f2bf(v >= 0.f ? v : 0.01f * v);
}

// ---------------- GAT ----------------
__global__ __launch_bounds__(256) void gat_scores_bf(const ushort* __restrict__ hg,
                                                     const float* __restrict__ a_src,
                                                     const float* __restrict__ a_dst,
                                                     float* __restrict__ asc,
                                                     float* __restrict__ adc, int n) {
  int node = blockIdx.x;
  int head = threadIdx.x >> 6;
  int lane = threadIdx.x & 63;
  ushort2 v = *reinterpret_cast<const ushort2*>(&hg[(size_t)node * 512 + head * 128 + lane * 2]);
  float v0 = bf2f(v.x), v1 = bf2f(v.y);
  float s = v0 * a_src[head * 128 + lane * 2] + v1 * a_src[head * 128 + lane * 2 + 1];
  float d = v0 * a_dst[head * 128 + lane * 2] + v1 * a_dst[head * 128 + lane * 2 + 1];
#pragma unroll
  for (int off = 32; off > 0; off >>= 1) {
    s += __shfl_down(s, off);
    d += __shfl_down(d, off);
  }
  if (lane == 0) {
    asc[node * 4 + head] = s;
    adc[node * 4 + head] = d;
  }
}

__global__ __launch_bounds__(256) void gat_softmax(const int* __restrict__ row_start,
                                                   const int* __restrict__ csr,
                                                   const float* __restrict__ asc,
                                                   const float* __restrict__ adc,
                                                   float* __restrict__ alpha,
                                                   float* __restrict__ wself,
                                                   float* __restrict__ invden, int n) {
  int i = blockIdx.x * 256 + threadIdx.x;
  if (i >= 4 * n) return;
  int node = i >> 2, h = i & 3;
  int s0 = row_start[node], s1 = row_start[node + 1];
  float ad = adc[i];
  float eself = lrelu02(asc[i] + ad);
  float m = eself;
  for (int e = s0; e < s1; ++e) {
    float v = lrelu02(asc[csr[e] * 4 + h] + ad);
    alpha[(size_t)e * 4 + h] = v;
    m = fmaxf(m, v);
  }
  float ws = __expf(eself - m);
  wself[i] = ws;
  float den = ws;
  for (int e = s0; e < s1; ++e) {
    float w = __expf(alpha[(size_t)e * 4 + h] - m);
    alpha[(size_t)e * 4 + h] = w;
    den += w;
  }
  invden[i] = 1.f / (den + 1e-16f);
}

__global__ __launch_bounds__(256) void gat_agg_bf(const ushort* __restrict__ hg,
                                                  const int* __restrict__ row_start,
                                                  const int* __restrict__ csr,
                                                  const float* __restrict__ alpha,
                                                  const float* __restrict__ wself,
                                                  const float* __restrict__ invden,
                                                  float* __restrict__ out, int n) {
  int node = blockIdx.x * 4 + (threadIdx.x >> 6);
  int lane = threadIdx.x & 63;
  if (node >= n) return;
  float4 idv = *reinterpret_cast<const float4*>(&invden[node * 4]);
  float4 wsv = *reinterpret_cast<const float4*>(&wself[node * 4]);
  float id0 = idv.x, id1 = idv.y, id2 = idv.z, id3 = idv.w;
  int f2 = lane * 2;
  const ushort* hrow = hg + (size_t)node * 512;
  float a0 = 0.f, a1 = 0.f;
  {
    ushort2 v0 = *reinterpret_cast<const ushort2*>(&hrow[f2]);
    ushort2 v1 = *reinterpret_cast<const ushort2*>(&hrow[128 + f2]);
    ushort2 v2 = *reinterpret_cast<const ushort2*>(&hrow[256 + f2]);
    ushort2 v3 = *reinterpret_cast<const ushort2*>(&hrow[384 + f2]);
    float c0 = wsv.x * id0, c1 = wsv.y * id1, c2 = wsv.z * id2, c3 = wsv.w * id3;
    a0 = c0 * bf2f(v0.x) + c1 * bf2f(v1.x) + c2 * bf2f(v2.x) + c3 * bf2f(v3.x);
    a1 = c0 * bf2f(v0.y) + c1 * bf2f(v1.y) + c2 * bf2f(v2.y) + c3 * bf2f(v3.y);
  }
  int s0 = row_start[node], s1 = row_start[node + 1];
  for (int e = s0; e < s1; ++e) {
    int s = csr[e];
    const ushort* srow = hg + (size_t)s * 512;
    float4 al = *reinterpret_cast<const float4*>(&alpha[(size_t)e * 4]);
    ushort2 v0 = *reinterpret_cast<const ushort2*>(&srow[f2]);
    ushort2 v1 = *reinterpret_cast<const ushort2*>(&srow[128 + f2]);
    ushort2 v2 = *reinterpret_cast<const ushort2*>(&srow[256 + f2]);
    ushort2 v3 = *reinterpret_cast<const ushort2*>(&srow[384 + f2]);
    float c0 = al.x * id0, c1 = al.y * id1, c2 = al.z * id2, c3 = al.w * id3;
    a0 += c0 * bf2f(v0.x) + c1 * bf2f(v1.x) + c2 * bf2f(v2.x) + c3 * bf2f(v3.x);
    a1 += c0 * bf2f(v0.y) + c1 * bf2f(v1.y) + c2 * bf2f(v2.y) + c3 * bf2f(v3.y);
  }
  out[(size_t)node * 128 + f2] = a0 * 0.25f;
  out[(size_t)node * 128 + f2 + 1] = a1 * 0.25f;
}

// ---------------- FC head + log_softmax ----------------
__global__ __launch_bounds__(256) void head_kernel(const float* __restrict__ h,
                                                   const float* __restrict__ fw1,
                                                   const float* __restrict__ fb1,
                                                   const float* __restrict__ fw2,
                                                   const float* __restrict__ fb2,
                                                   float* __restrict__ out, int n) {
  int i = blockIdx.x * 256 + threadIdx.x;
  if (i >= n) return;
  float xr[16];
#pragma unroll
  for (int q = 0; q < 4; ++q) {
    float4 v = *reinterpret_cast<const float4*>(&h[(size_t)i * 16 + q * 4]);
    xr[q * 4 + 0] = v.x; xr[q * 4 + 1] = v.y; xr[q * 4 + 2] = v.z; xr[q * 4 + 3] = v.w;
  }
  float z[8];
#pragma unroll
  for (int j = 0; j < 8; ++j) z[j] = fb1[j];
#pragma unroll
  for (int k = 0; k < 16; ++k) {
    float a = xr[k];
#pragma unroll
    for (int j = 0; j < 8; ++j) z[j] += a * fw1[k * 8 + j];
  }
#pragma unroll
  for (int j = 0; j < 8; ++j) z[j] = lrelu01(z[j]);
  float l[3];
#pragma unroll
  for (int j = 0; j < 3; ++j) l[j] = fb2[j];
#pragma unroll
  for (int k = 0; k < 8; ++k) {
    float a = z[k];
#pragma unroll
    for (int j = 0; j < 3; ++j) l[j] += a * fw2[k * 3 + j];
  }
  float mx = fmaxf(l[0], fmaxf(l[1], l[2]));
  float se = __expf(l[0] - mx) + __expf(l[1] - mx) + __expf(l[2] - mx);
  float ls = __logf(se);
#pragma unroll
  for (int j = 0; j < 3; ++j) out[(size_t)i * 3 + j] = l[j] - mx - ls;
}

// ---------------- launch ----------------
extern "C" void kernel_launch(void* const* d_in, const int* in_sizes, int n_in,
                              void* d_out, int out_size, void* d_ws, size_t ws_size,
                              hipStream_t stream) {
  const float* x      = (const float*)d_in[0];
  const int*   ei     = (const int*)d_in[1];
  const int*   srcI   = ei;
  const int*   dstI   = ei + NE;
  const float* w1     = (const float*)d_in[2];
  const float* g1     = (const float*)d_in[4];
  const float* be1    = (const float*)d_in[5];
  const float* gat_w  = (const float*)d_in[6];
  const float* gat_as = (const float*)d_in[7];
  const float* gat_ad = (const float*)d_in[8];
  const float* g2     = (const float*)d_in[10];
  const float* be2    = (const float*)d_in[11];
  const float* w3     = (const float*)d_in[12];
  const float* g3     = (const float*)d_in[14];
  const float* be3    = (const float*)d_in[15];
  const float* w4     = (const float*)d_in[16];
  const float* g4     = (const float*)d_in[18];
  const float* be4    = (const float*)d_in[19];
  const float* w5     = (const float*)d_in[20];
  const float* g5     = (const float*)d_in[22];
  const float* be5    = (const float*)d_in[23];
  const float* fw1    = (const float*)d_in[24];
  const float* fb1    = (const float*)d_in[25];
  const float* fw2    = (const float*)d_in[26];
  const float* fb2    = (const float*)d_in[27];
  // b1/b3/b4/b5/gat_b are per-column constants followed by BatchNorm ->
  // exactly cancelled by mean subtraction; dropped.
  float* out = (float*)d_out;

  char* wsp = (char*)d_ws;
  size_t off = 0;
  auto alloc = [&](size_t bytes) -> void* {
    void* p = wsp + off;
    off += (bytes + 255) & ~(size_t)255;
    return p;
  };
  ushort* hw_bf  = (ushort*)alloc((size_t)NN * 512 * 2);
  float*  bufB   = (float*)alloc((size_t)NN * 256 * 4);
  ushort* x_bf   = (ushort*)alloc((size_t)NN * 256 * 2);
  ushort* h1_bf  = (ushort*)alloc((size_t)NN * 256 * 2);
  ushort* h2_bf  = (ushort*)alloc((size_t)NN * 128 * 2);
  ushort* h3_bf  = (ushort*)alloc((size_t)NN * 64 * 2);
  ushort* h4_bf  = (ushort*)alloc((size_t)NN * 32 * 2);
  ushort* w1T    = (ushort*)alloc((size_t)256 * 256 * 2);
  ushort* gwT    = (ushort*)alloc((size_t)512 * 256 * 2);
  ushort* w3T    = (ushort*)alloc((size_t)64 * 128 * 2);
  ushort* w4T    = (ushort*)alloc((size_t)32 * 64 * 2);
  ushort* w5T    = (ushort*)alloc((size_t)16 * 32 * 2);
  float*  dinv   = (float*)alloc((size_t)NN * 4);
  int*    counts = (int*)alloc((size_t)NN * 4);
  int*    cursor = (int*)alloc((size_t)NN * 4);
  int*    rstart = (int*)alloc((size_t)(NN + 4) * 4);
  int*    bsum   = (int*)alloc((size_t)256 * 4);
  int*    csr    = (int*)alloc((size_t)NE * 4);
  float*  asc    = (float*)alloc((size_t)NN * 4 * 4);
  float*  adc    = (float*)alloc((size_t)NN * 4 * 4);
  float*  wself  = (float*)alloc((size_t)NN * 4 * 4);
  float*  invden = (float*)alloc((size_t)NN * 4 * 4);
  float*  alpha  = (float*)alloc((size_t)NE * 4 * 4);
  float*  stats  = (float*)alloc(2048);
  const int PB = (NN + 63) / 64;          // 782 stat partial blocks
  float*  partials = (float*)alloc((size_t)PB * 512 * 4);

  const int egrid = (NE + 255) / 256;
  const int ngrid = (NN + 255) / 256;     // 196
  const int mblocks = (NN + 127) / 128;   // 391

  // CSR build (hierarchical scan, no single-block serialization)
  hipMemsetAsync(counts, 0, (size_t)NN * 4, stream);
  hipMemsetAsync(cursor, 0, (size_t)NN * 4, stream);
  count_kernel<<<egrid, 256, 0, stream>>>(dstI, counts, NE);
  block_count_sum<<<ngrid, 256, 0, stream>>>(counts, bsum, dinv, NN);
  scan_bsum<<<1, 256, 0, stream>>>(bsum, ngrid);
  row_start_kernel<<<ngrid, 256, 0, stream>>>(counts, bsum, rstart, NN);
  fill_kernel<<<egrid, 256, 0, stream>>>(srcI, dstI, rstart, cursor, csr, NE);

  // conversions
  f32_to_bf16<<<(NN * 256 / 4 + 255) / 256, 256, 0, stream>>>(x, x_bf, NN * 256 / 4);
  transpose_bf<<<(256 * 256 + 255) / 256, 256, 0, stream>>>(w1, w1T, 256, 256);
  transpose_bf<<<(256 * 512 + 255) / 256, 256, 0, stream>>>(gat_w, gwT, 256, 512);
  transpose_bf<<<(128 * 64 + 255) / 256, 256, 0, stream>>>(w3, w3T, 128, 64);
  transpose_bf<<<(64 * 32 + 255) / 256, 256, 0, stream>>>(w4, w4T, 64, 32);
  transpose_bf<<<(32 * 16 + 255) / 256, 256, 0, stream>>>(w5, w5T, 32, 16);

  // ---- Layer 1: GCN 256 -> 256 ----
  gemm_mfma<<<dim3(mblocks, 2), 256, 0, stream>>>(x_bf, w1T, hw_bf, NN, 256, 256, dinv);
  gcn_agg_bf<256><<<(NN + 3) / 4, 256, 0, stream>>>(hw_bf, rstart, csr, dinv, bufB, NN);
  bn_stats_part<256><<<PB, 256, 0, stream>>>(bufB, partials, NN);
  bn_stats_reduce<<<1, 512, 0, stream>>>(partials, stats, PB, 512);
  bn_lrelu_bf<256><<<(NN * 256 + 255) / 256, 256, 0, stream>>>(bufB, stats, g1, be1, h1_bf, NN);

  // ---- Layer 2: GAT 256 -> 128 (4 heads, mean) ----
  gemm_mfma<<<dim3(mblocks, 4), 256, 0, stream>>>(h1_bf, gwT, hw_bf, NN, 256, 512, nullptr);
  gat_scores_bf<<<NN, 256, 0, stream>>>(hw_bf, gat_as, gat_ad, asc, adc, NN);
  gat_softmax<<<(4 * NN + 255) / 256, 256, 0, stream>>>(rstart, csr, asc, adc, alpha, wself, invden, NN);
  gat_agg_bf<<<(NN + 3) / 4, 256, 0, stream>>>(hw_bf, rstart, csr, alpha, wself, invden, bufB, NN);
  bn_stats_part<128><<<PB, 256, 0, stream>>>(bufB, partials, NN);
  bn_stats_reduce<<<1, 512, 0, stream>>>(partials, stats, PB, 256);
  bn_lrelu_bf<128><<<(NN * 128 + 255) / 256, 256, 0, stream>>>(bufB, stats, g2, be2, h2_bf, NN);

  // ---- Layer 3: GCN 128 -> 64 ----
  gemm_mfma_n<64><<<mblocks, 256, 0, stream>>>(h2_bf, w3T, hw_bf, NN, 128, dinv);
  gcn_agg_bf<64><<<(NN + 15) / 16, 256, 0, stream>>>(hw_bf, rstart, csr, dinv, bufB, NN);
  bn_stats_part<64><<<PB, 256, 0, stream>>>(bufB, partials, NN);
  bn_stats_reduce<<<1, 512, 0, stream>>>(partials, stats, PB, 128);
  bn_lrelu_bf<64><<<(NN * 64 + 255) / 256, 256, 0, stream>>>(bufB, stats, g3, be3, h3_bf, NN);

  // ---- Layer 4: GCN 64 -> 32 ----
  gemm_mfma_n<32><<<mblocks, 256, 0, stream>>>(h3_bf, w4T, hw_bf, NN, 64, dinv);
  gcn_agg_bf<32><<<(NN + 31) / 32, 256, 0, stream>>>(hw_bf, rstart, csr, dinv, bufB, NN);
  bn_stats_part<32><<<PB, 256, 0, stream>>>(bufB, partials, NN);
  bn_stats_reduce<<<1, 512, 0, stream>>>(partials, stats, PB, 64);
  bn_lrelu_bf<32><<<(NN * 32 + 255) / 256, 256, 0, stream>>>(bufB, stats, g4, be4, h4_bf, NN);

  // ---- Layer 5: GCN 32 -> 16 ----
  gemm_mfma_n<16><<<mblocks, 256, 0, stream>>>(h4_bf, w5T, hw_bf, NN, 32, dinv);
  gcn_agg_bf<16><<<(NN + 63) / 64, 256, 0, stream>>>(hw_bf, rstart, csr, dinv, bufB, NN);
  bn_stats_part<16><<<PB, 256, 0, stream>>>(bufB, partials, NN);
  bn_stats_reduce<<<1, 512, 0, stream>>>(partials, stats, PB, 32);
  bn_lrelu<16><<<(NN * 16 + 255) / 256, 256, 0, stream>>>(bufB, stats, g5, be5, NN);

  // ---- FC head + log_softmax ----
  head_kernel<<<ngrid, 256, 0, stream>>>(bufB, fw1, fb1, fw2, fb2, out, NN);
}

// Round 6
// 394.654 us; speedup vs baseline: 3.3433x; 1.8661x over previous
//
#include <hip/hip_runtime.h>

#define NN 50000
#define NE 400000
#define GSTAT 2048

typedef short bf16x8 __attribute__((ext_vector_type(8)));
typedef float f32x4 __attribute__((ext_vector_type(4)));

__device__ __forceinline__ float lrelu01(float v) { return v >= 0.f ? v : 0.01f * v; }
__device__ __forceinline__ float lrelu02(float v) { return v >= 0.f ? v : 0.2f * v; }

__device__ __forceinline__ ushort f2bf(float f) {
  union { float f; unsigned u; } v; v.f = f;
  unsigned u = v.u;
  return (ushort)((u + 0x7FFFu + ((u >> 16) & 1u)) >> 16);
}
__device__ __forceinline__ float bf2f(ushort u) {
  union { unsigned u; float f; } v; v.u = ((unsigned)u) << 16;
  return v.f;
}

// ---------------- weight prep: all 5 transposes fused ----------------
__global__ void wprep(const float* __restrict__ w1, const float* __restrict__ gw,
                      const float* __restrict__ w3, const float* __restrict__ w4,
                      const float* __restrict__ w5,
                      ushort* __restrict__ w1T, ushort* __restrict__ gwT,
                      ushort* __restrict__ w3T, ushort* __restrict__ w4T,
                      ushort* __restrict__ w5T) {
  int i = blockIdx.x * 256 + threadIdx.x;
  const float* W; ushort* WT; int K, N, j;
  if (i < 65536)        { W = w1; WT = w1T; K = 256; N = 256; j = i; }
  else if (i < 196608)  { W = gw; WT = gwT; K = 256; N = 512; j = i - 65536; }
  else if (i < 204800)  { W = w3; WT = w3T; K = 128; N = 64;  j = i - 196608; }
  else if (i < 206848)  { W = w4; WT = w4T; K = 64;  N = 32;  j = i - 204800; }
  else if (i < 207360)  { W = w5; WT = w5T; K = 32;  N = 16;  j = i - 206848; }
  else return;
  int k = j / N, c = j % N;
  WT[(size_t)c * K + k] = f2bf(W[(size_t)j]);
}

// ---------------- CSR build ----------------
__global__ void count_kernel(const int* __restrict__ dst, int* __restrict__ counts, int e) {
  int i = blockIdx.x * 256 + threadIdx.x;
  if (i < e) atomicAdd(&counts[dst[i]], 1);
}

__global__ __launch_bounds__(256) void block_count_sum(const int* __restrict__ counts,
                                                       int* __restrict__ bsum,
                                                       float* __restrict__ dinv, int n) {
  int i = blockIdx.x * 256 + threadIdx.x;
  int c = (i < n) ? counts[i] : 0;
  if (i < n) dinv[i] = rsqrtf((float)c + 1.0f);
  int s = c;
#pragma unroll
  for (int off = 32; off > 0; off >>= 1) s += __shfl_down(s, off);
  __shared__ int ws[4];
  if ((threadIdx.x & 63) == 0) ws[threadIdx.x >> 6] = s;
  __syncthreads();
  if (threadIdx.x == 0) bsum[blockIdx.x] = ws[0] + ws[1] + ws[2] + ws[3];
}

__global__ __launch_bounds__(256) void scan_bsum(int* __restrict__ bsum, int nb) {
  __shared__ int sh[256];
  int v = (threadIdx.x < nb) ? bsum[threadIdx.x] : 0;
  sh[threadIdx.x] = v;
  __syncthreads();
  for (int off = 1; off < 256; off <<= 1) {
    int t = (threadIdx.x >= off) ? sh[threadIdx.x - off] : 0;
    __syncthreads();
    sh[threadIdx.x] += t;
    __syncthreads();
  }
  if (threadIdx.x < nb) bsum[threadIdx.x] = sh[threadIdx.x] - v;
}

__global__ __launch_bounds__(256) void row_start_kernel(const int* __restrict__ counts,
                                                        const int* __restrict__ bsum,
                                                        int* __restrict__ row_start, int n) {
  __shared__ int sh[256];
  int i = blockIdx.x * 256 + threadIdx.x;
  int c = (i < n) ? counts[i] : 0;
  sh[threadIdx.x] = c;
  __syncthreads();
  for (int off = 1; off < 256; off <<= 1) {
    int t = (threadIdx.x >= off) ? sh[threadIdx.x - off] : 0;
    __syncthreads();
    sh[threadIdx.x] += t;
    __syncthreads();
  }
  int incl = sh[threadIdx.x];
  int base = bsum[blockIdx.x];
  if (i < n) row_start[i] = base + incl - c;
  if (i == n - 1) row_start[n] = base + incl;
}

__global__ void fill_kernel(const int* __restrict__ src, const int* __restrict__ dst,
                            const int* __restrict__ row_start, int* __restrict__ cursor,
                            int* __restrict__ csr, int e) {
  int i = blockIdx.x * 256 + threadIdx.x;
  if (i >= e) return;
  int d = dst[i];
  int pos = atomicAdd(&cursor[d], 1);
  csr[row_start[d] + pos] = src[i];
}

// ---------------- GEMM 1: A fp32 (x), bf16 out, rowscale ----------------
__global__ __launch_bounds__(256) void gemm_mfma_x(const float* __restrict__ A,
                                                   const ushort* __restrict__ BT,
                                                   ushort* __restrict__ C,
                                                   int M, int K, int N,
                                                   const float* __restrict__ rowscale) {
  __shared__ ushort As[128][40];
  __shared__ ushort Bs[128][40];
  const int tid = threadIdx.x;
  const int bm = blockIdx.x * 128;
  const int bn = blockIdx.y * 128;
  const int wave = tid >> 6, lane = tid & 63;
  const int wr = (wave >> 1) * 64;
  const int wc = (wave & 1) * 64;
  const int lr = lane & 15;
  const int lk = (lane >> 4) * 8;

  f32x4 acc[4][4];
#pragma unroll
  for (int m = 0; m < 4; ++m)
#pragma unroll
    for (int n = 0; n < 4; ++n)
#pragma unroll
      for (int q = 0; q < 4; ++q) acc[m][n][q] = 0.f;

  for (int k0 = 0; k0 < K; k0 += 32) {
#pragma unroll
    for (int it = 0; it < 2; ++it) {
      int s = tid + it * 256;
      int r = s >> 2;
      int c = (s & 3) * 8;
      int grow = bm + r; if (grow >= M) grow = M - 1;
      float4 va = *reinterpret_cast<const float4*>(&A[(size_t)grow * K + k0 + c]);
      float4 vb = *reinterpret_cast<const float4*>(&A[(size_t)grow * K + k0 + c + 4]);
      ushort4 lo = make_ushort4(f2bf(va.x), f2bf(va.y), f2bf(va.z), f2bf(va.w));
      ushort4 hi = make_ushort4(f2bf(vb.x), f2bf(vb.y), f2bf(vb.z), f2bf(vb.w));
      *reinterpret_cast<ushort4*>(&As[r][c]) = lo;
      *reinterpret_cast<ushort4*>(&As[r][c + 4]) = hi;
    }
#pragma unroll
    for (int it = 0; it < 2; ++it) {
      int s = tid + it * 256;
      int r = s >> 2;
      int c = (s & 3) * 8;
      int4 v = *reinterpret_cast<const int4*>(&BT[(size_t)(bn + r) * K + k0 + c]);
      *reinterpret_cast<int4*>(&Bs[r][c]) = v;
    }
    __syncthreads();

    bf16x8 af[4], bfr[4];
#pragma unroll
    for (int m = 0; m < 4; ++m)
      af[m] = *reinterpret_cast<const bf16x8*>(&As[wr + m * 16 + lr][lk]);
#pragma unroll
    for (int n = 0; n < 4; ++n)
      bfr[n] = *reinterpret_cast<const bf16x8*>(&Bs[wc + n * 16 + lr][lk]);
#pragma unroll
    for (int m = 0; m < 4; ++m)
#pragma unroll
      for (int n = 0; n < 4; ++n)
        acc[m][n] = __builtin_amdgcn_mfma_f32_16x16x32_bf16(af[m], bfr[n], acc[m][n], 0, 0, 0);
    __syncthreads();
  }

  const int rbase = (lane >> 4) * 4;
  const int cbase = lane & 15;
#pragma unroll
  for (int m = 0; m < 4; ++m) {
#pragma unroll
    for (int q = 0; q < 4; ++q) {
      int row = bm + wr + m * 16 + rbase + q;
      if (row >= M) continue;
      float sc = rowscale ? rowscale[row] : 1.f;
#pragma unroll
      for (int n = 0; n < 4; ++n) {
        int col = bn + wc + n * 16 + cbase;
        C[(size_t)row * N + col] = f2bf(acc[m][n][q] * sc);
      }
    }
  }
}

// ---------------- GEMM with fused BN+lrelu on A (raw bf16 + stats) ----------------
__global__ __launch_bounds__(256) void gemm_mfma_bn(const ushort* __restrict__ A,
                                                    const ushort* __restrict__ BT,
                                                    ushort* __restrict__ C,
                                                    int M, int K, int N,
                                                    const float* __restrict__ rowscale,
                                                    const float* __restrict__ stats,
                                                    const float* __restrict__ gamma,
                                                    const float* __restrict__ beta) {
  __shared__ ushort As[128][40];
  __shared__ ushort Bs[128][40];
  __shared__ float scl[256], shl[256];
  const int tid = threadIdx.x;
  const float inv_n = 1.0f / (float)NN;
  for (int k = tid; k < K; k += 256) {
    float mean = stats[k] * inv_n;
    float var = stats[K + k] * inv_n - mean * mean;
    float sc = gamma[k] * rsqrtf(var + 1e-5f);
    scl[k] = sc;
    shl[k] = beta[k] - mean * sc;
  }
  const int bm = blockIdx.x * 128;
  const int bn = blockIdx.y * 128;
  const int wave = tid >> 6, lane = tid & 63;
  const int wr = (wave >> 1) * 64;
  const int wc = (wave & 1) * 64;
  const int lr = lane & 15;
  const int lk = (lane >> 4) * 8;

  f32x4 acc[4][4];
#pragma unroll
  for (int m = 0; m < 4; ++m)
#pragma unroll
    for (int n = 0; n < 4; ++n)
#pragma unroll
      for (int q = 0; q < 4; ++q) acc[m][n][q] = 0.f;
  __syncthreads();

  for (int k0 = 0; k0 < K; k0 += 32) {
#pragma unroll
    for (int it = 0; it < 2; ++it) {
      int s = tid + it * 256;
      int r = s >> 2;
      int c = (s & 3) * 8;
      int grow = bm + r; if (grow >= M) grow = M - 1;
      int4 v = *reinterpret_cast<const int4*>(&A[(size_t)grow * K + k0 + c]);
      ushort* u = reinterpret_cast<ushort*>(&v);
      ushort tmp[8];
#pragma unroll
      for (int j = 0; j < 8; ++j) {
        float f = bf2f(u[j]) * scl[k0 + c + j] + shl[k0 + c + j];
        tmp[j] = f2bf(f >= 0.f ? f : 0.01f * f);
      }
      *reinterpret_cast<int4*>(&As[r][c]) = *reinterpret_cast<int4*>(tmp);
    }
#pragma unroll
    for (int it = 0; it < 2; ++it) {
      int s = tid + it * 256;
      int r = s >> 2;
      int c = (s & 3) * 8;
      int4 v = *reinterpret_cast<const int4*>(&BT[(size_t)(bn + r) * K + k0 + c]);
      *reinterpret_cast<int4*>(&Bs[r][c]) = v;
    }
    __syncthreads();

    bf16x8 af[4], bfr[4];
#pragma unroll
    for (int m = 0; m < 4; ++m)
      af[m] = *reinterpret_cast<const bf16x8*>(&As[wr + m * 16 + lr][lk]);
#pragma unroll
    for (int n = 0; n < 4; ++n)
      bfr[n] = *reinterpret_cast<const bf16x8*>(&Bs[wc + n * 16 + lr][lk]);
#pragma unroll
    for (int m = 0; m < 4; ++m)
#pragma unroll
      for (int n = 0; n < 4; ++n)
        acc[m][n] = __builtin_amdgcn_mfma_f32_16x16x32_bf16(af[m], bfr[n], acc[m][n], 0, 0, 0);
    __syncthreads();
  }

  const int rbase = (lane >> 4) * 4;
  const int cbase = lane & 15;
#pragma unroll
  for (int m = 0; m < 4; ++m) {
#pragma unroll
    for (int q = 0; q < 4; ++q) {
      int row = bm + wr + m * 16 + rbase + q;
      if (row >= M) continue;
      float sc = rowscale ? rowscale[row] : 1.f;
#pragma unroll
      for (int n = 0; n < 4; ++n) {
        int col = bn + wc + n * 16 + cbase;
        C[(size_t)row * N + col] = f2bf(acc[m][n][q] * sc);
      }
    }
  }
}

// ---------------- small-N GEMM with fused BN+lrelu on A ----------------
template <int TN>
__global__ __launch_bounds__(256) void gemm_mfma_n_bn(const ushort* __restrict__ A,
                                                      const ushort* __restrict__ BT,
                                                      ushort* __restrict__ C,
                                                      int M, int K,
                                                      const float* __restrict__ rowscale,
                                                      const float* __restrict__ stats,
                                                      const float* __restrict__ gamma,
                                                      const float* __restrict__ beta) {
  __shared__ ushort As[128][40];
  __shared__ ushort Bs[TN][40];
  __shared__ float scl[128], shl[128];
  const int tid = threadIdx.x;
  const float inv_n = 1.0f / (float)NN;
  if (tid < K) {
    float mean = stats[tid] * inv_n;
    float var = stats[K + tid] * inv_n - mean * mean;
    float sc = gamma[tid] * rsqrtf(var + 1e-5f);
    scl[tid] = sc;
    shl[tid] = beta[tid] - mean * sc;
  }
  const int bm = blockIdx.x * 128;
  const int wave = tid >> 6, lane = tid & 63;
  const int wr = wave * 32;
  const int lr = lane & 15;
  const int lk = (lane >> 4) * 8;
  constexpr int NF = TN / 16;

  f32x4 acc[2][NF];
#pragma unroll
  for (int m = 0; m < 2; ++m)
#pragma unroll
    for (int n = 0; n < NF; ++n)
#pragma unroll
      for (int q = 0; q < 4; ++q) acc[m][n][q] = 0.f;
  __syncthreads();

  for (int k0 = 0; k0 < K; k0 += 32) {
#pragma unroll
    for (int it = 0; it < 2; ++it) {
      int s = tid + it * 256;
      int r = s >> 2;
      int c = (s & 3) * 8;
      int grow = bm + r; if (grow >= M) grow = M - 1;
      int4 v = *reinterpret_cast<const int4*>(&A[(size_t)grow * K + k0 + c]);
      ushort* u = reinterpret_cast<ushort*>(&v);
      ushort tmp[8];
#pragma unroll
      for (int j = 0; j < 8; ++j) {
        float f = bf2f(u[j]) * scl[k0 + c + j] + shl[k0 + c + j];
        tmp[j] = f2bf(f >= 0.f ? f : 0.01f * f);
      }
      *reinterpret_cast<int4*>(&As[r][c]) = *reinterpret_cast<int4*>(tmp);
    }
    if (tid < TN * 4) {
      int r = tid >> 2;
      int c = (tid & 3) * 8;
      int4 v = *reinterpret_cast<const int4*>(&BT[(size_t)r * K + k0 + c]);
      *reinterpret_cast<int4*>(&Bs[r][c]) = v;
    }
    __syncthreads();

    bf16x8 af[2], bfr[NF];
#pragma unroll
    for (int m = 0; m < 2; ++m)
      af[m] = *reinterpret_cast<const bf16x8*>(&As[wr + m * 16 + lr][lk]);
#pragma unroll
    for (int n = 0; n < NF; ++n)
      bfr[n] = *reinterpret_cast<const bf16x8*>(&Bs[n * 16 + lr][lk]);
#pragma unroll
    for (int m = 0; m < 2; ++m)
#pragma unroll
      for (int n = 0; n < NF; ++n)
        acc[m][n] = __builtin_amdgcn_mfma_f32_16x16x32_bf16(af[m], bfr[n], acc[m][n], 0, 0, 0);
    __syncthreads();
  }

  const int rbase = (lane >> 4) * 4;
  const int cbase = lane & 15;
#pragma unroll
  for (int m = 0; m < 2; ++m) {
#pragma unroll
    for (int q = 0; q < 4; ++q) {
      int row = bm + wr + m * 16 + rbase + q;
      if (row >= M) continue;
      float sc = rowscale ? rowscale[row] : 1.f;
#pragma unroll
      for (int n = 0; n < NF; ++n) {
        int col = n * 16 + cbase;
        C[(size_t)row * TN + col] = f2bf(acc[m][n][q] * sc);
      }
    }
  }
}

// ---------------- GCN agg + fused BN stats partials (bf16 in/out) ----------------
template <int F>
__global__ __launch_bounds__(256) void gcn_agg_stats(const ushort* __restrict__ h,
                                                     const int* __restrict__ row_start,
                                                     const int* __restrict__ csr,
                                                     const float* __restrict__ dinv,
                                                     ushort* __restrict__ out,
                                                     float* __restrict__ partials, int n) {
  constexpr int TPN = F / 4;
  constexpr int NPB = 256 / TPN;
  const int tid = threadIdx.x;
  const int sub = tid / TPN;
  const int f4 = (tid % TPN) * 4;
  float ps0 = 0.f, ps1 = 0.f, ps2 = 0.f, ps3 = 0.f;
  float pq0 = 0.f, pq1 = 0.f, pq2 = 0.f, pq3 = 0.f;

  for (int node = blockIdx.x * NPB + sub; node < n; node += GSTAT * NPB) {
    float di = dinv[node];
    ushort4 sv = *reinterpret_cast<const ushort4*>(&h[(size_t)node * F + f4]);
    float a0 = bf2f(sv.x), a1 = bf2f(sv.y), a2 = bf2f(sv.z), a3 = bf2f(sv.w);
    int s0 = row_start[node], s1 = row_start[node + 1];
    int e = s0;
    for (; e + 1 < s1; e += 2) {
      int sA = csr[e], sB = csr[e + 1];
      ushort4 vA = *reinterpret_cast<const ushort4*>(&h[(size_t)sA * F + f4]);
      ushort4 vB = *reinterpret_cast<const ushort4*>(&h[(size_t)sB * F + f4]);
      a0 += bf2f(vA.x) + bf2f(vB.x);
      a1 += bf2f(vA.y) + bf2f(vB.y);
      a2 += bf2f(vA.z) + bf2f(vB.z);
      a3 += bf2f(vA.w) + bf2f(vB.w);
    }
    if (e < s1) {
      int sA = csr[e];
      ushort4 vA = *reinterpret_cast<const ushort4*>(&h[(size_t)sA * F + f4]);
      a0 += bf2f(vA.x); a1 += bf2f(vA.y); a2 += bf2f(vA.z); a3 += bf2f(vA.w);
    }
    a0 *= di; a1 *= di; a2 *= di; a3 *= di;
    ushort4 o = make_ushort4(f2bf(a0), f2bf(a1), f2bf(a2), f2bf(a3));
    *reinterpret_cast<ushort4*>(&out[(size_t)node * F + f4]) = o;
    ps0 += a0; ps1 += a1; ps2 += a2; ps3 += a3;
    pq0 += a0 * a0; pq1 += a1 * a1; pq2 += a2 * a2; pq3 += a3 * a3;
  }

  __shared__ float red[8][256];
  red[0][tid] = ps0; red[1][tid] = ps1; red[2][tid] = ps2; red[3][tid] = ps3;
  red[4][tid] = pq0; red[5][tid] = pq1; red[6][tid] = pq2; red[7][tid] = pq3;
  __syncthreads();
#pragma unroll
  for (int half = 128; half >= TPN; half >>= 1) {
    if (tid < half) {
#pragma unroll
      for (int k = 0; k < 8; ++k) red[k][tid] += red[k][tid + half];
    }
    __syncthreads();
  }
  if (tid < TPN) {
    int b = blockIdx.x;
#pragma unroll
    for (int j = 0; j < 4; ++j) {
      partials[(size_t)(tid * 4 + j) * GSTAT + b] = red[j][tid];
      partials[(size_t)(F + tid * 4 + j) * GSTAT + b] = red[4 + j][tid];
    }
  }
}

// ---------------- GAT agg + fused BN stats partials ----------------
__global__ __launch_bounds__(256) void gat_agg_stats(const ushort* __restrict__ hg,
                                                     const int* __restrict__ row_start,
                                                     const int* __restrict__ csr,
                                                     const float* __restrict__ alpha,
                                                     const float* __restrict__ wself,
                                                     const float* __restrict__ invden,
                                                     ushort* __restrict__ out,
                                                     float* __restrict__ partials, int n) {
  const int tid = threadIdx.x;
  const int wave = tid >> 6;
  const int lane = tid & 63;
  const int f2 = lane * 2;
  float ps0 = 0.f, ps1 = 0.f, pq0 = 0.f, pq1 = 0.f;

  for (int node = blockIdx.x * 4 + wave; node < n; node += GSTAT * 4) {
    float4 idv = *reinterpret_cast<const float4*>(&invden[node * 4]);
    float4 wsv = *reinterpret_cast<const float4*>(&wself[node * 4]);
    float a0, a1;
    {
      const ushort* hrow = hg + (size_t)node * 512;
      ushort2 v0 = *reinterpret_cast<const ushort2*>(&hrow[f2]);
      ushort2 v1 = *reinterpret_cast<const ushort2*>(&hrow[128 + f2]);
      ushort2 v2 = *reinterpret_cast<const ushort2*>(&hrow[256 + f2]);
      ushort2 v3 = *reinterpret_cast<const ushort2*>(&hrow[384 + f2]);
      float c0 = wsv.x * idv.x, c1 = wsv.y * idv.y, c2 = wsv.z * idv.z, c3 = wsv.w * idv.w;
      a0 = c0 * bf2f(v0.x) + c1 * bf2f(v1.x) + c2 * bf2f(v2.x) + c3 * bf2f(v3.x);
      a1 = c0 * bf2f(v0.y) + c1 * bf2f(v1.y) + c2 * bf2f(v2.y) + c3 * bf2f(v3.y);
    }
    int s0 = row_start[node], s1 = row_start[node + 1];
    int e = s0;
    for (; e + 1 < s1; e += 2) {
      int sA = csr[e], sB = csr[e + 1];
      float4 alA = *reinterpret_cast<const float4*>(&alpha[(size_t)e * 4]);
      float4 alB = *reinterpret_cast<const float4*>(&alpha[(size_t)(e + 1) * 4]);
      const ushort* rA = hg + (size_t)sA * 512;
      const ushort* rB = hg + (size_t)sB * 512;
      ushort2 A0 = *reinterpret_cast<const ushort2*>(&rA[f2]);
      ushort2 A1 = *reinterpret_cast<const ushort2*>(&rA[128 + f2]);
      ushort2 A2 = *reinterpret_cast<const ushort2*>(&rA[256 + f2]);
      ushort2 A3 = *reinterpret_cast<const ushort2*>(&rA[384 + f2]);
      ushort2 B0 = *reinterpret_cast<const ushort2*>(&rB[f2]);
      ushort2 B1 = *reinterpret_cast<const ushort2*>(&rB[128 + f2]);
      ushort2 B2 = *reinterpret_cast<const ushort2*>(&rB[256 + f2]);
      ushort2 B3 = *reinterpret_cast<const ushort2*>(&rB[384 + f2]);
      float cA0 = alA.x * idv.x, cA1 = alA.y * idv.y, cA2 = alA.z * idv.z, cA3 = alA.w * idv.w;
      float cB0 = alB.x * idv.x, cB1 = alB.y * idv.y, cB2 = alB.z * idv.z, cB3 = alB.w * idv.w;
      a0 += cA0 * bf2f(A0.x) + cA1 * bf2f(A1.x) + cA2 * bf2f(A2.x) + cA3 * bf2f(A3.x)
          + cB0 * bf2f(B0.x) + cB1 * bf2f(B1.x) + cB2 * bf2f(B2.x) + cB3 * bf2f(B3.x);
      a1 += cA0 * bf2f(A0.y) + cA1 * bf2f(A1.y) + cA2 * bf2f(A2.y) + cA3 * bf2f(A3.y)
          + cB0 * bf2f(B0.y) + cB1 * bf2f(B1.y) + cB2 * bf2f(B2.y) + cB3 * bf2f(B3.y);
    }
    if (e < s1) {
      int sA = csr[e];
      float4 alA = *reinterpret_cast<const float4*>(&alpha[(size_t)e * 4]);
      const ushort* rA = hg + (size_t)sA * 512;
      ushort2 A0 = *reinterpret_cast<const ushort2*>(&rA[f2]);
      ushort2 A1 = *reinterpret_cast<const ushort2*>(&rA[128 + f2]);
      ushort2 A2 = *reinterpret_cast<const ushort2*>(&rA[256 + f2]);
      ushort2 A3 = *reinterpret_cast<const ushort2*>(&rA[384 + f2]);
      float cA0 = alA.x * idv.x, cA1 = alA.y * idv.y, cA2 = alA.z * idv.z, cA3 = alA.w * idv.w;
      a0 += cA0 * bf2f(A0.x) + cA1 * bf2f(A1.x) + cA2 * bf2f(A2.x) + cA3 * bf2f(A3.x);
      a1 += cA0 * bf2f(A0.y) + cA1 * bf2f(A1.y) + cA2 * bf2f(A2.y) + cA3 * bf2f(A3.y);
    }
    a0 *= 0.25f; a1 *= 0.25f;
    ushort2 o = make_ushort2(f2bf(a0), f2bf(a1));
    *reinterpret_cast<ushort2*>(&out[(size_t)node * 128 + f2]) = o;
    ps0 += a0; ps1 += a1; pq0 += a0 * a0; pq1 += a1 * a1;
  }

  __shared__ float red[4][256];
  red[0][tid] = ps0; red[1][tid] = ps1; red[2][tid] = pq0; red[3][tid] = pq1;
  __syncthreads();
#pragma unroll
  for (int half = 128; half >= 64; half >>= 1) {
    if (tid < half) {
#pragma unroll
      for (int k = 0; k < 4; ++k) red[k][tid] += red[k][tid + half];
    }
    __syncthreads();
  }
  if (tid < 64) {
    int b = blockIdx.x;
    partials[(size_t)(tid * 2 + 0) * GSTAT + b] = red[0][tid];
    partials[(size_t)(tid * 2 + 1) * GSTAT + b] = red[1][tid];
    partials[(size_t)(128 + tid * 2 + 0) * GSTAT + b] = red[2][tid];
    partials[(size_t)(128 + tid * 2 + 1) * GSTAT + b] = red[3][tid];
  }
}

// ---------------- stats reduce: one block per column ----------------
__global__ __launch_bounds__(256) void bn_reduce_col(const float* __restrict__ partials,
                                                     float* __restrict__ stats) {
  int c = blockIdx.x;
  float s = 0.f;
  for (int b = threadIdx.x; b < GSTAT; b += 256) s += partials[(size_t)c * GSTAT + b];
#pragma unroll
  for (int off = 32; off > 0; off >>= 1) s += __shfl_down(s, off);
  __shared__ float ws[4];
  if ((threadIdx.x & 63) == 0) ws[threadIdx.x >> 6] = s;
  __syncthreads();
  if (threadIdx.x == 0) stats[c] = ws[0] + ws[1] + ws[2] + ws[3];
}

// ---------------- GAT scores / softmax ----------------
__global__ __launch_bounds__(256) void gat_scores_bf(const ushort* __restrict__ hg,
                                                     const float* __restrict__ a_src,
                                                     const float* __restrict__ a_dst,
                                                     float* __restrict__ asc,
                                                     float* __restrict__ adc, int n) {
  int node = blockIdx.x;
  int head = threadIdx.x >> 6;
  int lane = threadIdx.x & 63;
  ushort2 v = *reinterpret_cast<const ushort2*>(&hg[(size_t)node * 512 + head * 128 + lane * 2]);
  float v0 = bf2f(v.x), v1 = bf2f(v.y);
  float s = v0 * a_src[head * 128 + lane * 2] + v1 * a_src[head * 128 + lane * 2 + 1];
  float d = v0 * a_dst[head * 128 + lane * 2] + v1 * a_dst[head * 128 + lane * 2 + 1];
#pragma unroll
  for (int off = 32; off > 0; off >>= 1) {
    s += __shfl_down(s, off);
    d += __shfl_down(d, off);
  }
  if (lane == 0) {
    asc[node * 4 + head] = s;
    adc[node * 4 + head] = d;
  }
}

__global__ __launch_bounds__(256) void gat_softmax(const int* __restrict__ row_start,
                                                   const int* __restrict__ csr,
                                                   const float* __restrict__ asc,
                                                   const float* __restrict__ adc,
                                                   float* __restrict__ alpha,
                                                   float* __restrict__ wself,
                                                   float* __restrict__ invden, int n) {
  int i = blockIdx.x * 256 + threadIdx.x;
  if (i >= 4 * n) return;
  int node = i >> 2, h = i & 3;
  int s0 = row_start[node], s1 = row_start[node + 1];
  float ad = adc[i];
  float eself = lrelu02(asc[i] + ad);
  float m = eself;
  for (int e = s0; e < s1; ++e) {
    float v = lrelu02(asc[csr[e] * 4 + h] + ad);
    alpha[(size_t)e * 4 + h] = v;
    m = fmaxf(m, v);
  }
  float ws = __expf(eself - m);
  wself[i] = ws;
  float den = ws;
  for (int e = s0; e < s1; ++e) {
    float w = __expf(alpha[(size_t)e * 4 + h] - m);
    alpha[(size_t)e * 4 + h] = w;
    den += w;
  }
  invden[i] = 1.f / (den + 1e-16f);
}

// ---------------- FC head: fused BN+lrelu + MLP + log_softmax ----------------
__global__ __launch_bounds__(256) void head_kernel_bn(const ushort* __restrict__ h,
                                                      const float* __restrict__ stats,
                                                      const float* __restrict__ g5,
                                                      const float* __restrict__ be5,
                                                      const float* __restrict__ fw1,
                                                      const float* __restrict__ fb1,
                                                      const float* __restrict__ fw2,
                                                      const float* __restrict__ fb2,
                                                      float* __restrict__ out, int n) {
  __shared__ float scl[16], shl[16];
  if (threadIdx.x < 16) {
    const float inv_n = 1.0f / (float)NN;
    int k = threadIdx.x;
    float mean = stats[k] * inv_n;
    float var = stats[16 + k] * inv_n - mean * mean;
    float sc = g5[k] * rsqrtf(var + 1e-5f);
    scl[k] = sc;
    shl[k] = be5[k] - mean * sc;
  }
  __syncthreads();
  int i = blockIdx.x * 256 + threadIdx.x;
  if (i >= n) return;
  int4 ra = *reinterpret_cast<const int4*>(&h[(size_t)i * 16]);
  int4 rb = *reinterpret_cast<const int4*>(&h[(size_t)i * 16 + 8]);
  ushort u[16];
  *reinterpret_cast<int4*>(&u[0]) = ra;
  *reinterpret_cast<int4*>(&u[8]) = rb;
  float xr[16];
#pragma unroll
  for (int k = 0; k < 16; ++k) {
    float v = bf2f(u[k]) * scl[k] + shl[k];
    xr[k] = v >= 0.f ? v : 0.01f * v;
  }
  float z[8];
#pragma unroll
  for (int j = 0; j < 8; ++j) z[j] = fb1[j];
#pragma unroll
  for (int k = 0; k < 16; ++k) {
    float a = xr[k];
#pragma unroll
    for (int j = 0; j < 8; ++j) z[j] += a * fw1[k * 8 + j];
  }
#pragma unroll
  for (int j = 0; j < 8; ++j) z[j] = lrelu01(z[j]);
  float l[3];
#pragma unroll
  for (int j = 0; j < 3; ++j) l[j] = fb2[j];
#pragma unroll
  for (int k = 0; k < 8; ++k) {
    float a = z[k];
#pragma unroll
    for (int j = 0; j < 3; ++j) l[j] += a * fw2[k * 3 + j];
  }
  float mx = fmaxf(l[0], fmaxf(l[1], l[2]));
  float se = __expf(l[0] - mx) + __expf(l[1] - mx) + __expf(l[2] - mx);
  float ls = __logf(se);
#pragma unroll
  for (int j = 0; j < 3; ++j) out[(size_t)i * 3 + j] = l[j] - mx - ls;
}

// ---------------- launch ----------------
extern "C" void kernel_launch(void* const* d_in, const int* in_sizes, int n_in,
                              void* d_out, int out_size, void* d_ws, size_t ws_size,
                              hipStream_t stream) {
  const float* x      = (const float*)d_in[0];
  const int*   ei     = (const int*)d_in[1];
  const int*   srcI   = ei;
  const int*   dstI   = ei + NE;
  const float* w1     = (const float*)d_in[2];
  const float* g1     = (const float*)d_in[4];
  const float* be1    = (const float*)d_in[5];
  const float* gat_w  = (const float*)d_in[6];
  const float* gat_as = (const float*)d_in[7];
  const float* gat_ad = (const float*)d_in[8];
  const float* g2     = (const float*)d_in[10];
  const float* be2    = (const float*)d_in[11];
  const float* w3     = (const float*)d_in[12];
  const float* g3     = (const float*)d_in[14];
  const float* be3    = (const float*)d_in[15];
  const float* w4     = (const float*)d_in[16];
  const float* g4     = (const float*)d_in[18];
  const float* be4    = (const float*)d_in[19];
  const float* w5     = (const float*)d_in[20];
  const float* g5     = (const float*)d_in[22];
  const float* be5    = (const float*)d_in[23];
  const float* fw1    = (const float*)d_in[24];
  const float* fb1    = (const float*)d_in[25];
  const float* fw2    = (const float*)d_in[26];
  const float* fb2    = (const float*)d_in[27];
  // b1/b3/b4/b5/gat_b are per-column constants followed by BatchNorm ->
  // exactly cancelled by mean subtraction; dropped.
  float* out = (float*)d_out;

  char* wsp = (char*)d_ws;
  size_t off = 0;
  auto alloc = [&](size_t bytes) -> void* {
    void* p = wsp + off;
    off += (bytes + 255) & ~(size_t)255;
    return p;
  };
  ushort* hw_bf  = (ushort*)alloc((size_t)NN * 512 * 2);  // GEMM outputs
  ushort* r1     = (ushort*)alloc((size_t)NN * 256 * 2);  // raw agg outputs (pre-BN)
  ushort* r2     = (ushort*)alloc((size_t)NN * 128 * 2);
  ushort* r3     = (ushort*)alloc((size_t)NN * 64 * 2);
  ushort* r4     = (ushort*)alloc((size_t)NN * 32 * 2);
  ushort* r5     = (ushort*)alloc((size_t)NN * 16 * 2);
  ushort* w1T    = (ushort*)alloc((size_t)256 * 256 * 2);
  ushort* gwT    = (ushort*)alloc((size_t)512 * 256 * 2);
  ushort* w3T    = (ushort*)alloc((size_t)64 * 128 * 2);
  ushort* w4T    = (ushort*)alloc((size_t)32 * 64 * 2);
  ushort* w5T    = (ushort*)alloc((size_t)16 * 32 * 2);
  float*  dinv   = (float*)alloc((size_t)NN * 4);
  int*    counts = (int*)alloc((size_t)NN * 4);
  int*    cursor = (int*)alloc((size_t)NN * 4);
  int*    rstart = (int*)alloc((size_t)(NN + 4) * 4);
  int*    bsum   = (int*)alloc((size_t)256 * 4);
  int*    csr    = (int*)alloc((size_t)NE * 4);
  float*  asc    = (float*)alloc((size_t)NN * 4 * 4);
  float*  adc    = (float*)alloc((size_t)NN * 4 * 4);
  float*  wself  = (float*)alloc((size_t)NN * 4 * 4);
  float*  invden = (float*)alloc((size_t)NN * 4 * 4);
  float*  alpha  = (float*)alloc((size_t)NE * 4 * 4);
  float*  stats  = (float*)alloc(2048);
  float*  partials = (float*)alloc((size_t)512 * GSTAT * 4);  // column-major [2F][GSTAT]

  const int egrid = (NE + 255) / 256;
  const int ngrid = (NN + 255) / 256;     // 196
  const int mblocks = (NN + 127) / 128;   // 391

  // CSR build
  hipMemsetAsync(counts, 0, (size_t)NN * 4, stream);
  hipMemsetAsync(cursor, 0, (size_t)NN * 4, stream);
  count_kernel<<<egrid, 256, 0, stream>>>(dstI, counts, NE);
  block_count_sum<<<ngrid, 256, 0, stream>>>(counts, bsum, dinv, NN);
  scan_bsum<<<1, 256, 0, stream>>>(bsum, ngrid);
  row_start_kernel<<<ngrid, 256, 0, stream>>>(counts, bsum, rstart, NN);
  fill_kernel<<<egrid, 256, 0, stream>>>(srcI, dstI, rstart, cursor, csr, NE);

  // weight prep (all transposes fused)
  wprep<<<810, 256, 0, stream>>>(w1, gat_w, w3, w4, w5, w1T, gwT, w3T, w4T, w5T);

  // ---- Layer 1: GCN 256 -> 256 ----
  gemm_mfma_x<<<dim3(mblocks, 2), 256, 0, stream>>>(x, w1T, hw_bf, NN, 256, 256, dinv);
  gcn_agg_stats<256><<<GSTAT, 256, 0, stream>>>(hw_bf, rstart, csr, dinv, r1, partials, NN);
  bn_reduce_col<<<512, 256, 0, stream>>>(partials, stats);

  // ---- Layer 2: GAT 256 -> 128 (BN1+lrelu fused into A-staging) ----
  gemm_mfma_bn<<<dim3(mblocks, 4), 256, 0, stream>>>(r1, gwT, hw_bf, NN, 256, 512, nullptr,
                                                     stats, g1, be1);
  gat_scores_bf<<<NN, 256, 0, stream>>>(hw_bf, gat_as, gat_ad, asc, adc, NN);
  gat_softmax<<<(4 * NN + 255) / 256, 256, 0, stream>>>(rstart, csr, asc, adc, alpha, wself, invden, NN);
  gat_agg_stats<<<GSTAT, 256, 0, stream>>>(hw_bf, rstart, csr, alpha, wself, invden, r2, partials, NN);
  bn_reduce_col<<<256, 256, 0, stream>>>(partials, stats);

  // ---- Layer 3: GCN 128 -> 64 (BN2 fused) ----
  gemm_mfma_n_bn<64><<<mblocks, 256, 0, stream>>>(r2, w3T, hw_bf, NN, 128, dinv, stats, g2, be2);
  gcn_agg_stats<64><<<GSTAT, 256, 0, stream>>>(hw_bf, rstart, csr, dinv, r3, partials, NN);
  bn_reduce_col<<<128, 256, 0, stream>>>(partials, stats);

  // ---- Layer 4: GCN 64 -> 32 (BN3 fused) ----
  gemm_mfma_n_bn<32><<<mblocks, 256, 0, stream>>>(r3, w4T, hw_bf, NN, 64, dinv, stats, g3, be3);
  gcn_agg_stats<32><<<GSTAT, 256, 0, stream>>>(hw_bf, rstart, csr, dinv, r4, partials, NN);
  bn_reduce_col<<<64, 256, 0, stream>>>(partials, stats);

  // ---- Layer 5: GCN 32 -> 16 (BN4 fused) ----
  gemm_mfma_n_bn<16><<<mblocks, 256, 0, stream>>>(r4, w5T, hw_bf, NN, 32, dinv, stats, g4, be4);
  gcn_agg_stats<16><<<GSTAT, 256, 0, stream>>>(hw_bf, rstart, csr, dinv, r5, partials, NN);
  bn_reduce_col<<<32, 256, 0, stream>>>(partials, stats);

  // ---- FC head (BN5 fused) + log_softmax ----
  head_kernel_bn<<<ngrid, 256, 0, stream>>>(r5, stats, g5, be5, fw1, fb1, fw2, fb2, out, NN);
}

// Round 7
// 388.039 us; speedup vs baseline: 3.4003x; 1.0170x over previous
//
#include <hip/hip_runtime.h>

#define NN 50000
#define NE 400000
#define GSTAT 2048

typedef short bf16x8 __attribute__((ext_vector_type(8)));
typedef float f32x4 __attribute__((ext_vector_type(4)));

__device__ __forceinline__ float lrelu01(float v) { return v >= 0.f ? v : 0.01f * v; }
__device__ __forceinline__ float lrelu02(float v) { return v >= 0.f ? v : 0.2f * v; }

__device__ __forceinline__ ushort f2bf(float f) {
  union { float f; unsigned u; } v; v.f = f;
  unsigned u = v.u;
  return (ushort)((u + 0x7FFFu + ((u >> 16) & 1u)) >> 16);
}
__device__ __forceinline__ float bf2f(ushort u) {
  union { unsigned u; float f; } v; v.u = ((unsigned)u) << 16;
  return v.f;
}

// ---------------- weight prep: all 5 transposes fused ----------------
__global__ void wprep(const float* __restrict__ w1, const float* __restrict__ gw,
                      const float* __restrict__ w3, const float* __restrict__ w4,
                      const float* __restrict__ w5,
                      ushort* __restrict__ w1T, ushort* __restrict__ gwT,
                      ushort* __restrict__ w3T, ushort* __restrict__ w4T,
                      ushort* __restrict__ w5T) {
  int i = blockIdx.x * 256 + threadIdx.x;
  const float* W; ushort* WT; int K, N, j;
  if (i < 65536)        { W = w1; WT = w1T; K = 256; N = 256; j = i; }
  else if (i < 196608)  { W = gw; WT = gwT; K = 256; N = 512; j = i - 65536; }
  else if (i < 204800)  { W = w3; WT = w3T; K = 128; N = 64;  j = i - 196608; }
  else if (i < 206848)  { W = w4; WT = w4T; K = 64;  N = 32;  j = i - 204800; }
  else if (i < 207360)  { W = w5; WT = w5T; K = 32;  N = 16;  j = i - 206848; }
  else return;
  int k = j / N, c = j % N;
  WT[(size_t)c * K + k] = f2bf(W[(size_t)j]);
}

// ---------------- CSR build ----------------
__global__ void count_kernel(const int* __restrict__ dst, int* __restrict__ counts, int e) {
  int i = blockIdx.x * 256 + threadIdx.x;
  if (i < e) atomicAdd(&counts[dst[i]], 1);
}

__global__ __launch_bounds__(256) void block_count_sum(const int* __restrict__ counts,
                                                       int* __restrict__ bsum,
                                                       float* __restrict__ dinv, int n) {
  int i = blockIdx.x * 256 + threadIdx.x;
  int c = (i < n) ? counts[i] : 0;
  if (i < n) dinv[i] = rsqrtf((float)c + 1.0f);
  int s = c;
#pragma unroll
  for (int off = 32; off > 0; off >>= 1) s += __shfl_down(s, off);
  __shared__ int ws[4];
  if ((threadIdx.x & 63) == 0) ws[threadIdx.x >> 6] = s;
  __syncthreads();
  if (threadIdx.x == 0) bsum[blockIdx.x] = ws[0] + ws[1] + ws[2] + ws[3];
}

__global__ __launch_bounds__(256) void scan_bsum(int* __restrict__ bsum, int nb) {
  __shared__ int sh[256];
  int v = (threadIdx.x < nb) ? bsum[threadIdx.x] : 0;
  sh[threadIdx.x] = v;
  __syncthreads();
  for (int off = 1; off < 256; off <<= 1) {
    int t = (threadIdx.x >= off) ? sh[threadIdx.x - off] : 0;
    __syncthreads();
    sh[threadIdx.x] += t;
    __syncthreads();
  }
  if (threadIdx.x < nb) bsum[threadIdx.x] = sh[threadIdx.x] - v;
}

__global__ __launch_bounds__(256) void row_start_kernel(const int* __restrict__ counts,
                                                        const int* __restrict__ bsum,
                                                        int* __restrict__ row_start, int n) {
  __shared__ int sh[256];
  int i = blockIdx.x * 256 + threadIdx.x;
  int c = (i < n) ? counts[i] : 0;
  sh[threadIdx.x] = c;
  __syncthreads();
  for (int off = 1; off < 256; off <<= 1) {
    int t = (threadIdx.x >= off) ? sh[threadIdx.x - off] : 0;
    __syncthreads();
    sh[threadIdx.x] += t;
    __syncthreads();
  }
  int incl = sh[threadIdx.x];
  int base = bsum[blockIdx.x];
  if (i < n) row_start[i] = base + incl - c;
  if (i == n - 1) row_start[n] = base + incl;
}

__global__ void fill_kernel(const int* __restrict__ src, const int* __restrict__ dst,
                            const int* __restrict__ row_start, int* __restrict__ cursor,
                            int* __restrict__ csr, int e) {
  int i = blockIdx.x * 256 + threadIdx.x;
  if (i >= e) return;
  int d = dst[i];
  int pos = atomicAdd(&cursor[d], 1);
  csr[row_start[d] + pos] = src[i];
}

// ---------------- GEMM 1: A fp32 (x), bf16 out, rowscale ----------------
__global__ __launch_bounds__(256) void gemm_mfma_x(const float* __restrict__ A,
                                                   const ushort* __restrict__ BT,
                                                   ushort* __restrict__ C,
                                                   int M, int K, int N,
                                                   const float* __restrict__ rowscale) {
  __shared__ ushort As[128][40];
  __shared__ ushort Bs[128][40];
  const int tid = threadIdx.x;
  const int bm = blockIdx.x * 128;
  const int bn = blockIdx.y * 128;
  const int wave = tid >> 6, lane = tid & 63;
  const int wr = (wave >> 1) * 64;
  const int wc = (wave & 1) * 64;
  const int lr = lane & 15;
  const int lk = (lane >> 4) * 8;

  f32x4 acc[4][4];
#pragma unroll
  for (int m = 0; m < 4; ++m)
#pragma unroll
    for (int n = 0; n < 4; ++n)
#pragma unroll
      for (int q = 0; q < 4; ++q) acc[m][n][q] = 0.f;

  for (int k0 = 0; k0 < K; k0 += 32) {
#pragma unroll
    for (int it = 0; it < 2; ++it) {
      int s = tid + it * 256;
      int r = s >> 2;
      int c = (s & 3) * 8;
      int grow = bm + r; if (grow >= M) grow = M - 1;
      float4 va = *reinterpret_cast<const float4*>(&A[(size_t)grow * K + k0 + c]);
      float4 vb = *reinterpret_cast<const float4*>(&A[(size_t)grow * K + k0 + c + 4]);
      ushort4 lo = make_ushort4(f2bf(va.x), f2bf(va.y), f2bf(va.z), f2bf(va.w));
      ushort4 hi = make_ushort4(f2bf(vb.x), f2bf(vb.y), f2bf(vb.z), f2bf(vb.w));
      *reinterpret_cast<ushort4*>(&As[r][c]) = lo;
      *reinterpret_cast<ushort4*>(&As[r][c + 4]) = hi;
    }
#pragma unroll
    for (int it = 0; it < 2; ++it) {
      int s = tid + it * 256;
      int r = s >> 2;
      int c = (s & 3) * 8;
      int4 v = *reinterpret_cast<const int4*>(&BT[(size_t)(bn + r) * K + k0 + c]);
      *reinterpret_cast<int4*>(&Bs[r][c]) = v;
    }
    __syncthreads();

    bf16x8 af[4], bfr[4];
#pragma unroll
    for (int m = 0; m < 4; ++m)
      af[m] = *reinterpret_cast<const bf16x8*>(&As[wr + m * 16 + lr][lk]);
#pragma unroll
    for (int n = 0; n < 4; ++n)
      bfr[n] = *reinterpret_cast<const bf16x8*>(&Bs[wc + n * 16 + lr][lk]);
#pragma unroll
    for (int m = 0; m < 4; ++m)
#pragma unroll
      for (int n = 0; n < 4; ++n)
        acc[m][n] = __builtin_amdgcn_mfma_f32_16x16x32_bf16(af[m], bfr[n], acc[m][n], 0, 0, 0);
    __syncthreads();
  }

  const int rbase = (lane >> 4) * 4;
  const int cbase = lane & 15;
#pragma unroll
  for (int m = 0; m < 4; ++m) {
#pragma unroll
    for (int q = 0; q < 4; ++q) {
      int row = bm + wr + m * 16 + rbase + q;
      if (row >= M) continue;
      float sc = rowscale ? rowscale[row] : 1.f;
#pragma unroll
      for (int n = 0; n < 4; ++n) {
        int col = bn + wc + n * 16 + cbase;
        C[(size_t)row * N + col] = f2bf(acc[m][n][q] * sc);
      }
    }
  }
}

// ---------------- GEMM with fused BN+lrelu on A (raw bf16 + stats) ----------------
__global__ __launch_bounds__(256) void gemm_mfma_bn(const ushort* __restrict__ A,
                                                    const ushort* __restrict__ BT,
                                                    ushort* __restrict__ C,
                                                    int M, int K, int N,
                                                    const float* __restrict__ rowscale,
                                                    const float* __restrict__ stats,
                                                    const float* __restrict__ gamma,
                                                    const float* __restrict__ beta) {
  __shared__ ushort As[128][40];
  __shared__ ushort Bs[128][40];
  __shared__ float scl[256], shl[256];
  const int tid = threadIdx.x;
  const float inv_n = 1.0f / (float)NN;
  for (int k = tid; k < K; k += 256) {
    float mean = stats[k] * inv_n;
    float var = stats[K + k] * inv_n - mean * mean;
    float sc = gamma[k] * rsqrtf(var + 1e-5f);
    scl[k] = sc;
    shl[k] = beta[k] - mean * sc;
  }
  const int bm = blockIdx.x * 128;
  const int bn = blockIdx.y * 128;
  const int wave = tid >> 6, lane = tid & 63;
  const int wr = (wave >> 1) * 64;
  const int wc = (wave & 1) * 64;
  const int lr = lane & 15;
  const int lk = (lane >> 4) * 8;

  f32x4 acc[4][4];
#pragma unroll
  for (int m = 0; m < 4; ++m)
#pragma unroll
    for (int n = 0; n < 4; ++n)
#pragma unroll
      for (int q = 0; q < 4; ++q) acc[m][n][q] = 0.f;
  __syncthreads();

  for (int k0 = 0; k0 < K; k0 += 32) {
#pragma unroll
    for (int it = 0; it < 2; ++it) {
      int s = tid + it * 256;
      int r = s >> 2;
      int c = (s & 3) * 8;
      int grow = bm + r; if (grow >= M) grow = M - 1;
      int4 v = *reinterpret_cast<const int4*>(&A[(size_t)grow * K + k0 + c]);
      ushort* u = reinterpret_cast<ushort*>(&v);
      ushort tmp[8];
#pragma unroll
      for (int j = 0; j < 8; ++j) {
        float f = bf2f(u[j]) * scl[k0 + c + j] + shl[k0 + c + j];
        tmp[j] = f2bf(f >= 0.f ? f : 0.01f * f);
      }
      *reinterpret_cast<int4*>(&As[r][c]) = *reinterpret_cast<int4*>(tmp);
    }
#pragma unroll
    for (int it = 0; it < 2; ++it) {
      int s = tid + it * 256;
      int r = s >> 2;
      int c = (s & 3) * 8;
      int4 v = *reinterpret_cast<const int4*>(&BT[(size_t)(bn + r) * K + k0 + c]);
      *reinterpret_cast<int4*>(&Bs[r][c]) = v;
    }
    __syncthreads();

    bf16x8 af[4], bfr[4];
#pragma unroll
    for (int m = 0; m < 4; ++m)
      af[m] = *reinterpret_cast<const bf16x8*>(&As[wr + m * 16 + lr][lk]);
#pragma unroll
    for (int n = 0; n < 4; ++n)
      bfr[n] = *reinterpret_cast<const bf16x8*>(&Bs[wc + n * 16 + lr][lk]);
#pragma unroll
    for (int m = 0; m < 4; ++m)
#pragma unroll
      for (int n = 0; n < 4; ++n)
        acc[m][n] = __builtin_amdgcn_mfma_f32_16x16x32_bf16(af[m], bfr[n], acc[m][n], 0, 0, 0);
    __syncthreads();
  }

  const int rbase = (lane >> 4) * 4;
  const int cbase = lane & 15;
#pragma unroll
  for (int m = 0; m < 4; ++m) {
#pragma unroll
    for (int q = 0; q < 4; ++q) {
      int row = bm + wr + m * 16 + rbase + q;
      if (row >= M) continue;
      float sc = rowscale ? rowscale[row] : 1.f;
#pragma unroll
      for (int n = 0; n < 4; ++n) {
        int col = bn + wc + n * 16 + cbase;
        C[(size_t)row * N + col] = f2bf(acc[m][n][q] * sc);
      }
    }
  }
}

// ---------------- small-N GEMM with fused BN+lrelu on A ----------------
template <int TN>
__global__ __launch_bounds__(256) void gemm_mfma_n_bn(const ushort* __restrict__ A,
                                                      const ushort* __restrict__ BT,
                                                      ushort* __restrict__ C,
                                                      int M, int K,
                                                      const float* __restrict__ rowscale,
                                                      const float* __restrict__ stats,
                                                      const float* __restrict__ gamma,
                                                      const float* __restrict__ beta) {
  __shared__ ushort As[128][40];
  __shared__ ushort Bs[TN][40];
  __shared__ float scl[128], shl[128];
  const int tid = threadIdx.x;
  const float inv_n = 1.0f / (float)NN;
  if (tid < K) {
    float mean = stats[tid] * inv_n;
    float var = stats[K + tid] * inv_n - mean * mean;
    float sc = gamma[tid] * rsqrtf(var + 1e-5f);
    scl[tid] = sc;
    shl[tid] = beta[tid] - mean * sc;
  }
  const int bm = blockIdx.x * 128;
  const int wave = tid >> 6, lane = tid & 63;
  const int wr = wave * 32;
  const int lr = lane & 15;
  const int lk = (lane >> 4) * 8;
  constexpr int NF = TN / 16;

  f32x4 acc[2][NF];
#pragma unroll
  for (int m = 0; m < 2; ++m)
#pragma unroll
    for (int n = 0; n < NF; ++n)
#pragma unroll
      for (int q = 0; q < 4; ++q) acc[m][n][q] = 0.f;
  __syncthreads();

  for (int k0 = 0; k0 < K; k0 += 32) {
#pragma unroll
    for (int it = 0; it < 2; ++it) {
      int s = tid + it * 256;
      int r = s >> 2;
      int c = (s & 3) * 8;
      int grow = bm + r; if (grow >= M) grow = M - 1;
      int4 v = *reinterpret_cast<const int4*>(&A[(size_t)grow * K + k0 + c]);
      ushort* u = reinterpret_cast<ushort*>(&v);
      ushort tmp[8];
#pragma unroll
      for (int j = 0; j < 8; ++j) {
        float f = bf2f(u[j]) * scl[k0 + c + j] + shl[k0 + c + j];
        tmp[j] = f2bf(f >= 0.f ? f : 0.01f * f);
      }
      *reinterpret_cast<int4*>(&As[r][c]) = *reinterpret_cast<int4*>(tmp);
    }
    if (tid < TN * 4) {
      int r = tid >> 2;
      int c = (tid & 3) * 8;
      int4 v = *reinterpret_cast<const int4*>(&BT[(size_t)r * K + k0 + c]);
      *reinterpret_cast<int4*>(&Bs[r][c]) = v;
    }
    __syncthreads();

    bf16x8 af[2], bfr[NF];
#pragma unroll
    for (int m = 0; m < 2; ++m)
      af[m] = *reinterpret_cast<const bf16x8*>(&As[wr + m * 16 + lr][lk]);
#pragma unroll
    for (int n = 0; n < NF; ++n)
      bfr[n] = *reinterpret_cast<const bf16x8*>(&Bs[n * 16 + lr][lk]);
#pragma unroll
    for (int m = 0; m < 2; ++m)
#pragma unroll
      for (int n = 0; n < NF; ++n)
        acc[m][n] = __builtin_amdgcn_mfma_f32_16x16x32_bf16(af[m], bfr[n], acc[m][n], 0, 0, 0);
    __syncthreads();
  }

  const int rbase = (lane >> 4) * 4;
  const int cbase = lane & 15;
#pragma unroll
  for (int m = 0; m < 2; ++m) {
#pragma unroll
    for (int q = 0; q < 4; ++q) {
      int row = bm + wr + m * 16 + rbase + q;
      if (row >= M) continue;
      float sc = rowscale ? rowscale[row] : 1.f;
#pragma unroll
      for (int n = 0; n < NF; ++n) {
        int col = n * 16 + cbase;
        C[(size_t)row * TN + col] = f2bf(acc[m][n][q] * sc);
      }
    }
  }
}

// ---------------- GCN agg + fused BN stats (int4 gathers, x4 unroll) ----------------
template <int F>
__global__ __launch_bounds__(256) void gcn_agg_stats(const ushort* __restrict__ h,
                                                     const int* __restrict__ row_start,
                                                     const int* __restrict__ csr,
                                                     const float* __restrict__ dinv,
                                                     ushort* __restrict__ out,
                                                     float* __restrict__ partials, int n) {
  constexpr int LPN = F / 8;           // lanes per node (8 features each)
  constexpr int NPB = 256 / LPN;       // node slots per block
  const int tid = threadIdx.x;
  const int sub = tid / LPN;
  const int f8 = (tid % LPN) * 8;
  float ps[8], pq[8];
#pragma unroll
  for (int j = 0; j < 8; ++j) { ps[j] = 0.f; pq[j] = 0.f; }

  for (int node = blockIdx.x * NPB + sub; node < n; node += GSTAT * NPB) {
    float di = dinv[node];
    float a[8];
    {
      int4 v = *reinterpret_cast<const int4*>(&h[(size_t)node * F + f8]);
      const ushort* u = reinterpret_cast<const ushort*>(&v);
#pragma unroll
      for (int j = 0; j < 8; ++j) a[j] = bf2f(u[j]);
    }
    int s0 = row_start[node], s1 = row_start[node + 1];
    int e = s0;
    for (; e + 3 < s1; e += 4) {
      int sA = csr[e], sB = csr[e + 1], sC = csr[e + 2], sD = csr[e + 3];
      int4 vA = *reinterpret_cast<const int4*>(&h[(size_t)sA * F + f8]);
      int4 vB = *reinterpret_cast<const int4*>(&h[(size_t)sB * F + f8]);
      int4 vC = *reinterpret_cast<const int4*>(&h[(size_t)sC * F + f8]);
      int4 vD = *reinterpret_cast<const int4*>(&h[(size_t)sD * F + f8]);
      const ushort* uA = reinterpret_cast<const ushort*>(&vA);
      const ushort* uB = reinterpret_cast<const ushort*>(&vB);
      const ushort* uC = reinterpret_cast<const ushort*>(&vC);
      const ushort* uD = reinterpret_cast<const ushort*>(&vD);
#pragma unroll
      for (int j = 0; j < 8; ++j)
        a[j] += (bf2f(uA[j]) + bf2f(uB[j])) + (bf2f(uC[j]) + bf2f(uD[j]));
    }
    for (; e < s1; ++e) {
      int sA = csr[e];
      int4 vA = *reinterpret_cast<const int4*>(&h[(size_t)sA * F + f8]);
      const ushort* uA = reinterpret_cast<const ushort*>(&vA);
#pragma unroll
      for (int j = 0; j < 8; ++j) a[j] += bf2f(uA[j]);
    }
    ushort u[8];
#pragma unroll
    for (int j = 0; j < 8; ++j) {
      a[j] *= di;
      u[j] = f2bf(a[j]);
      ps[j] += a[j];
      pq[j] += a[j] * a[j];
    }
    *reinterpret_cast<int4*>(&out[(size_t)node * F + f8]) = *reinterpret_cast<int4*>(u);
  }

  // block stats reduction: red[slot][2F]
  __shared__ float red[NPB][2 * F];
#pragma unroll
  for (int j = 0; j < 8; ++j) {
    red[sub][f8 + j] = ps[j];
    red[sub][F + f8 + j] = pq[j];
  }
  __syncthreads();
  for (int c = tid; c < 2 * F; c += 256) {
    float t = 0.f;
#pragma unroll 4
    for (int s = 0; s < NPB; ++s) t += red[s][c];
    partials[(size_t)c * GSTAT + blockIdx.x] = t;
  }
}

// ---------------- GAT agg: fused softmax + aggregation + BN stats ----------------
// lane = h*16 + l: head h, feature slot l (8 features via one int4 per edge)
__global__ __launch_bounds__(256) void gat_agg_fused(const ushort* __restrict__ hg,
                                                     const int* __restrict__ row_start,
                                                     const int* __restrict__ csr,
                                                     const float* __restrict__ asc,
                                                     const float* __restrict__ adc,
                                                     ushort* __restrict__ out,
                                                     float* __restrict__ partials, int n) {
  const int tid = threadIdx.x;
  const int wave = tid >> 6, lane = tid & 63;
  const int h = lane >> 4;
  const int l = lane & 15;
  const int f8 = l * 8;
  float ps[8], pq[8];
#pragma unroll
  for (int j = 0; j < 8; ++j) { ps[j] = 0.f; pq[j] = 0.f; }

  for (int node = blockIdx.x * 4 + wave; node < n; node += GSTAT * 4) {
    float ad = adc[node * 4 + h];
    float es = lrelu02(asc[node * 4 + h] + ad);
    int s0 = row_start[node], s1 = row_start[node + 1];
    // pass 1: per-head max over incoming edges (16 lanes strided)
    float m = es;
    for (int e = s0 + l; e < s1; e += 16)
      m = fmaxf(m, lrelu02(asc[csr[e] * 4 + h] + ad));
#pragma unroll
    for (int off = 1; off < 16; off <<= 1) m = fmaxf(m, __shfl_xor(m, off));
    float wself = __expf(es - m);
    // pass 2: denominator (16 lanes strided)
    float d = (l == 0) ? wself : 0.f;
    for (int e = s0 + l; e < s1; e += 16)
      d += __expf(lrelu02(asc[csr[e] * 4 + h] + ad) - m);
#pragma unroll
    for (int off = 1; off < 16; off <<= 1) d += __shfl_xor(d, off);
    float coef = 0.25f / (d + 1e-16f);
    // main pass: self + all edges; one int4 (8 features of head h) per edge per lane
    const ushort* base = hg + h * 128 + f8;
    float a[8];
    {
      int4 v = *reinterpret_cast<const int4*>(base + (size_t)node * 512);
      const ushort* u = reinterpret_cast<const ushort*>(&v);
#pragma unroll
      for (int j = 0; j < 8; ++j) a[j] = wself * bf2f(u[j]);
    }
    int e = s0;
    for (; e + 1 < s1; e += 2) {
      int sA = csr[e], sB = csr[e + 1];
      float wA = __expf(lrelu02(asc[sA * 4 + h] + ad) - m);
      float wB = __expf(lrelu02(asc[sB * 4 + h] + ad) - m);
      int4 vA = *reinterpret_cast<const int4*>(base + (size_t)sA * 512);
      int4 vB = *reinterpret_cast<const int4*>(base + (size_t)sB * 512);
      const ushort* uA = reinterpret_cast<const ushort*>(&vA);
      const ushort* uB = reinterpret_cast<const ushort*>(&vB);
#pragma unroll
      for (int j = 0; j < 8; ++j) a[j] += wA * bf2f(uA[j]) + wB * bf2f(uB[j]);
    }
    if (e < s1) {
      int sA = csr[e];
      float wA = __expf(lrelu02(asc[sA * 4 + h] + ad) - m);
      int4 vA = *reinterpret_cast<const int4*>(base + (size_t)sA * 512);
      const ushort* uA = reinterpret_cast<const ushort*>(&vA);
#pragma unroll
      for (int j = 0; j < 8; ++j) a[j] += wA * bf2f(uA[j]);
    }
    // scale by per-head 0.25/den, then sum across the 4 heads
#pragma unroll
    for (int j = 0; j < 8; ++j) {
      a[j] *= coef;
      a[j] += __shfl_xor(a[j], 16);
      a[j] += __shfl_xor(a[j], 32);
    }
    if (h == 0) {
      ushort u[8];
#pragma unroll
      for (int j = 0; j < 8; ++j) {
        u[j] = f2bf(a[j]);
        ps[j] += a[j];
        pq[j] += a[j] * a[j];
      }
      *reinterpret_cast<int4*>(&out[(size_t)node * 128 + f8]) = *reinterpret_cast<int4*>(u);
    }
  }

  // block stats reduction: only h==0 lanes hold partials; red[wave][2*128]
  __shared__ float red[4][256];
  if (h == 0) {
#pragma unroll
    for (int j = 0; j < 8; ++j) {
      red[wave][f8 + j] = ps[j];
      red[wave][128 + f8 + j] = pq[j];
    }
  }
  __syncthreads();
  if (tid < 256) {
    int c = tid;
    float t = red[0][c] + red[1][c] + red[2][c] + red[3][c];
    partials[(size_t)c * GSTAT + blockIdx.x] = t;
  }
}

// ---------------- stats reduce: one block per column ----------------
__global__ __launch_bounds__(256) void bn_reduce_col(const float* __restrict__ partials,
                                                     float* __restrict__ stats) {
  int c = blockIdx.x;
  float s = 0.f;
  for (int b = threadIdx.x; b < GSTAT; b += 256) s += partials[(size_t)c * GSTAT + b];
#pragma unroll
  for (int off = 32; off > 0; off >>= 1) s += __shfl_down(s, off);
  __shared__ float ws[4];
  if ((threadIdx.x & 63) == 0) ws[threadIdx.x >> 6] = s;
  __syncthreads();
  if (threadIdx.x == 0) stats[c] = ws[0] + ws[1] + ws[2] + ws[3];
}

// ---------------- GAT scores ----------------
__global__ __launch_bounds__(256) void gat_scores_bf(const ushort* __restrict__ hg,
                                                     const float* __restrict__ a_src,
                                                     const float* __restrict__ a_dst,
                                                     float* __restrict__ asc,
                                                     float* __restrict__ adc, int n) {
  int node = blockIdx.x;
  int head = threadIdx.x >> 6;
  int lane = threadIdx.x & 63;
  ushort2 v = *reinterpret_cast<const ushort2*>(&hg[(size_t)node * 512 + head * 128 + lane * 2]);
  float v0 = bf2f(v.x), v1 = bf2f(v.y);
  float s = v0 * a_src[head * 128 + lane * 2] + v1 * a_src[head * 128 + lane * 2 + 1];
  float d = v0 * a_dst[head * 128 + lane * 2] + v1 * a_dst[head * 128 + lane * 2 + 1];
#pragma unroll
  for (int off = 32; off > 0; off >>= 1) {
    s += __shfl_down(s, off);
    d += __shfl_down(d, off);
  }
  if (lane == 0) {
    asc[node * 4 + head] = s;
    adc[node * 4 + head] = d;
  }
}

// ---------------- FC head: fused BN+lrelu + MLP + log_softmax ----------------
__global__ __launch_bounds__(256) void head_kernel_bn(const ushort* __restrict__ h,
                                                      const float* __restrict__ stats,
                                                      const float* __restrict__ g5,
                                                      const float* __restrict__ be5,
                                                      const float* __restrict__ fw1,
                                                      const float* __restrict__ fb1,
                                                      const float* __restrict__ fw2,
                                                      const float* __restrict__ fb2,
                                                      float* __restrict__ out, int n) {
  __shared__ float scl[16], shl[16];
  if (threadIdx.x < 16) {
    const float inv_n = 1.0f / (float)NN;
    int k = threadIdx.x;
    float mean = stats[k] * inv_n;
    float var = stats[16 + k] * inv_n - mean * mean;
    float sc = g5[k] * rsqrtf(var + 1e-5f);
    scl[k] = sc;
    shl[k] = be5[k] - mean * sc;
  }
  __syncthreads();
  int i = blockIdx.x * 256 + threadIdx.x;
  if (i >= n) return;
  int4 ra = *reinterpret_cast<const int4*>(&h[(size_t)i * 16]);
  int4 rb = *reinterpret_cast<const int4*>(&h[(size_t)i * 16 + 8]);
  ushort u[16];
  *reinterpret_cast<int4*>(&u[0]) = ra;
  *reinterpret_cast<int4*>(&u[8]) = rb;
  float xr[16];
#pragma unroll
  for (int k = 0; k < 16; ++k) {
    float v = bf2f(u[k]) * scl[k] + shl[k];
    xr[k] = v >= 0.f ? v : 0.01f * v;
  }
  float z[8];
#pragma unroll
  for (int j = 0; j < 8; ++j) z[j] = fb1[j];
#pragma unroll
  for (int k = 0; k < 16; ++k) {
    float a = xr[k];
#pragma unroll
    for (int j = 0; j < 8; ++j) z[j] += a * fw1[k * 8 + j];
  }
#pragma unroll
  for (int j = 0; j < 8; ++j) z[j] = lrelu01(z[j]);
  float l[3];
#pragma unroll
  for (int j = 0; j < 3; ++j) l[j] = fb2[j];
#pragma unroll
  for (int k = 0; k < 8; ++k) {
    float a = z[k];
#pragma unroll
    for (int j = 0; j < 3; ++j) l[j] += a * fw2[k * 3 + j];
  }
  float mx = fmaxf(l[0], fmaxf(l[1], l[2]));
  float se = __expf(l[0] - mx) + __expf(l[1] - mx) + __expf(l[2] - mx);
  float ls = __logf(se);
#pragma unroll
  for (int j = 0; j < 3; ++j) out[(size_t)i * 3 + j] = l[j] - mx - ls;
}

// ---------------- launch ----------------
extern "C" void kernel_launch(void* const* d_in, const int* in_sizes, int n_in,
                              void* d_out, int out_size, void* d_ws, size_t ws_size,
                              hipStream_t stream) {
  const float* x      = (const float*)d_in[0];
  const int*   ei     = (const int*)d_in[1];
  const int*   srcI   = ei;
  const int*   dstI   = ei + NE;
  const float* w1     = (const float*)d_in[2];
  const float* g1     = (const float*)d_in[4];
  const float* be1    = (const float*)d_in[5];
  const float* gat_w  = (const float*)d_in[6];
  const float* gat_as = (const float*)d_in[7];
  const float* gat_ad = (const float*)d_in[8];
  const float* g2     = (const float*)d_in[10];
  const float* be2    = (const float*)d_in[11];
  const float* w3     = (const float*)d_in[12];
  const float* g3     = (const float*)d_in[14];
  const float* be3    = (const float*)d_in[15];
  const float* w4     = (const float*)d_in[16];
  const float* g4     = (const float*)d_in[18];
  const float* be4    = (const float*)d_in[19];
  const float* w5     = (const float*)d_in[20];
  const float* g5     = (const float*)d_in[22];
  const float* be5    = (const float*)d_in[23];
  const float* fw1    = (const float*)d_in[24];
  const float* fb1    = (const float*)d_in[25];
  const float* fw2    = (const float*)d_in[26];
  const float* fb2    = (const float*)d_in[27];
  // b1/b3/b4/b5/gat_b are per-column constants followed by BatchNorm ->
  // exactly cancelled by mean subtraction; dropped.
  float* out = (float*)d_out;

  char* wsp = (char*)d_ws;
  size_t off = 0;
  auto alloc = [&](size_t bytes) -> void* {
    void* p = wsp + off;
    off += (bytes + 255) & ~(size_t)255;
    return p;
  };
  ushort* hw_bf  = (ushort*)alloc((size_t)NN * 512 * 2);  // GEMM outputs
  ushort* r1     = (ushort*)alloc((size_t)NN * 256 * 2);  // raw agg outputs (pre-BN)
  ushort* r2     = (ushort*)alloc((size_t)NN * 128 * 2);
  ushort* r3     = (ushort*)alloc((size_t)NN * 64 * 2);
  ushort* r4     = (ushort*)alloc((size_t)NN * 32 * 2);
  ushort* r5     = (ushort*)alloc((size_t)NN * 16 * 2);
  ushort* w1T    = (ushort*)alloc((size_t)256 * 256 * 2);
  ushort* gwT    = (ushort*)alloc((size_t)512 * 256 * 2);
  ushort* w3T    = (ushort*)alloc((size_t)64 * 128 * 2);
  ushort* w4T    = (ushort*)alloc((size_t)32 * 64 * 2);
  ushort* w5T    = (ushort*)alloc((size_t)16 * 32 * 2);
  float*  dinv   = (float*)alloc((size_t)NN * 4);
  int*    counts = (int*)alloc((size_t)NN * 4);
  int*    cursor = (int*)alloc((size_t)NN * 4);
  int*    rstart = (int*)alloc((size_t)(NN + 4) * 4);
  int*    bsum   = (int*)alloc((size_t)256 * 4);
  int*    csr    = (int*)alloc((size_t)NE * 4);
  float*  asc    = (float*)alloc((size_t)NN * 4 * 4);
  float*  adc    = (float*)alloc((size_t)NN * 4 * 4);
  float*  stats  = (float*)alloc(2048);
  float*  partials = (float*)alloc((size_t)512 * GSTAT * 4);  // column-major [2F][GSTAT]

  const int egrid = (NE + 255) / 256;
  const int ngrid = (NN + 255) / 256;     // 196
  const int mblocks = (NN + 127) / 128;   // 391

  // CSR build
  hipMemsetAsync(counts, 0, (size_t)NN * 4, stream);
  hipMemsetAsync(cursor, 0, (size_t)NN * 4, stream);
  count_kernel<<<egrid, 256, 0, stream>>>(dstI, counts, NE);
  block_count_sum<<<ngrid, 256, 0, stream>>>(counts, bsum, dinv, NN);
  scan_bsum<<<1, 256, 0, stream>>>(bsum, ngrid);
  row_start_kernel<<<ngrid, 256, 0, stream>>>(counts, bsum, rstart, NN);
  fill_kernel<<<egrid, 256, 0, stream>>>(srcI, dstI, rstart, cursor, csr, NE);

  // weight prep
  wprep<<<810, 256, 0, stream>>>(w1, gat_w, w3, w4, w5, w1T, gwT, w3T, w4T, w5T);

  // ---- Layer 1: GCN 256 -> 256 ----
  gemm_mfma_x<<<dim3(mblocks, 2), 256, 0, stream>>>(x, w1T, hw_bf, NN, 256, 256, dinv);
  gcn_agg_stats<256><<<GSTAT, 256, 0, stream>>>(hw_bf, rstart, csr, dinv, r1, partials, NN);
  bn_reduce_col<<<512, 256, 0, stream>>>(partials, stats);

  // ---- Layer 2: GAT 256 -> 128 (BN1+lrelu fused into A-staging) ----
  gemm_mfma_bn<<<dim3(mblocks, 4), 256, 0, stream>>>(r1, gwT, hw_bf, NN, 256, 512, nullptr,
                                                     stats, g1, be1);
  gat_scores_bf<<<NN, 256, 0, stream>>>(hw_bf, gat_as, gat_ad, asc, adc, NN);
  gat_agg_fused<<<GSTAT, 256, 0, stream>>>(hw_bf, rstart, csr, asc, adc, r2, partials, NN);
  bn_reduce_col<<<256, 256, 0, stream>>>(partials, stats);

  // ---- Layer 3: GCN 128 -> 64 (BN2 fused) ----
  gemm_mfma_n_bn<64><<<mblocks, 256, 0, stream>>>(r2, w3T, hw_bf, NN, 128, dinv, stats, g2, be2);
  gcn_agg_stats<64><<<GSTAT, 256, 0, stream>>>(hw_bf, rstart, csr, dinv, r3, partials, NN);
  bn_reduce_col<<<128, 256, 0, stream>>>(partials, stats);

  // ---- Layer 4: GCN 64 -> 32 (BN3 fused) ----
  gemm_mfma_n_bn<32><<<mblocks, 256, 0, stream>>>(r3, w4T, hw_bf, NN, 64, dinv, stats, g3, be3);
  gcn_agg_stats<32><<<GSTAT, 256, 0, stream>>>(hw_bf, rstart, csr, dinv, r4, partials, NN);
  bn_reduce_col<<<64, 256, 0, stream>>>(partials, stats);

  // ---- Layer 5: GCN 32 -> 16 (BN4 fused) ----
  gemm_mfma_n_bn<16><<<mblocks, 256, 0, stream>>>(r4, w5T, hw_bf, NN, 32, dinv, stats, g4, be4);
  gcn_agg_stats<16><<<GSTAT, 256, 0, stream>>>(hw_bf, rstart, csr, dinv, r5, partials, NN);
  bn_reduce_col<<<32, 256, 0, stream>>>(partials, stats);

  // ---- FC head (BN5 fused) + log_softmax ----
  head_kernel_bn<<<ngrid, 256, 0, stream>>>(r5, stats, g5, be5, fw1, fb1, fw2, fb2, out, NN);
}